// Round 2
// baseline (4938.165 us; speedup 1.0000x reference)
//
#include <hip/hip_runtime.h>
#include <hip/hip_bf16.h>

__device__ __forceinline__ float bfu(unsigned short u){ return __uint_as_float(((unsigned int)u)<<16); }
__device__ __forceinline__ unsigned short f2b(float f){
  unsigned int u = __float_as_uint(f);
  unsigned int r = (u + 0x7FFFu + ((u >> 16) & 1u)) >> 16;
  return (unsigned short)r;
}
// shifted softplus: softplus(x) - log(2)
__device__ __forceinline__ float actf(float v){
  return fmaxf(v, 0.f) + log1pf(expf(-fabsf(v))) - 0.69314718055994530942f;
}
__device__ __forceinline__ void atomAddF(float* p, float v){
  unsafeAtomicAdd(p, v);
}

__global__ __launch_bounds__(256) void k_zero(float* p, int n){
  int i = blockIdx.x*256 + threadIdx.x;
  if (i < n) p[i] = 0.f;
}

__global__ __launch_bounds__(256) void k_embed(const int* __restrict__ Z,
    const float* __restrict__ emb, float* __restrict__ x, int N){
  int gid = blockIdx.x*256 + threadIdx.x;
  if (gid < N*128){
    int n = gid >> 7, f = gid & 127;
    x[gid] = emb[Z[n]*128 + f];
  }
}

// One thread per pair: Dij (fp32) to ws and to d_out.
__global__ __launch_bounds__(256) void k_dij(
    const float* __restrict__ R, const int* __restrict__ idx_i, const int* __restrict__ idx_j,
    float* __restrict__ DijF, float* __restrict__ Dout, int P){
  int p = blockIdx.x*256 + threadIdx.x;
  if (p >= P) return;
  int i = idx_i[p], j = idx_j[p];
  float dx = R[i*3+0] - R[j*3+0];
  float dy = R[i*3+1] - R[j*3+1];
  float dz = R[i*3+2] - R[j*3+2];
  float D = sqrtf(fmaxf(dx*dx + dy*dy + dz*dz, 0.f));
  DijF[p] = D;
  Dout[p] = D;
}

// out[n,f] = (RES==2 ? u[f]*Rbuf[n,f] : 0) + (RES==1 ? Rbuf[n,f] : 0)
//            + postact( sum_k preact(A[n,k]) * W[k,f] + bias[f] )
template<int PRE, int POST, int RES>
__global__ __launch_bounds__(256) void k_mm(
    const float* __restrict__ A, const float* __restrict__ W, const float* __restrict__ bias,
    const float* __restrict__ Rbuf, const float* __restrict__ uvec,
    float* __restrict__ out, int N){
  __shared__ __align__(16) unsigned short Ws[128*128]; // bf16 raw, 32 KB
  __shared__ __align__(16) float As[32*128];           // 16 KB
  __shared__ float bS[128];
  __shared__ float uS[128];
  int tid = threadIdx.x;
  {
    const float4* wv = (const float4*)W;
    ushort4* wsv = (ushort4*)Ws;
    #pragma unroll
    for (int i = 0; i < 16; ++i){
      float4 w4 = wv[tid + 256*i];
      ushort4 u4;
      u4.x = f2b(w4.x); u4.y = f2b(w4.y); u4.z = f2b(w4.z); u4.w = f2b(w4.w);
      wsv[tid + 256*i] = u4;
    }
  }
  int rbase = blockIdx.x*32;
  {
    const float4* av = (const float4*)(A + (size_t)rbase*128);
    float4* asv = (float4*)As;
    #pragma unroll
    for (int i = 0; i < 4; ++i){
      int idx = tid + 256*i;
      int rr = idx >> 5;                 // 32 float4 per row
      float4 v = make_float4(0.f,0.f,0.f,0.f);
      if (rbase + rr < N) v = av[idx];
      if (PRE){ v.x=actf(v.x); v.y=actf(v.y); v.z=actf(v.z); v.w=actf(v.w); }
      asv[idx] = v;
    }
  }
  if (tid < 128){
    bS[tid] = bias[tid];
    if (RES == 2) uS[tid] = uvec[tid];
  }
  __syncthreads();
  int f = tid & 127, half = tid >> 7;
  for (int r0 = 0; r0 < 16; ++r0){
    int row = r0*2 + half;
    int grow = rbase + row;
    if (grow >= N) continue;
    const float4* arow4 = (const float4*)&As[row*128];
    float acc = 0.f;
    #pragma unroll
    for (int k4 = 0; k4 < 32; ++k4){
      float4 a4 = arow4[k4];
      int kb = k4*4;
      acc = fmaf(a4.x, bfu(Ws[(kb+0)*128+f]), acc);
      acc = fmaf(a4.y, bfu(Ws[(kb+1)*128+f]), acc);
      acc = fmaf(a4.z, bfu(Ws[(kb+2)*128+f]), acc);
      acc = fmaf(a4.w, bfu(Ws[(kb+3)*128+f]), acc);
    }
    float val = acc + bS[f];
    if (POST) val = actf(val);
    if (RES == 1) val += Rbuf[(size_t)grow*128+f];
    if (RES == 2) val += uS[f]*Rbuf[(size_t)grow*128+f];
    out[(size_t)grow*128+f] = val;
  }
}

// One wave per pair: recompute rbf row from Dij, g = rbf @ k2f (LDS),
// msg = g * xj[idx_j], atomic scatter-add into m[idx_i].
__global__ __launch_bounds__(256) void k_pair_msg(
    const float* __restrict__ DijF, const float* __restrict__ cent, const float* __restrict__ wid,
    const float* __restrict__ k2f,
    const int* __restrict__ idx_i, const int* __restrict__ idx_j,
    const float* __restrict__ xj, float* __restrict__ m, int P){
  __shared__ float k2fS[64*128]; // 32 KB
  int tid = threadIdx.x;
  #pragma unroll
  for (int i = 0; i < 32; ++i) k2fS[tid + 256*i] = k2f[tid + 256*i];
  __syncthreads();
  int p = blockIdx.x*4 + (tid >> 6);
  int lane = tid & 63;
  if (p >= P) return;
  float D = DijF[p];
  float xc = D * 0.1f;
  float cut = 0.f;
  if (xc < 1.f){
    float x3 = xc*xc*xc, x4 = x3*xc, x5 = x4*xc;
    cut = 1.f - 6.f*x5 + 15.f*x4 - 10.f*x3;
  }
  float t = expf(-D) - cent[lane];
  float rl = cut * expf(-wid[lane]*t*t);
  int i = idx_i[p], j = idx_j[p];
  float acc0 = 0.f, acc1 = 0.f;
  #pragma unroll
  for (int k = 0; k < 64; ++k){
    float rk = __shfl(rl, k, 64);
    acc0 = fmaf(rk, k2fS[k*128 + lane], acc0);
    acc1 = fmaf(rk, k2fS[k*128 + 64 + lane], acc1);
  }
  float g0 = acc0 * xj[(size_t)j*128 + lane];
  float g1 = acc1 * xj[(size_t)j*128 + 64 + lane];
  atomAddF(&m[(size_t)i*128 + lane], g0);
  atomAddF(&m[(size_t)i*128 + 64 + lane], g1);
}

// out = act(o) @ out_W[b] ([128,2]); accumulate Ea/Qa, nhloss terms, last2.
__global__ __launch_bounds__(256) void k_outhead(
    const float* __restrict__ o, const float* __restrict__ outW,
    float* __restrict__ Ea, float* __restrict__ Qa,
    float* __restrict__ last2, float* __restrict__ nh, int b, int N){
  __shared__ float w0S[128], w1S[128];
  int tid = threadIdx.x;
  if (tid < 128){ w0S[tid] = outW[tid*2]; w1S[tid] = outW[tid*2+1]; }
  __syncthreads();
  int n = blockIdx.x*256 + tid;
  if (n >= N) return;
  float acc0 = 0.f, acc1 = 0.f;
  const float* orow = o + (size_t)n*128;
  #pragma unroll 8
  for (int f = 0; f < 128; ++f){
    float a = actf(orow[f]);
    acc0 = fmaf(a, w0S[f], acc0);
    acc1 = fmaf(a, w1S[f], acc1);
  }
  Ea[n] += acc0;
  Qa[n] += acc1;
  float e2 = acc0*acc0, q2 = acc1*acc1;
  if (b > 0){
    float le = last2[n*2], lq = last2[n*2+1];
    float t = e2/(e2+le+1e-7f) + q2/(q2+lq+1e-7f);
    atomAddF(nh, t);
  }
  last2[n*2] = e2; last2[n*2+1] = q2;
}

__global__ __launch_bounds__(256) void k_final(
    const int* __restrict__ Z, const float* __restrict__ Ea, const float* __restrict__ Qa,
    const float* __restrict__ Es, const float* __restrict__ Eh,
    const float* __restrict__ Qs, const float* __restrict__ Qh,
    const float* __restrict__ nh, float* __restrict__ out, int N, int P){
  int n = blockIdx.x*256 + threadIdx.x;
  if (n < N){
    int z = Z[n];
    out[n]   = Es[z]*Ea[n] + Eh[z];
    out[N+n] = Qs[z]*Qa[n] + Qh[z];
  }
  if (blockIdx.x == 0 && threadIdx.x == 0)
    out[(size_t)2*N + P] = nh[0] / (2.f * (float)N);
}

extern "C" void kernel_launch(void* const* d_in, const int* in_sizes, int n_in,
                              void* d_out, int out_size, void* d_ws, size_t ws_size,
                              hipStream_t stream){
  const int N = in_sizes[0];
  const int P = in_sizes[2];
  const int F = 128, NB = 5, NRI = 3, NRA = 2;

  const int* Z      = (const int*)d_in[0];
  const float* R    = (const float*)d_in[1];
  const int* idx_i  = (const int*)d_in[2];
  const int* idx_j  = (const int*)d_in[3];
  const float* emb  = (const float*)d_in[4];
  const float* cent = (const float*)d_in[5];
  const float* wid  = (const float*)d_in[6];
  const float* k2f  = (const float*)d_in[7];
  const float* Wi   = (const float*)d_in[8];  const float* bi   = (const float*)d_in[9];
  const float* Wj   = (const float*)d_in[10]; const float* bj   = (const float*)d_in[11];
  const float* riW1 = (const float*)d_in[12]; const float* rib1 = (const float*)d_in[13];
  const float* riW2 = (const float*)d_in[14]; const float* rib2 = (const float*)d_in[15];
  const float* dWp  = (const float*)d_in[16]; const float* dbp  = (const float*)d_in[17];
  const float* u    = (const float*)d_in[18];
  const float* raW1 = (const float*)d_in[19]; const float* rab1 = (const float*)d_in[20];
  const float* raW2 = (const float*)d_in[21]; const float* rab2 = (const float*)d_in[22];
  const float* roW1 = (const float*)d_in[23]; const float* rob1 = (const float*)d_in[24];
  const float* roW2 = (const float*)d_in[25]; const float* rob2 = (const float*)d_in[26];
  const float* outW = (const float*)d_in[27];
  const float* Es   = (const float*)d_in[28]; const float* Eh   = (const float*)d_in[29];
  const float* Qs   = (const float*)d_in[30]; const float* Qh   = (const float*)d_in[31];

  char* ws = (char*)d_ws;
  size_t off = 0;
  float* DijF = (float*)(ws + off); off += (size_t)P*4;
  float* x    = (float*)(ws + off); off += (size_t)N*F*4;
  float* xjb  = (float*)(ws + off); off += (size_t)N*F*4;
  float* m    = (float*)(ws + off); off += (size_t)N*F*4;
  float* h    = (float*)(ws + off); off += (size_t)N*F*4;
  float* o    = (float*)(ws + off); off += (size_t)N*F*4;
  float* Ea   = (float*)(ws + off); off += (size_t)N*4;   // Ea,Qa,nh contiguous: one zero pass
  float* Qa   = (float*)(ws + off); off += (size_t)N*4;
  float* nh   = (float*)(ws + off); off += 256;
  float* last2= (float*)(ws + off); off += (size_t)N*2*4;

  float* outF = (float*)d_out;
  float* Dout = outF + (size_t)2*N;

  k_zero<<<dim3((2*N+1+255)/256), dim3(256), 0, stream>>>(Ea, 2*N+1);
  k_embed<<<dim3((N*F+255)/256), dim3(256), 0, stream>>>(Z, emb, x, N);
  k_dij<<<dim3((P+255)/256), dim3(256), 0, stream>>>(R, idx_i, idx_j, DijF, Dout, P);

  const int mmg = (N + 31)/32;
  const int pg  = (P + 3)/4;
  for (int b = 0; b < NB; ++b){
    k_mm<1,1,0><<<dim3(mmg),dim3(256),0,stream>>>(x, Wi + (size_t)b*F*F, bi + b*F, nullptr, nullptr, m, N);
    k_mm<1,1,0><<<dim3(mmg),dim3(256),0,stream>>>(x, Wj + (size_t)b*F*F, bj + b*F, nullptr, nullptr, xjb, N);
    k_pair_msg<<<dim3(pg),dim3(256),0,stream>>>(DijF, cent, wid, k2f + (size_t)b*64*F, idx_i, idx_j, xjb, m, P);
    for (int l = 0; l < NRI; ++l){
      size_t wo = (size_t)(b*NRI + l)*F*F; int bo = (b*NRI + l)*F;
      k_mm<1,1,0><<<dim3(mmg),dim3(256),0,stream>>>(m, riW1 + wo, rib1 + bo, nullptr, nullptr, h, N);
      k_mm<0,0,1><<<dim3(mmg),dim3(256),0,stream>>>(h, riW2 + wo, rib2 + bo, m, nullptr, m, N);
    }
    k_mm<1,0,2><<<dim3(mmg),dim3(256),0,stream>>>(m, dWp + (size_t)b*F*F, dbp + b*F, x, u + b*F, x, N);
    for (int l = 0; l < NRA; ++l){
      size_t wo = (size_t)(b*NRA + l)*F*F; int bo = (b*NRA + l)*F;
      k_mm<1,1,0><<<dim3(mmg),dim3(256),0,stream>>>(x, raW1 + wo, rab1 + bo, nullptr, nullptr, h, N);
      k_mm<0,0,1><<<dim3(mmg),dim3(256),0,stream>>>(h, raW2 + wo, rab2 + bo, x, nullptr, x, N);
    }
    k_mm<1,1,0><<<dim3(mmg),dim3(256),0,stream>>>(x, roW1 + (size_t)b*F*F, rob1 + b*F, nullptr, nullptr, h, N);
    k_mm<0,0,1><<<dim3(mmg),dim3(256),0,stream>>>(h, roW2 + (size_t)b*F*F, rob2 + b*F, x, nullptr, o, N);
    k_outhead<<<dim3((N+255)/256),dim3(256),0,stream>>>(o, outW + (size_t)b*F*2, Ea, Qa, last2, nh, b, N);
  }
  k_final<<<dim3((N+255)/256),dim3(256),0,stream>>>(Z, Ea, Qa, Es, Eh, Qs, Qh, nh, outF, N, P);
}

// Round 3
// 2846.642 us; speedup vs baseline: 1.7347x; 1.7347x over previous
//
#include <hip/hip_runtime.h>

__device__ __forceinline__ unsigned short f2b(float f){
  unsigned int u = __float_as_uint(f);
  return (unsigned short)((u + 0x7FFFu + ((u >> 16) & 1u)) >> 16);
}
// shifted softplus: softplus(x) - log(2)
__device__ __forceinline__ float actf(float v){
  return fmaxf(v, 0.f) + log1pf(expf(-fabsf(v))) - 0.69314718055994530942f;
}

// ---- shared building blocks for the fused row-tile kernels ----
// Stage a 128x128 fp32 weight matrix from global into LDS as bf16.
__device__ __forceinline__ void stage_w(const float* __restrict__ Wg, unsigned short* Wl, int tid){
  const float4* wv = (const float4*)Wg;
  ushort4* wsv = (ushort4*)Wl;
  #pragma unroll
  for (int i = 0; i < 16; ++i){
    float4 w = wv[tid + 256*i];
    ushort4 u4; u4.x=f2b(w.x); u4.y=f2b(w.y); u4.z=f2b(w.z); u4.w=f2b(w.w);
    wsv[tid + 256*i] = u4;
  }
}

// acc[4][4] = src[32x128 LDS] @ W[128x128 bf16 LDS], thread tile rows r0..r0+3, cols f0..f0+3
__device__ __forceinline__ void mm_core(const float* __restrict__ src,
    const unsigned short* __restrict__ Wl, int r0, int f0, float acc[4][4]){
  #pragma unroll
  for (int r=0;r<4;++r){
    #pragma unroll
    for (int c=0;c<4;++c) acc[r][c]=0.f;
  }
  #pragma unroll 4
  for (int k4 = 0; k4 < 32; ++k4){
    float4 a[4];
    #pragma unroll
    for (int r=0;r<4;++r) a[r] = *(const float4*)(src + (r0+r)*128 + k4*4);
    #pragma unroll
    for (int kk=0;kk<4;++kk){
      uint2 wp = *(const uint2*)(Wl + (k4*4+kk)*128 + f0);
      float w0 = __uint_as_float(wp.x << 16);
      float w1 = __uint_as_float(wp.x & 0xffff0000u);
      float w2 = __uint_as_float(wp.y << 16);
      float w3 = __uint_as_float(wp.y & 0xffff0000u);
      #pragma unroll
      for (int r=0;r<4;++r){
        float ar = ((const float*)&a[r])[kk];
        acc[r][0]=fmaf(ar,w0,acc[r][0]);
        acc[r][1]=fmaf(ar,w1,acc[r][1]);
        acc[r][2]=fmaf(ar,w2,acc[r][2]);
        acc[r][3]=fmaf(ar,w3,acc[r][3]);
      }
    }
  }
}

// ---- small utility kernels ----
__global__ __launch_bounds__(256) void k_zero(float* p, int n){
  int i = blockIdx.x*256 + threadIdx.x;
  if (i < n) p[i] = 0.f;
}

// Dij + per-atom pair count
__global__ __launch_bounds__(256) void k_dij_count(
    const float* __restrict__ R, const int* __restrict__ idx_i, const int* __restrict__ idx_j,
    float* __restrict__ DijF, float* __restrict__ Dout, int* __restrict__ counts, int P){
  int p = blockIdx.x*256 + threadIdx.x;
  if (p >= P) return;
  int i = idx_i[p], j = idx_j[p];
  float dx = R[i*3+0] - R[j*3+0];
  float dy = R[i*3+1] - R[j*3+1];
  float dz = R[i*3+2] - R[j*3+2];
  float D = sqrtf(fmaxf(dx*dx + dy*dy + dz*dz, 0.f));
  DijF[p] = D;
  Dout[p] = D;
  atomicAdd(&counts[i], 1);
}

// single-block exclusive scan over counts[N] -> starts[N+1], cursor[N]
__global__ __launch_bounds__(256) void k_scan(const int* __restrict__ counts,
    int* __restrict__ starts, int* __restrict__ cursor, int N){
  __shared__ int buf[256];
  __shared__ int carryS;
  int tid = threadIdx.x;
  if (tid == 0) carryS = 0;
  __syncthreads();
  for (int base = 0; base < N; base += 256){
    int idx = base + tid;
    int v = (idx < N) ? counts[idx] : 0;
    buf[tid] = v;
    __syncthreads();
    for (int off = 1; off < 256; off <<= 1){
      int t = (tid >= off) ? buf[tid-off] : 0;
      __syncthreads();
      buf[tid] += t;
      __syncthreads();
    }
    int excl = carryS + buf[tid] - v;
    if (idx < N){ starts[idx] = excl; cursor[idx] = excl; }
    __syncthreads();
    if (tid == 255) carryS += buf[255];
    __syncthreads();
  }
  if (tid == 0) starts[N] = carryS;
}

__global__ __launch_bounds__(256) void k_scatter(const int* __restrict__ idx_i,
    int* __restrict__ cursor, int* __restrict__ perm, int P){
  int p = blockIdx.x*256 + threadIdx.x;
  if (p >= P) return;
  int i = idx_i[p];
  int pos = atomicAdd(&cursor[i], 1);
  perm[pos] = p;
}

// ---- phase 1: x = emb[Z]; m = act(act(x)@Wi+bi); xjb = act(act(x)@Wj+bj) ----
__global__ __launch_bounds__(256,2) void k_phase1(
    const int* __restrict__ Z, const float* __restrict__ emb,
    const float* __restrict__ Wi, const float* __restrict__ bi,
    const float* __restrict__ Wj, const float* __restrict__ bj,
    float* __restrict__ x_g, float* __restrict__ m_g, float* __restrict__ xjb_g, int N){
  __shared__ float abuf[32*128];
  __shared__ unsigned short Wl[128*128];
  int tid = threadIdx.x, r0 = (tid>>5)*4, f0 = (tid&31)*4, rbase = blockIdx.x*32;
  float acc[4][4];
  #pragma unroll
  for (int r=0;r<4;++r){
    int row = rbase + r0 + r;
    float4 v = make_float4(0.f,0.f,0.f,0.f);
    if (row < N){
      int z = Z[row];
      v = *(const float4*)(emb + (size_t)z*128 + f0);
      *(float4*)(x_g + (size_t)row*128 + f0) = v;
    }
    float4 av; av.x=actf(v.x); av.y=actf(v.y); av.z=actf(v.z); av.w=actf(v.w);
    *(float4*)(abuf + (r0+r)*128 + f0) = av;
  }
  stage_w(Wi, Wl, tid);
  __syncthreads();
  mm_core(abuf, Wl, r0, f0, acc);
  {
    float4 bv = *(const float4*)(bi + f0);
    #pragma unroll
    for (int r=0;r<4;++r){
      int row = rbase + r0 + r;
      if (row < N){
        float4 ov;
        ov.x=actf(acc[r][0]+bv.x); ov.y=actf(acc[r][1]+bv.y);
        ov.z=actf(acc[r][2]+bv.z); ov.w=actf(acc[r][3]+bv.w);
        *(float4*)(m_g + (size_t)row*128 + f0) = ov;
      }
    }
  }
  __syncthreads();
  stage_w(Wj, Wl, tid);
  __syncthreads();
  mm_core(abuf, Wl, r0, f0, acc);
  {
    float4 bv = *(const float4*)(bj + f0);
    #pragma unroll
    for (int r=0;r<4;++r){
      int row = rbase + r0 + r;
      if (row < N){
        float4 ov;
        ov.x=actf(acc[r][0]+bv.x); ov.y=actf(acc[r][1]+bv.y);
        ov.z=actf(acc[r][2]+bv.z); ov.w=actf(acc[r][3]+bv.w);
        *(float4*)(xjb_g + (size_t)row*128 + f0) = ov;
      }
    }
  }
}

// ---- sorted pair message: one wave per atom, no atomics ----
__global__ __launch_bounds__(256) void k_pairmsg(
    const float* __restrict__ DijF, const float* __restrict__ cent, const float* __restrict__ wid,
    const float* __restrict__ k2f, const int* __restrict__ idx_j,
    const int* __restrict__ starts, const int* __restrict__ perm,
    const float* __restrict__ xjb, float* __restrict__ m_g, int N){
  __shared__ float k2fS[64*128];
  int tid = threadIdx.x;
  {
    const float4* kv = (const float4*)k2f;
    float4* ks = (float4*)k2fS;
    #pragma unroll
    for (int i=0;i<8;++i) ks[tid + 256*i] = kv[tid + 256*i];
  }
  __syncthreads();
  int i = blockIdx.x*4 + (tid >> 6);
  int lane = tid & 63;
  if (i >= N) return;
  int s = starts[i], e = starts[i+1];
  float cl = cent[lane], wl = wid[lane];
  float macc0 = 0.f, macc1 = 0.f;
  for (int t = s; t < e; ++t){
    int p = perm[t];
    float D = DijF[p];
    int j = idx_j[p];
    float xc = D * 0.1f;
    float cut = 0.f;
    if (xc < 1.f){
      float x3 = xc*xc*xc, x4 = x3*xc, x5 = x4*xc;
      cut = 1.f - 6.f*x5 + 15.f*x4 - 10.f*x3;
    }
    float tt = expf(-D) - cl;
    float rl = cut * expf(-wl*tt*tt);
    float acc0 = 0.f, acc1 = 0.f;
    #pragma unroll
    for (int k = 0; k < 64; ++k){
      float rk = __shfl(rl, k, 64);
      acc0 = fmaf(rk, k2fS[k*128 + lane], acc0);
      acc1 = fmaf(rk, k2fS[k*128 + 64 + lane], acc1);
    }
    macc0 = fmaf(acc0, xjb[(size_t)j*128 + lane], macc0);
    macc1 = fmaf(acc1, xjb[(size_t)j*128 + 64 + lane], macc1);
  }
  m_g[(size_t)i*128 + lane] += macc0;
  m_g[(size_t)i*128 + 64 + lane] += macc1;
}

// ---- phase 2: the whole per-block row-local chain, fused ----
// NRI residuals on m -> x = u*x + act(m)@dW+db -> NRA residuals -> output block
// -> head (Ea/Qa/last2/nhloss) -> (HASNEXT) xi/xjb for next block.
template<int HASNEXT, int NH>
__global__ __launch_bounds__(256,2) void k_phase2(
    float* __restrict__ m_g, float* __restrict__ x_g, float* __restrict__ xjb_g,
    const float* __restrict__ riW1, const float* __restrict__ rib1,
    const float* __restrict__ riW2, const float* __restrict__ rib2,
    const float* __restrict__ dW, const float* __restrict__ db, const float* __restrict__ u,
    const float* __restrict__ raW1, const float* __restrict__ rab1,
    const float* __restrict__ raW2, const float* __restrict__ rab2,
    const float* __restrict__ roW1, const float* __restrict__ rob1,
    const float* __restrict__ roW2, const float* __restrict__ rob2,
    const float* __restrict__ outW,
    const float* __restrict__ WiN, const float* __restrict__ biN,
    const float* __restrict__ WjN, const float* __restrict__ bjN,
    float* __restrict__ Ea, float* __restrict__ Qa,
    float* __restrict__ last2, float* __restrict__ nh, int N){
  __shared__ float xbuf[32*128];   // act-buf during NRI, then x tile
  __shared__ float bufA[32*128];   // m tile, then act-buf, then act(o)
  __shared__ float bufB[32*128];   // h tile / scratch
  __shared__ unsigned short Wl[128*128];
  int tid = threadIdx.x, r0 = (tid>>5)*4, f0 = (tid&31)*4, rbase = blockIdx.x*32;
  float acc[4][4];

  // load m tile -> bufA ; xbuf = act(m)
  #pragma unroll
  for (int r=0;r<4;++r){
    int row = rbase + r0 + r;
    float4 v = make_float4(0.f,0.f,0.f,0.f);
    if (row < N) v = *(const float4*)(m_g + (size_t)row*128 + f0);
    *(float4*)(bufA + (r0+r)*128 + f0) = v;
    float4 av; av.x=actf(v.x); av.y=actf(v.y); av.z=actf(v.z); av.w=actf(v.w);
    *(float4*)(xbuf + (r0+r)*128 + f0) = av;
  }
  // --- NRI residuals on m (bufA), act-src in xbuf ---
  for (int l = 0; l < 3; ++l){
    __syncthreads();
    stage_w(riW1 + l*16384, Wl, tid);
    __syncthreads();
    mm_core(xbuf, Wl, r0, f0, acc);
    {
      float4 bv = *(const float4*)(rib1 + l*128 + f0);
      #pragma unroll
      for (int r=0;r<4;++r){
        float* hp = bufB + (r0+r)*128 + f0;
        hp[0]=actf(acc[r][0]+bv.x); hp[1]=actf(acc[r][1]+bv.y);
        hp[2]=actf(acc[r][2]+bv.z); hp[3]=actf(acc[r][3]+bv.w);
      }
    }
    __syncthreads();
    stage_w(riW2 + l*16384, Wl, tid);
    __syncthreads();
    mm_core(bufB, Wl, r0, f0, acc);
    {
      float4 bv = *(const float4*)(rib2 + l*128 + f0);
      #pragma unroll
      for (int r=0;r<4;++r){
        float* mp = bufA + (r0+r)*128 + f0;
        float* ap = xbuf + (r0+r)*128 + f0;
        float n0=mp[0]+acc[r][0]+bv.x, n1=mp[1]+acc[r][1]+bv.y;
        float n2=mp[2]+acc[r][2]+bv.z, n3=mp[3]+acc[r][3]+bv.w;
        mp[0]=n0; mp[1]=n1; mp[2]=n2; mp[3]=n3;
        ap[0]=actf(n0); ap[1]=actf(n1); ap[2]=actf(n2); ap[3]=actf(n3);
      }
    }
  }
  // --- x-update: xbuf (currently act(m_final)) is both src and dst ---
  __syncthreads();
  stage_w(dW, Wl, tid);
  __syncthreads();
  mm_core(xbuf, Wl, r0, f0, acc);
  __syncthreads();   // all cross-thread reads of xbuf complete before overwrite
  {
    float4 uv = *(const float4*)(u + f0);
    float4 bv = *(const float4*)(db + f0);
    #pragma unroll
    for (int r=0;r<4;++r){
      int row = rbase + r0 + r;
      float4 xv = make_float4(0.f,0.f,0.f,0.f);
      if (row < N) xv = *(const float4*)(x_g + (size_t)row*128 + f0);
      float n0 = uv.x*xv.x + acc[r][0] + bv.x;
      float n1 = uv.y*xv.y + acc[r][1] + bv.y;
      float n2 = uv.z*xv.z + acc[r][2] + bv.z;
      float n3 = uv.w*xv.w + acc[r][3] + bv.w;
      float* xp = xbuf + (r0+r)*128 + f0;
      xp[0]=n0; xp[1]=n1; xp[2]=n2; xp[3]=n3;
      float* ap = bufA + (r0+r)*128 + f0;
      ap[0]=actf(n0); ap[1]=actf(n1); ap[2]=actf(n2); ap[3]=actf(n3);
    }
  }
  // --- NRA residuals on x (xbuf), act-src bufA ---
  for (int l = 0; l < 2; ++l){
    __syncthreads();
    stage_w(raW1 + l*16384, Wl, tid);
    __syncthreads();
    mm_core(bufA, Wl, r0, f0, acc);
    {
      float4 bv = *(const float4*)(rab1 + l*128 + f0);
      #pragma unroll
      for (int r=0;r<4;++r){
        float* hp = bufB + (r0+r)*128 + f0;
        hp[0]=actf(acc[r][0]+bv.x); hp[1]=actf(acc[r][1]+bv.y);
        hp[2]=actf(acc[r][2]+bv.z); hp[3]=actf(acc[r][3]+bv.w);
      }
    }
    __syncthreads();
    stage_w(raW2 + l*16384, Wl, tid);
    __syncthreads();
    mm_core(bufB, Wl, r0, f0, acc);
    {
      float4 bv = *(const float4*)(rab2 + l*128 + f0);
      #pragma unroll
      for (int r=0;r<4;++r){
        int row = rbase + r0 + r;
        float* xp = xbuf + (r0+r)*128 + f0;
        float n0=xp[0]+acc[r][0]+bv.x, n1=xp[1]+acc[r][1]+bv.y;
        float n2=xp[2]+acc[r][2]+bv.z, n3=xp[3]+acc[r][3]+bv.w;
        xp[0]=n0; xp[1]=n1; xp[2]=n2; xp[3]=n3;
        float* ap = bufA + (r0+r)*128 + f0;
        ap[0]=actf(n0); ap[1]=actf(n1); ap[2]=actf(n2); ap[3]=actf(n3);
        if (HASNEXT && l == 1 && row < N){
          float4 ov; ov.x=n0; ov.y=n1; ov.z=n2; ov.w=n3;
          *(float4*)(x_g + (size_t)row*128 + f0) = ov;
        }
      }
    }
  }
  // --- output block: o = x + act(act(x)@roW1+b1)@roW2+b2 ; keep act(o) in bufA ---
  __syncthreads();
  stage_w(roW1, Wl, tid);
  __syncthreads();
  mm_core(bufA, Wl, r0, f0, acc);
  {
    float4 bv = *(const float4*)(rob1 + f0);
    #pragma unroll
    for (int r=0;r<4;++r){
      float* hp = bufB + (r0+r)*128 + f0;
      hp[0]=actf(acc[r][0]+bv.x); hp[1]=actf(acc[r][1]+bv.y);
      hp[2]=actf(acc[r][2]+bv.z); hp[3]=actf(acc[r][3]+bv.w);
    }
  }
  __syncthreads();
  stage_w(roW2, Wl, tid);
  __syncthreads();
  mm_core(bufB, Wl, r0, f0, acc);
  {
    float4 bv = *(const float4*)(rob2 + f0);
    #pragma unroll
    for (int r=0;r<4;++r){
      const float* xp = xbuf + (r0+r)*128 + f0;
      float* ap = bufA + (r0+r)*128 + f0;
      ap[0]=actf(xp[0]+acc[r][0]+bv.x); ap[1]=actf(xp[1]+acc[r][1]+bv.y);
      ap[2]=actf(xp[2]+acc[r][2]+bv.z); ap[3]=actf(xp[3]+acc[r][3]+bv.w);
    }
  }
  // --- head: out = act(o)@outW ; Ea/Qa/last2/nhloss ---
  __syncthreads();
  if (tid < 64) *(float4*)(bufB + tid*4) = *(const float4*)(outW + tid*4);
  __syncthreads();
  float tpart = 0.f;
  if (tid < 32){
    int row = rbase + tid;
    if (row < N){
      float a0 = 0.f, a1 = 0.f;
      for (int f = 0; f < 128; ++f){
        float a = bufA[tid*128 + f];
        a0 = fmaf(a, bufB[f*2], a0);
        a1 = fmaf(a, bufB[f*2+1], a1);
      }
      Ea[row] += a0;
      Qa[row] += a1;
      float e2 = a0*a0, q2 = a1*a1;
      if (NH){
        float le = last2[row*2], lq = last2[row*2+1];
        tpart = e2/(e2+le+1e-7f) + q2/(q2+lq+1e-7f);
      }
      last2[row*2] = e2; last2[row*2+1] = q2;
    }
  }
  if (NH){
    __syncthreads();
    if (tid < 32) bufB[256 + tid] = tpart;
    __syncthreads();
    if (tid == 0){
      float s = 0.f;
      for (int q = 0; q < 32; ++q) s += bufB[256 + q];
      unsafeAtomicAdd(nh, s);
    }
  }
  // --- next block's xi / xjb from final x ---
  if (HASNEXT){
    __syncthreads();   // head's reads of bufA done
    #pragma unroll
    for (int r=0;r<4;++r){
      float* ap = bufA + (r0+r)*128 + f0;
      const float* xp = xbuf + (r0+r)*128 + f0;
      ap[0]=actf(xp[0]); ap[1]=actf(xp[1]); ap[2]=actf(xp[2]); ap[3]=actf(xp[3]);
    }
    stage_w(WiN, Wl, tid);
    __syncthreads();
    mm_core(bufA, Wl, r0, f0, acc);
    {
      float4 bv = *(const float4*)(biN + f0);
      #pragma unroll
      for (int r=0;r<4;++r){
        int row = rbase + r0 + r;
        if (row < N){
          float4 ov;
          ov.x=actf(acc[r][0]+bv.x); ov.y=actf(acc[r][1]+bv.y);
          ov.z=actf(acc[r][2]+bv.z); ov.w=actf(acc[r][3]+bv.w);
          *(float4*)(m_g + (size_t)row*128 + f0) = ov;
        }
      }
    }
    __syncthreads();
    stage_w(WjN, Wl, tid);
    __syncthreads();
    mm_core(bufA, Wl, r0, f0, acc);
    {
      float4 bv = *(const float4*)(bjN + f0);
      #pragma unroll
      for (int r=0;r<4;++r){
        int row = rbase + r0 + r;
        if (row < N){
          float4 ov;
          ov.x=actf(acc[r][0]+bv.x); ov.y=actf(acc[r][1]+bv.y);
          ov.z=actf(acc[r][2]+bv.z); ov.w=actf(acc[r][3]+bv.w);
          *(float4*)(xjb_g + (size_t)row*128 + f0) = ov;
        }
      }
    }
  }
}

__global__ __launch_bounds__(256) void k_final(
    const int* __restrict__ Z, const float* __restrict__ Ea, const float* __restrict__ Qa,
    const float* __restrict__ Es, const float* __restrict__ Eh,
    const float* __restrict__ Qs, const float* __restrict__ Qh,
    const float* __restrict__ nh, float* __restrict__ out, int N, int P){
  int n = blockIdx.x*256 + threadIdx.x;
  if (n < N){
    int z = Z[n];
    out[n]   = Es[z]*Ea[n] + Eh[z];
    out[N+n] = Qs[z]*Qa[n] + Qh[z];
  }
  if (blockIdx.x == 0 && threadIdx.x == 0)
    out[(size_t)2*N + P] = nh[0] / (2.f * (float)N);
}

extern "C" void kernel_launch(void* const* d_in, const int* in_sizes, int n_in,
                              void* d_out, int out_size, void* d_ws, size_t ws_size,
                              hipStream_t stream){
  const int N = in_sizes[0];
  const int P = in_sizes[2];
  const int F = 128, NRI = 3, NRA = 2;

  const int* Z      = (const int*)d_in[0];
  const float* R    = (const float*)d_in[1];
  const int* idx_i  = (const int*)d_in[2];
  const int* idx_j  = (const int*)d_in[3];
  const float* emb  = (const float*)d_in[4];
  const float* cent = (const float*)d_in[5];
  const float* wid  = (const float*)d_in[6];
  const float* k2f  = (const float*)d_in[7];
  const float* Wi   = (const float*)d_in[8];  const float* bi   = (const float*)d_in[9];
  const float* Wj   = (const float*)d_in[10]; const float* bj   = (const float*)d_in[11];
  const float* riW1 = (const float*)d_in[12]; const float* rib1 = (const float*)d_in[13];
  const float* riW2 = (const float*)d_in[14]; const float* rib2 = (const float*)d_in[15];
  const float* dWp  = (const float*)d_in[16]; const float* dbp  = (const float*)d_in[17];
  const float* u    = (const float*)d_in[18];
  const float* raW1 = (const float*)d_in[19]; const float* rab1 = (const float*)d_in[20];
  const float* raW2 = (const float*)d_in[21]; const float* rab2 = (const float*)d_in[22];
  const float* roW1 = (const float*)d_in[23]; const float* rob1 = (const float*)d_in[24];
  const float* roW2 = (const float*)d_in[25]; const float* rob2 = (const float*)d_in[26];
  const float* outW = (const float*)d_in[27];
  const float* Es   = (const float*)d_in[28]; const float* Eh   = (const float*)d_in[29];
  const float* Qs   = (const float*)d_in[30]; const float* Qh   = (const float*)d_in[31];

  char* ws = (char*)d_ws;
  size_t off = 0;
  float* DijF  = (float*)(ws + off); off += (size_t)P*4;
  float* x     = (float*)(ws + off); off += (size_t)N*F*4;
  float* xjb   = (float*)(ws + off); off += (size_t)N*F*4;
  float* m     = (float*)(ws + off); off += (size_t)N*F*4;
  float* last2 = (float*)(ws + off); off += (size_t)N*2*4;
  float* Ea    = (float*)(ws + off); off += (size_t)N*4;   // zero region start
  float* Qa    = (float*)(ws + off); off += (size_t)N*4;
  float* nh    = (float*)(ws + off); off += 256;
  int*   counts= (int*)  (ws + off); off += (size_t)N*4;   // zero region end
  int*   starts= (int*)  (ws + off); off += (size_t)(N+1)*4;
  int*   cursor= (int*)  (ws + off); off += (size_t)N*4;
  int*   perm  = (int*)  (ws + off); off += (size_t)P*4;

  float* outF = (float*)d_out;
  float* Dout = outF + (size_t)2*N;

  const int nzero = 3*N + 64;
  k_zero<<<dim3((nzero+255)/256), dim3(256), 0, stream>>>(Ea, nzero);
  k_dij_count<<<dim3((P+255)/256), dim3(256), 0, stream>>>(R, idx_i, idx_j, DijF, Dout, counts, P);
  k_scan<<<dim3(1), dim3(256), 0, stream>>>(counts, starts, cursor, N);
  k_scatter<<<dim3((P+255)/256), dim3(256), 0, stream>>>(idx_i, cursor, perm, P);

  const int mmg = (N + 31)/32;
  k_phase1<<<dim3(mmg), dim3(256), 0, stream>>>(Z, emb, Wi, bi, Wj, bj, x, m, xjb, N);

  const int pg = (N + 3)/4;
  for (int b = 0; b < 5; ++b){
    k_pairmsg<<<dim3(pg), dim3(256), 0, stream>>>(DijF, cent, wid, k2f + (size_t)b*64*F,
                                                  idx_j, starts, perm, xjb, m, N);
    const float* a_riW1 = riW1 + (size_t)b*NRI*F*F;
    const float* a_rib1 = rib1 + (size_t)b*NRI*F;
    const float* a_riW2 = riW2 + (size_t)b*NRI*F*F;
    const float* a_rib2 = rib2 + (size_t)b*NRI*F;
    const float* a_dW   = dWp  + (size_t)b*F*F;
    const float* a_db   = dbp  + (size_t)b*F;
    const float* a_u    = u    + (size_t)b*F;
    const float* a_raW1 = raW1 + (size_t)b*NRA*F*F;
    const float* a_rab1 = rab1 + (size_t)b*NRA*F;
    const float* a_raW2 = raW2 + (size_t)b*NRA*F*F;
    const float* a_rab2 = rab2 + (size_t)b*NRA*F;
    const float* a_roW1 = roW1 + (size_t)b*F*F;
    const float* a_rob1 = rob1 + (size_t)b*F;
    const float* a_roW2 = roW2 + (size_t)b*F*F;
    const float* a_rob2 = rob2 + (size_t)b*F;
    const float* a_outW = outW + (size_t)b*F*2;
    int bn = (b < 4) ? (b+1) : 4;
    const float* a_WiN = Wi + (size_t)bn*F*F; const float* a_biN = bi + (size_t)bn*F;
    const float* a_WjN = Wj + (size_t)bn*F*F; const float* a_bjN = bj + (size_t)bn*F;
    if (b == 0){
      k_phase2<1,0><<<dim3(mmg), dim3(256), 0, stream>>>(m, x, xjb,
        a_riW1, a_rib1, a_riW2, a_rib2, a_dW, a_db, a_u,
        a_raW1, a_rab1, a_raW2, a_rab2, a_roW1, a_rob1, a_roW2, a_rob2,
        a_outW, a_WiN, a_biN, a_WjN, a_bjN, Ea, Qa, last2, nh, N);
    } else if (b < 4){
      k_phase2<1,1><<<dim3(mmg), dim3(256), 0, stream>>>(m, x, xjb,
        a_riW1, a_rib1, a_riW2, a_rib2, a_dW, a_db, a_u,
        a_raW1, a_rab1, a_raW2, a_rab2, a_roW1, a_rob1, a_roW2, a_rob2,
        a_outW, a_WiN, a_biN, a_WjN, a_bjN, Ea, Qa, last2, nh, N);
    } else {
      k_phase2<0,1><<<dim3(mmg), dim3(256), 0, stream>>>(m, x, xjb,
        a_riW1, a_rib1, a_riW2, a_rib2, a_dW, a_db, a_u,
        a_raW1, a_rab1, a_raW2, a_rab2, a_roW1, a_rob1, a_roW2, a_rob2,
        a_outW, a_WiN, a_biN, a_WjN, a_bjN, Ea, Qa, last2, nh, N);
    }
  }
  k_final<<<dim3((N+255)/256), dim3(256), 0, stream>>>(Z, Ea, Qa, Es, Eh, Qs, Qh, nh, outF, N, P);
}

// Round 4
// 1712.988 us; speedup vs baseline: 2.8828x; 1.6618x over previous
//
#include <hip/hip_runtime.h>

typedef __attribute__((ext_vector_type(8))) short bfrag;   // 8 bf16 (4 VGPRs)
typedef __attribute__((ext_vector_type(4))) float ffrag;   // 4 fp32

__device__ __forceinline__ unsigned short f2b(float f){
  unsigned int u = __float_as_uint(f);
  return (unsigned short)((u + 0x7FFFu + ((u >> 16) & 1u)) >> 16);
}
// shifted softplus: softplus(x) - log(2)
__device__ __forceinline__ float actf(float v){
  return fmaxf(v, 0.f) + log1pf(expf(-fabsf(v))) - 0.69314718055994530942f;
}

// Stage a 128x128 fp32 weight matrix from global into LDS as bf16.
__device__ __forceinline__ void stage_w(const float* __restrict__ Wg, unsigned short* Wl, int tid){
  const float4* wv = (const float4*)Wg;
  ushort4* wsv = (ushort4*)Wl;
  #pragma unroll
  for (int i = 0; i < 16; ++i){
    float4 w = wv[tid + 256*i];
    ushort4 u4; u4.x=f2b(w.x); u4.y=f2b(w.y); u4.z=f2b(w.z); u4.w=f2b(w.w);
    wsv[tid + 256*i] = u4;
  }
}

// acc[4][4] = src[32x128 LDS] @ W[128x128 bf16 LDS]
__device__ __forceinline__ void mm_core(const float* __restrict__ src,
    const unsigned short* __restrict__ Wl, int r0, int f0, float acc[4][4]){
  #pragma unroll
  for (int r=0;r<4;++r){
    #pragma unroll
    for (int c=0;c<4;++c) acc[r][c]=0.f;
  }
  #pragma unroll 4
  for (int k4 = 0; k4 < 32; ++k4){
    float4 a[4];
    #pragma unroll
    for (int r=0;r<4;++r) a[r] = *(const float4*)(src + (r0+r)*128 + k4*4);
    #pragma unroll
    for (int kk=0;kk<4;++kk){
      uint2 wp = *(const uint2*)(Wl + (k4*4+kk)*128 + f0);
      float w0 = __uint_as_float(wp.x << 16);
      float w1 = __uint_as_float(wp.x & 0xffff0000u);
      float w2 = __uint_as_float(wp.y << 16);
      float w3 = __uint_as_float(wp.y & 0xffff0000u);
      #pragma unroll
      for (int r=0;r<4;++r){
        float ar = ((const float*)&a[r])[kk];
        acc[r][0]=fmaf(ar,w0,acc[r][0]);
        acc[r][1]=fmaf(ar,w1,acc[r][1]);
        acc[r][2]=fmaf(ar,w2,acc[r][2]);
        acc[r][3]=fmaf(ar,w3,acc[r][3]);
      }
    }
  }
}

__global__ __launch_bounds__(256) void k_zero(float* p, int n){
  int i = blockIdx.x*256 + threadIdx.x;
  if (i < n) p[i] = 0.f;
}

__global__ __launch_bounds__(256) void k_dij_count(
    const float* __restrict__ R, const int* __restrict__ idx_i, const int* __restrict__ idx_j,
    float* __restrict__ DijF, float* __restrict__ Dout, int* __restrict__ counts, int P){
  int p = blockIdx.x*256 + threadIdx.x;
  if (p >= P) return;
  int i = idx_i[p], j = idx_j[p];
  float dx = R[i*3+0] - R[j*3+0];
  float dy = R[i*3+1] - R[j*3+1];
  float dz = R[i*3+2] - R[j*3+2];
  float D = sqrtf(fmaxf(dx*dx + dy*dy + dz*dz, 0.f));
  DijF[p] = D;
  Dout[p] = D;
  atomicAdd(&counts[i], 1);
}

__global__ __launch_bounds__(256) void k_scan(const int* __restrict__ counts,
    int* __restrict__ starts, int* __restrict__ cursor, int N){
  __shared__ int buf[256];
  __shared__ int carryS;
  int tid = threadIdx.x;
  if (tid == 0) carryS = 0;
  __syncthreads();
  for (int base = 0; base < N; base += 256){
    int idx = base + tid;
    int v = (idx < N) ? counts[idx] : 0;
    buf[tid] = v;
    __syncthreads();
    for (int off = 1; off < 256; off <<= 1){
      int t = (tid >= off) ? buf[tid-off] : 0;
      __syncthreads();
      buf[tid] += t;
      __syncthreads();
    }
    int excl = carryS + buf[tid] - v;
    if (idx < N){ starts[idx] = excl; cursor[idx] = excl; }
    __syncthreads();
    if (tid == 255) carryS += buf[255];
    __syncthreads();
  }
  if (tid == 0) starts[N] = carryS;
}

// scatter into sorted-by-i arrays: i_s, j_s, D_s
__global__ __launch_bounds__(256) void k_scatter(const int* __restrict__ idx_i,
    const int* __restrict__ idx_j, const float* __restrict__ DijF,
    int* __restrict__ cursor, int* __restrict__ i_s, int* __restrict__ j_s,
    float* __restrict__ D_s, int P){
  int p = blockIdx.x*256 + threadIdx.x;
  if (p >= P) return;
  int i = idx_i[p];
  int pos = atomicAdd(&cursor[i], 1);
  i_s[pos] = i;
  j_s[pos] = idx_j[p];
  D_s[pos] = DijF[p];
}

// rbf_s[t][k] bf16, one thread per (t,k)
__global__ __launch_bounds__(256) void k_rbf(
    const float* __restrict__ D_s, const float* __restrict__ cent, const float* __restrict__ wid,
    unsigned short* __restrict__ rbf_s, int P){
  int gid = blockIdx.x*256 + threadIdx.x;
  if (gid >= P*64) return;
  int t = gid >> 6, k = gid & 63;
  float D = D_s[t];
  float xc = D * 0.1f;
  float cut = 0.f;
  if (xc < 1.f){
    float x3 = xc*xc*xc, x4 = x3*xc, x5 = x4*xc;
    cut = 1.f - 6.f*x5 + 15.f*x4 - 10.f*x3;
  }
  float tt = expf(-D) - cent[k];
  rbf_s[gid] = f2b(cut * expf(-wid[k]*tt*tt));
}

// prepack k2f (all 5 blocks) into MFMA B-frag order:
// k2fP[((b*16 + tile*2 + kh)*64 + lane)*8 + j] = bf16(k2f[b][kh*32+(lane>>4)*8+j][tile*16+(lane&15)])
__global__ __launch_bounds__(256) void k_prep(const float* __restrict__ k2f,
    unsigned short* __restrict__ k2fP){
  int gid = blockIdx.x*256 + threadIdx.x;
  if (gid >= 5120) return;
  int l = gid & 63, fr = (gid >> 6) & 15, b = gid >> 10;
  int tile = fr >> 1, kh = fr & 1;
  const float* src = k2f + (size_t)b*64*128;
  int n = tile*16 + (l & 15);
  int kbase = kh*32 + (l >> 4)*8;
  ushort4 o0, o1;
  o0.x = f2b(src[(kbase+0)*128+n]); o0.y = f2b(src[(kbase+1)*128+n]);
  o0.z = f2b(src[(kbase+2)*128+n]); o0.w = f2b(src[(kbase+3)*128+n]);
  o1.x = f2b(src[(kbase+4)*128+n]); o1.y = f2b(src[(kbase+5)*128+n]);
  o1.z = f2b(src[(kbase+6)*128+n]); o1.w = f2b(src[(kbase+7)*128+n]);
  ushort4* dst = (ushort4*)(k2fP + (size_t)gid*8);
  dst[0] = o0; dst[1] = o1;
}

// MFMA pair-message: each wave owns 128 contiguous sorted pairs.
// Per 16-pair batch: G[16x128] = rbf_s[16x64] @ k2f[64x128] via 16 mfma,
// G through wave-private LDS, then modulate with gathered xj and
// register-accumulate per segment; atomic flush at segment boundaries.
__global__ __launch_bounds__(256) void k_pairmsg2(
    const unsigned short* __restrict__ rbf_s, const unsigned short* __restrict__ k2fP,
    const int* __restrict__ i_s, const int* __restrict__ j_s,
    const float* __restrict__ xj, float* __restrict__ m_g, int P){
  __shared__ float G[4][16*130];
  int tid = threadIdx.x, w = tid >> 6, l = tid & 63;
  float* Gw = &G[w][0];
  bfrag B[8][2];
  #pragma unroll
  for (int t = 0; t < 8; ++t){
    #pragma unroll
    for (int kh = 0; kh < 2; ++kh)
      B[t][kh] = *(const bfrag*)(k2fP + (size_t)((t*2+kh)*64 + l)*8);
  }
  int wstart = (blockIdx.x*4 + w)*128;
  int row16 = l & 15, quad = l >> 4;
  float a0 = 0.f, a1 = 0.f;
  int iCur = -1;
  for (int bt = wstart; bt < wstart + 128; bt += 16){
    if (bt >= P) break;
    int arow = bt + row16;
    bfrag A0 = {0,0,0,0,0,0,0,0}, A1 = {0,0,0,0,0,0,0,0};
    if (arow < P){
      A0 = *(const bfrag*)(rbf_s + (size_t)arow*64 + quad*8);
      A1 = *(const bfrag*)(rbf_s + (size_t)arow*64 + 32 + quad*8);
    }
    #pragma unroll
    for (int t = 0; t < 8; ++t){
      ffrag C = {0.f,0.f,0.f,0.f};
      C = __builtin_amdgcn_mfma_f32_16x16x32_bf16(A0, B[t][0], C, 0, 0, 0);
      C = __builtin_amdgcn_mfma_f32_16x16x32_bf16(A1, B[t][1], C, 0, 0, 0);
      #pragma unroll
      for (int r = 0; r < 4; ++r)
        Gw[(quad*4+r)*130 + t*16 + row16] = C[r];   // G[p=quad*4+r][f=t*16+row16]
    }
    int tmax = P - bt; if (tmax > 16) tmax = 16;
    for (int k = 0; k < 16; ++k){
      if (k >= tmax) break;
      int t = bt + k;
      int i = i_s[t], j = j_s[t];
      if (i != iCur){
        if (iCur >= 0){
          unsafeAtomicAdd(&m_g[(size_t)iCur*128 + 2*l],     a0);
          unsafeAtomicAdd(&m_g[(size_t)iCur*128 + 2*l + 1], a1);
        }
        iCur = i; a0 = 0.f; a1 = 0.f;
      }
      float2 xv = *(const float2*)(xj + (size_t)j*128 + 2*l);
      float g0 = Gw[k*130 + 2*l], g1 = Gw[k*130 + 2*l + 1];
      a0 = fmaf(g0, xv.x, a0);
      a1 = fmaf(g1, xv.y, a1);
    }
  }
  if (iCur >= 0){
    unsafeAtomicAdd(&m_g[(size_t)iCur*128 + 2*l],     a0);
    unsafeAtomicAdd(&m_g[(size_t)iCur*128 + 2*l + 1], a1);
  }
}

// phase 1: x = emb[Z]; m = act(act(x)@Wi+bi); xjb = act(act(x)@Wj+bj)
__global__ __launch_bounds__(256,2) void k_phase1(
    const int* __restrict__ Z, const float* __restrict__ emb,
    const float* __restrict__ Wi, const float* __restrict__ bi,
    const float* __restrict__ Wj, const float* __restrict__ bj,
    float* __restrict__ x_g, float* __restrict__ m_g, float* __restrict__ xjb_g, int N){
  __shared__ float abuf[32*128];
  __shared__ unsigned short Wl[128*128];
  int tid = threadIdx.x, r0 = (tid>>5)*4, f0 = (tid&31)*4, rbase = blockIdx.x*32;
  float acc[4][4];
  #pragma unroll
  for (int r=0;r<4;++r){
    int row = rbase + r0 + r;
    float4 v = make_float4(0.f,0.f,0.f,0.f);
    if (row < N){
      int z = Z[row];
      v = *(const float4*)(emb + (size_t)z*128 + f0);
      *(float4*)(x_g + (size_t)row*128 + f0) = v;
    }
    float4 av; av.x=actf(v.x); av.y=actf(v.y); av.z=actf(v.z); av.w=actf(v.w);
    *(float4*)(abuf + (r0+r)*128 + f0) = av;
  }
  stage_w(Wi, Wl, tid);
  __syncthreads();
  mm_core(abuf, Wl, r0, f0, acc);
  {
    float4 bv = *(const float4*)(bi + f0);
    #pragma unroll
    for (int r=0;r<4;++r){
      int row = rbase + r0 + r;
      if (row < N){
        float4 ov;
        ov.x=actf(acc[r][0]+bv.x); ov.y=actf(acc[r][1]+bv.y);
        ov.z=actf(acc[r][2]+bv.z); ov.w=actf(acc[r][3]+bv.w);
        *(float4*)(m_g + (size_t)row*128 + f0) = ov;
      }
    }
  }
  __syncthreads();
  stage_w(Wj, Wl, tid);
  __syncthreads();
  mm_core(abuf, Wl, r0, f0, acc);
  {
    float4 bv = *(const float4*)(bj + f0);
    #pragma unroll
    for (int r=0;r<4;++r){
      int row = rbase + r0 + r;
      if (row < N){
        float4 ov;
        ov.x=actf(acc[r][0]+bv.x); ov.y=actf(acc[r][1]+bv.y);
        ov.z=actf(acc[r][2]+bv.z); ov.w=actf(acc[r][3]+bv.w);
        *(float4*)(xjb_g + (size_t)row*128 + f0) = ov;
      }
    }
  }
}

// phase 2: fused per-block row-local chain (unchanged from round 3)
template<int HASNEXT, int NH>
__global__ __launch_bounds__(256,2) void k_phase2(
    float* __restrict__ m_g, float* __restrict__ x_g, float* __restrict__ xjb_g,
    const float* __restrict__ riW1, const float* __restrict__ rib1,
    const float* __restrict__ riW2, const float* __restrict__ rib2,
    const float* __restrict__ dW, const float* __restrict__ db, const float* __restrict__ u,
    const float* __restrict__ raW1, const float* __restrict__ rab1,
    const float* __restrict__ raW2, const float* __restrict__ rab2,
    const float* __restrict__ roW1, const float* __restrict__ rob1,
    const float* __restrict__ roW2, const float* __restrict__ rob2,
    const float* __restrict__ outW,
    const float* __restrict__ WiN, const float* __restrict__ biN,
    const float* __restrict__ WjN, const float* __restrict__ bjN,
    float* __restrict__ Ea, float* __restrict__ Qa,
    float* __restrict__ last2, float* __restrict__ nh, int N){
  __shared__ float xbuf[32*128];
  __shared__ float bufA[32*128];
  __shared__ float bufB[32*128];
  __shared__ unsigned short Wl[128*128];
  int tid = threadIdx.x, r0 = (tid>>5)*4, f0 = (tid&31)*4, rbase = blockIdx.x*32;
  float acc[4][4];

  #pragma unroll
  for (int r=0;r<4;++r){
    int row = rbase + r0 + r;
    float4 v = make_float4(0.f,0.f,0.f,0.f);
    if (row < N) v = *(const float4*)(m_g + (size_t)row*128 + f0);
    *(float4*)(bufA + (r0+r)*128 + f0) = v;
    float4 av; av.x=actf(v.x); av.y=actf(v.y); av.z=actf(v.z); av.w=actf(v.w);
    *(float4*)(xbuf + (r0+r)*128 + f0) = av;
  }
  for (int l = 0; l < 3; ++l){
    __syncthreads();
    stage_w(riW1 + l*16384, Wl, tid);
    __syncthreads();
    mm_core(xbuf, Wl, r0, f0, acc);
    {
      float4 bv = *(const float4*)(rib1 + l*128 + f0);
      #pragma unroll
      for (int r=0;r<4;++r){
        float* hp = bufB + (r0+r)*128 + f0;
        hp[0]=actf(acc[r][0]+bv.x); hp[1]=actf(acc[r][1]+bv.y);
        hp[2]=actf(acc[r][2]+bv.z); hp[3]=actf(acc[r][3]+bv.w);
      }
    }
    __syncthreads();
    stage_w(riW2 + l*16384, Wl, tid);
    __syncthreads();
    mm_core(bufB, Wl, r0, f0, acc);
    {
      float4 bv = *(const float4*)(rib2 + l*128 + f0);
      #pragma unroll
      for (int r=0;r<4;++r){
        float* mp = bufA + (r0+r)*128 + f0;
        float* ap = xbuf + (r0+r)*128 + f0;
        float n0=mp[0]+acc[r][0]+bv.x, n1=mp[1]+acc[r][1]+bv.y;
        float n2=mp[2]+acc[r][2]+bv.z, n3=mp[3]+acc[r][3]+bv.w;
        mp[0]=n0; mp[1]=n1; mp[2]=n2; mp[3]=n3;
        ap[0]=actf(n0); ap[1]=actf(n1); ap[2]=actf(n2); ap[3]=actf(n3);
      }
    }
  }
  __syncthreads();
  stage_w(dW, Wl, tid);
  __syncthreads();
  mm_core(xbuf, Wl, r0, f0, acc);
  __syncthreads();
  {
    float4 uv = *(const float4*)(u + f0);
    float4 bv = *(const float4*)(db + f0);
    #pragma unroll
    for (int r=0;r<4;++r){
      int row = rbase + r0 + r;
      float4 xv = make_float4(0.f,0.f,0.f,0.f);
      if (row < N) xv = *(const float4*)(x_g + (size_t)row*128 + f0);
      float n0 = uv.x*xv.x + acc[r][0] + bv.x;
      float n1 = uv.y*xv.y + acc[r][1] + bv.y;
      float n2 = uv.z*xv.z + acc[r][2] + bv.z;
      float n3 = uv.w*xv.w + acc[r][3] + bv.w;
      float* xp = xbuf + (r0+r)*128 + f0;
      xp[0]=n0; xp[1]=n1; xp[2]=n2; xp[3]=n3;
      float* ap = bufA + (r0+r)*128 + f0;
      ap[0]=actf(n0); ap[1]=actf(n1); ap[2]=actf(n2); ap[3]=actf(n3);
    }
  }
  for (int l = 0; l < 2; ++l){
    __syncthreads();
    stage_w(raW1 + l*16384, Wl, tid);
    __syncthreads();
    mm_core(bufA, Wl, r0, f0, acc);
    {
      float4 bv = *(const float4*)(rab1 + l*128 + f0);
      #pragma unroll
      for (int r=0;r<4;++r){
        float* hp = bufB + (r0+r)*128 + f0;
        hp[0]=actf(acc[r][0]+bv.x); hp[1]=actf(acc[r][1]+bv.y);
        hp[2]=actf(acc[r][2]+bv.z); hp[3]=actf(acc[r][3]+bv.w);
      }
    }
    __syncthreads();
    stage_w(raW2 + l*16384, Wl, tid);
    __syncthreads();
    mm_core(bufB, Wl, r0, f0, acc);
    {
      float4 bv = *(const float4*)(rab2 + l*128 + f0);
      #pragma unroll
      for (int r=0;r<4;++r){
        int row = rbase + r0 + r;
        float* xp = xbuf + (r0+r)*128 + f0;
        float n0=xp[0]+acc[r][0]+bv.x, n1=xp[1]+acc[r][1]+bv.y;
        float n2=xp[2]+acc[r][2]+bv.z, n3=xp[3]+acc[r][3]+bv.w;
        xp[0]=n0; xp[1]=n1; xp[2]=n2; xp[3]=n3;
        float* ap = bufA + (r0+r)*128 + f0;
        ap[0]=actf(n0); ap[1]=actf(n1); ap[2]=actf(n2); ap[3]=actf(n3);
        if (HASNEXT && l == 1 && row < N){
          float4 ov; ov.x=n0; ov.y=n1; ov.z=n2; ov.w=n3;
          *(float4*)(x_g + (size_t)row*128 + f0) = ov;
        }
      }
    }
  }
  __syncthreads();
  stage_w(roW1, Wl, tid);
  __syncthreads();
  mm_core(bufA, Wl, r0, f0, acc);
  {
    float4 bv = *(const float4*)(rob1 + f0);
    #pragma unroll
    for (int r=0;r<4;++r){
      float* hp = bufB + (r0+r)*128 + f0;
      hp[0]=actf(acc[r][0]+bv.x); hp[1]=actf(acc[r][1]+bv.y);
      hp[2]=actf(acc[r][2]+bv.z); hp[3]=actf(acc[r][3]+bv.w);
    }
  }
  __syncthreads();
  stage_w(roW2, Wl, tid);
  __syncthreads();
  mm_core(bufB, Wl, r0, f0, acc);
  {
    float4 bv = *(const float4*)(rob2 + f0);
    #pragma unroll
    for (int r=0;r<4;++r){
      const float* xp = xbuf + (r0+r)*128 + f0;
      float* ap = bufA + (r0+r)*128 + f0;
      ap[0]=actf(xp[0]+acc[r][0]+bv.x); ap[1]=actf(xp[1]+acc[r][1]+bv.y);
      ap[2]=actf(xp[2]+acc[r][2]+bv.z); ap[3]=actf(xp[3]+acc[r][3]+bv.w);
    }
  }
  __syncthreads();
  if (tid < 64) *(float4*)(bufB + tid*4) = *(const float4*)(outW + tid*4);
  __syncthreads();
  float tpart = 0.f;
  if (tid < 32){
    int row = rbase + tid;
    if (row < N){
      float a0 = 0.f, a1 = 0.f;
      for (int f = 0; f < 128; ++f){
        float a = bufA[tid*128 + f];
        a0 = fmaf(a, bufB[f*2], a0);
        a1 = fmaf(a, bufB[f*2+1], a1);
      }
      Ea[row] += a0;
      Qa[row] += a1;
      float e2 = a0*a0, q2 = a1*a1;
      if (NH){
        float le = last2[row*2], lq = last2[row*2+1];
        tpart = e2/(e2+le+1e-7f) + q2/(q2+lq+1e-7f);
      }
      last2[row*2] = e2; last2[row*2+1] = q2;
    }
  }
  if (NH){
    __syncthreads();
    if (tid < 32) bufB[256 + tid] = tpart;
    __syncthreads();
    if (tid == 0){
      float s = 0.f;
      for (int q = 0; q < 32; ++q) s += bufB[256 + q];
      unsafeAtomicAdd(nh, s);
    }
  }
  if (HASNEXT){
    __syncthreads();
    #pragma unroll
    for (int r=0;r<4;++r){
      float* ap = bufA + (r0+r)*128 + f0;
      const float* xp = xbuf + (r0+r)*128 + f0;
      ap[0]=actf(xp[0]); ap[1]=actf(xp[1]); ap[2]=actf(xp[2]); ap[3]=actf(xp[3]);
    }
    stage_w(WiN, Wl, tid);
    __syncthreads();
    mm_core(bufA, Wl, r0, f0, acc);
    {
      float4 bv = *(const float4*)(biN + f0);
      #pragma unroll
      for (int r=0;r<4;++r){
        int row = rbase + r0 + r;
        if (row < N){
          float4 ov;
          ov.x=actf(acc[r][0]+bv.x); ov.y=actf(acc[r][1]+bv.y);
          ov.z=actf(acc[r][2]+bv.z); ov.w=actf(acc[r][3]+bv.w);
          *(float4*)(m_g + (size_t)row*128 + f0) = ov;
        }
      }
    }
    __syncthreads();
    stage_w(WjN, Wl, tid);
    __syncthreads();
    mm_core(bufA, Wl, r0, f0, acc);
    {
      float4 bv = *(const float4*)(bjN + f0);
      #pragma unroll
      for (int r=0;r<4;++r){
        int row = rbase + r0 + r;
        if (row < N){
          float4 ov;
          ov.x=actf(acc[r][0]+bv.x); ov.y=actf(acc[r][1]+bv.y);
          ov.z=actf(acc[r][2]+bv.z); ov.w=actf(acc[r][3]+bv.w);
          *(float4*)(xjb_g + (size_t)row*128 + f0) = ov;
        }
      }
    }
  }
}

__global__ __launch_bounds__(256) void k_final(
    const int* __restrict__ Z, const float* __restrict__ Ea, const float* __restrict__ Qa,
    const float* __restrict__ Es, const float* __restrict__ Eh,
    const float* __restrict__ Qs, const float* __restrict__ Qh,
    const float* __restrict__ nh, float* __restrict__ out, int N, int P){
  int n = blockIdx.x*256 + threadIdx.x;
  if (n < N){
    int z = Z[n];
    out[n]   = Es[z]*Ea[n] + Eh[z];
    out[N+n] = Qs[z]*Qa[n] + Qh[z];
  }
  if (blockIdx.x == 0 && threadIdx.x == 0)
    out[(size_t)2*N + P] = nh[0] / (2.f * (float)N);
}

extern "C" void kernel_launch(void* const* d_in, const int* in_sizes, int n_in,
                              void* d_out, int out_size, void* d_ws, size_t ws_size,
                              hipStream_t stream){
  const int N = in_sizes[0];
  const int P = in_sizes[2];
  const int F = 128, NRI = 3, NRA = 2;

  const int* Z      = (const int*)d_in[0];
  const float* R    = (const float*)d_in[1];
  const int* idx_i  = (const int*)d_in[2];
  const int* idx_j  = (const int*)d_in[3];
  const float* emb  = (const float*)d_in[4];
  const float* cent = (const float*)d_in[5];
  const float* wid  = (const float*)d_in[6];
  const float* k2f  = (const float*)d_in[7];
  const float* Wi   = (const float*)d_in[8];  const float* bi   = (const float*)d_in[9];
  const float* Wj   = (const float*)d_in[10]; const float* bj   = (const float*)d_in[11];
  const float* riW1 = (const float*)d_in[12]; const float* rib1 = (const float*)d_in[13];
  const float* riW2 = (const float*)d_in[14]; const float* rib2 = (const float*)d_in[15];
  const float* dWp  = (const float*)d_in[16]; const float* dbp  = (const float*)d_in[17];
  const float* u    = (const float*)d_in[18];
  const float* raW1 = (const float*)d_in[19]; const float* rab1 = (const float*)d_in[20];
  const float* raW2 = (const float*)d_in[21]; const float* rab2 = (const float*)d_in[22];
  const float* roW1 = (const float*)d_in[23]; const float* rob1 = (const float*)d_in[24];
  const float* roW2 = (const float*)d_in[25]; const float* rob2 = (const float*)d_in[26];
  const float* outW = (const float*)d_in[27];
  const float* Es   = (const float*)d_in[28]; const float* Eh   = (const float*)d_in[29];
  const float* Qs   = (const float*)d_in[30]; const float* Qh   = (const float*)d_in[31];

  char* ws = (char*)d_ws;
  size_t off = 0;
  float* DijF  = (float*)(ws + off); off += (size_t)P*4;
  float* D_s   = (float*)(ws + off); off += (size_t)P*4;
  int*   i_s   = (int*)  (ws + off); off += (size_t)P*4;
  int*   j_s   = (int*)  (ws + off); off += (size_t)P*4;
  unsigned short* rbf_s = (unsigned short*)(ws + off); off += (size_t)P*64*2;
  unsigned short* k2fP  = (unsigned short*)(ws + off); off += (size_t)5*16*64*8*2;
  float* x     = (float*)(ws + off); off += (size_t)N*F*4;
  float* xjb   = (float*)(ws + off); off += (size_t)N*F*4;
  float* m     = (float*)(ws + off); off += (size_t)N*F*4;
  float* last2 = (float*)(ws + off); off += (size_t)N*2*4;
  float* Ea    = (float*)(ws + off); off += (size_t)N*4;   // zero region start
  float* Qa    = (float*)(ws + off); off += (size_t)N*4;
  float* nh    = (float*)(ws + off); off += 256;
  int*   counts= (int*)  (ws + off); off += (size_t)N*4;   // zero region end
  int*   starts= (int*)  (ws + off); off += (size_t)(N+1)*4;
  int*   cursor= (int*)  (ws + off); off += (size_t)N*4;

  float* outF = (float*)d_out;
  float* Dout = outF + (size_t)2*N;

  const int nzero = 3*N + 64;
  k_zero<<<dim3((nzero+255)/256), dim3(256), 0, stream>>>(Ea, nzero);
  k_dij_count<<<dim3((P+255)/256), dim3(256), 0, stream>>>(R, idx_i, idx_j, DijF, Dout, counts, P);
  k_scan<<<dim3(1), dim3(256), 0, stream>>>(counts, starts, cursor, N);
  k_scatter<<<dim3((P+255)/256), dim3(256), 0, stream>>>(idx_i, idx_j, DijF, cursor, i_s, j_s, D_s, P);
  k_rbf<<<dim3((P*64+255)/256), dim3(256), 0, stream>>>(D_s, cent, wid, rbf_s, P);
  k_prep<<<dim3(20), dim3(256), 0, stream>>>(k2f, k2fP);

  const int mmg = (N + 31)/32;
  k_phase1<<<dim3(mmg), dim3(256), 0, stream>>>(Z, emb, Wi, bi, Wj, bj, x, m, xjb, N);

  const int pmg = (P + 511)/512;
  for (int b = 0; b < 5; ++b){
    k_pairmsg2<<<dim3(pmg), dim3(256), 0, stream>>>(rbf_s, k2fP + (size_t)b*16*64*8,
                                                    i_s, j_s, xjb, m, P);
    const float* a_riW1 = riW1 + (size_t)b*NRI*F*F;
    const float* a_rib1 = rib1 + (size_t)b*NRI*F;
    const float* a_riW2 = riW2 + (size_t)b*NRI*F*F;
    const float* a_rib2 = rib2 + (size_t)b*NRI*F;
    const float* a_dW   = dWp  + (size_t)b*F*F;
    const float* a_db   = dbp  + (size_t)b*F;
    const float* a_u    = u    + (size_t)b*F;
    const float* a_raW1 = raW1 + (size_t)b*NRA*F*F;
    const float* a_rab1 = rab1 + (size_t)b*NRA*F;
    const float* a_raW2 = raW2 + (size_t)b*NRA*F*F;
    const float* a_rab2 = rab2 + (size_t)b*NRA*F;
    const float* a_roW1 = roW1 + (size_t)b*F*F;
    const float* a_rob1 = rob1 + (size_t)b*F;
    const float* a_roW2 = roW2 + (size_t)b*F*F;
    const float* a_rob2 = rob2 + (size_t)b*F;
    const float* a_outW = outW + (size_t)b*F*2;
    int bn = (b < 4) ? (b+1) : 4;
    const float* a_WiN = Wi + (size_t)bn*F*F; const float* a_biN = bi + (size_t)bn*F;
    const float* a_WjN = Wj + (size_t)bn*F*F; const float* a_bjN = bj + (size_t)bn*F;
    if (b == 0){
      k_phase2<1,0><<<dim3(mmg), dim3(256), 0, stream>>>(m, x, xjb,
        a_riW1, a_rib1, a_riW2, a_rib2, a_dW, a_db, a_u,
        a_raW1, a_rab1, a_raW2, a_rab2, a_roW1, a_rob1, a_roW2, a_rob2,
        a_outW, a_WiN, a_biN, a_WjN, a_bjN, Ea, Qa, last2, nh, N);
    } else if (b < 4){
      k_phase2<1,1><<<dim3(mmg), dim3(256), 0, stream>>>(m, x, xjb,
        a_riW1, a_rib1, a_riW2, a_rib2, a_dW, a_db, a_u,
        a_raW1, a_rab1, a_raW2, a_rab2, a_roW1, a_rob1, a_roW2, a_rob2,
        a_outW, a_WiN, a_biN, a_WjN, a_bjN, Ea, Qa, last2, nh, N);
    } else {
      k_phase2<0,1><<<dim3(mmg), dim3(256), 0, stream>>>(m, x, xjb,
        a_riW1, a_rib1, a_riW2, a_rib2, a_dW, a_db, a_u,
        a_raW1, a_rab1, a_raW2, a_rab2, a_roW1, a_rob1, a_roW2, a_rob2,
        a_outW, a_WiN, a_biN, a_WjN, a_bjN, Ea, Qa, last2, nh, N);
    }
  }
  k_final<<<dim3((N+255)/256), dim3(256), 0, stream>>>(Z, Ea, Qa, Es, Eh, Qs, Qh, nh, outF, N, P);
}

// Round 7
// 935.680 us; speedup vs baseline: 5.2776x; 1.8307x over previous
//
#include <hip/hip_runtime.h>

typedef __attribute__((ext_vector_type(8))) short bfrag;   // 8 bf16 (4 VGPRs)
typedef __attribute__((ext_vector_type(4))) float ffrag;   // 4 fp32

__device__ __forceinline__ unsigned short f2b(float f){
  unsigned int u = __float_as_uint(f);
  return (unsigned short)((u + 0x7FFFu + ((u >> 16) & 1u)) >> 16);
}
// shifted softplus via v_exp/v_log (both base-2 on gfx950):
// max(x,0) + log2(1 + 2^(-|x|*log2e))*ln2 - ln2
__device__ __forceinline__ float actf(float v){
  float e = __builtin_amdgcn_exp2f(-fabsf(v)*1.44269504088896341f);
  return fmaxf(v, 0.f) + __builtin_amdgcn_logf(1.f + e)*0.69314718055994531f - 0.69314718055994531f;
}

// ---------- small utility kernels ----------
__global__ __launch_bounds__(256) void k_zero(float* p, int n){
  int i = blockIdx.x*256 + threadIdx.x;
  if (i < n) p[i] = 0.f;
}

__global__ __launch_bounds__(256) void k_dij_count(
    const float* __restrict__ R, const int* __restrict__ idx_i, const int* __restrict__ idx_j,
    float* __restrict__ DijF, float* __restrict__ Dout, int* __restrict__ counts, int P){
  int p = blockIdx.x*256 + threadIdx.x;
  if (p >= P) return;
  int i = idx_i[p], j = idx_j[p];
  float dx = R[i*3+0] - R[j*3+0];
  float dy = R[i*3+1] - R[j*3+1];
  float dz = R[i*3+2] - R[j*3+2];
  float D = sqrtf(fmaxf(dx*dx + dy*dy + dz*dz, 0.f));
  DijF[p] = D;
  Dout[p] = D;
  atomicAdd(&counts[i], 1);
}

__global__ __launch_bounds__(256) void k_scan(const int* __restrict__ counts,
    int* __restrict__ starts, int* __restrict__ cursor, int N){
  __shared__ int buf[256];
  __shared__ int carryS;
  int tid = threadIdx.x;
  if (tid == 0) carryS = 0;
  __syncthreads();
  for (int base = 0; base < N; base += 256){
    int idx = base + tid;
    int v = (idx < N) ? counts[idx] : 0;
    buf[tid] = v;
    __syncthreads();
    for (int off = 1; off < 256; off <<= 1){
      int t = (tid >= off) ? buf[tid-off] : 0;
      __syncthreads();
      buf[tid] += t;
      __syncthreads();
    }
    int excl = carryS + buf[tid] - v;
    if (idx < N){ starts[idx] = excl; cursor[idx] = excl; }
    __syncthreads();
    if (tid == 255) carryS += buf[255];
    __syncthreads();
  }
  if (tid == 0) starts[N] = carryS;
}

__global__ __launch_bounds__(256) void k_scatter(const int* __restrict__ idx_i,
    const int* __restrict__ idx_j, const float* __restrict__ DijF,
    int* __restrict__ cursor, int* __restrict__ i_s, int* __restrict__ j_s,
    float* __restrict__ D_s, int P){
  int p = blockIdx.x*256 + threadIdx.x;
  if (p >= P) return;
  int i = idx_i[p];
  int pos = atomicAdd(&cursor[i], 1);
  i_s[pos] = i;
  j_s[pos] = idx_j[p];
  D_s[pos] = DijF[p];
}

__global__ __launch_bounds__(256) void k_rbf(
    const float* __restrict__ D_s, const float* __restrict__ cent, const float* __restrict__ wid,
    unsigned short* __restrict__ rbf_s, int P){
  int gid = blockIdx.x*256 + threadIdx.x;
  if (gid >= P*64) return;
  int t = gid >> 6, k = gid & 63;
  float D = D_s[t];
  float xc = D * 0.1f;
  float cut = 0.f;
  if (xc < 1.f){
    float x3 = xc*xc*xc, x4 = x3*xc, x5 = x4*xc;
    cut = 1.f - 6.f*x5 + 15.f*x4 - 10.f*x3;
  }
  float tt = expf(-D) - cent[k];
  rbf_s[gid] = f2b(cut * expf(-wid[k]*tt*tt));
}

// k2f B-frag prep (k2fP[((b*16 + tile*2 + kh)*64 + l)*8 + j]) -- unchanged, HW-verified
__global__ __launch_bounds__(256) void k_prep(const float* __restrict__ k2f,
    unsigned short* __restrict__ k2fP){
  int gid = blockIdx.x*256 + threadIdx.x;
  if (gid >= 5120) return;
  int l = gid & 63, fr = (gid >> 6) & 15, b = gid >> 10;
  int tile = fr >> 1, kh = fr & 1;
  const float* src = k2f + (size_t)b*64*128;
  int n = tile*16 + (l & 15);
  int kbase = kh*32 + (l >> 4)*8;
  ushort4 o0, o1;
  o0.x = f2b(src[(kbase+0)*128+n]); o0.y = f2b(src[(kbase+1)*128+n]);
  o0.z = f2b(src[(kbase+2)*128+n]); o0.w = f2b(src[(kbase+3)*128+n]);
  o1.x = f2b(src[(kbase+4)*128+n]); o1.y = f2b(src[(kbase+5)*128+n]);
  o1.z = f2b(src[(kbase+6)*128+n]); o1.w = f2b(src[(kbase+7)*128+n]);
  ushort4* dst = (ushort4*)(k2fP + (size_t)gid*8);
  dst[0] = o0; dst[1] = o1;
}

// Repack a family of [128x128] fp32 matrices into B-frag bf16 order inside WBall.
// slot = (bBase + i/nl)*15 + off + (i%nl)*step ; WBall[slot*16384 + (fr*64+l)*8 + j]
// value = W[k0*32 + (l>>4)*8 + j][T*16 + (l&15)], fr = T*4 + k0.
__global__ __launch_bounds__(256) void k_prepW(const float* __restrict__ src,
    unsigned short* __restrict__ WBall, int nmat, int nl, int off, int step, int bBase){
  int gid = blockIdx.x*256 + threadIdx.x;
  if (gid >= nmat*2048) return;
  int i = gid >> 11, r = gid & 2047;
  int fr = r >> 6, l = r & 63;
  int T = fr >> 2, k0 = fr & 3;
  int n = T*16 + (l & 15);
  int kbase = k0*32 + (l >> 4)*8;
  int slot = (bBase + i/nl)*15 + off + (i % nl)*step;
  const float* S = src + (size_t)i*16384;
  unsigned short* D = WBall + ((size_t)slot*2048 + r)*8;
  ushort4 o0, o1;
  o0.x=f2b(S[(kbase+0)*128+n]); o0.y=f2b(S[(kbase+1)*128+n]);
  o0.z=f2b(S[(kbase+2)*128+n]); o0.w=f2b(S[(kbase+3)*128+n]);
  o1.x=f2b(S[(kbase+4)*128+n]); o1.y=f2b(S[(kbase+5)*128+n]);
  o1.z=f2b(S[(kbase+6)*128+n]); o1.w=f2b(S[(kbase+7)*128+n]);
  ((ushort4*)D)[0]=o0; ((ushort4*)D)[1]=o1;
}

// outW[b] [128x2] -> B-frags padded to 16 cols: outWB[b*2048 + (k0*64+l)*8 + j]
__global__ __launch_bounds__(256) void k_prepO(const float* __restrict__ outW,
    unsigned short* __restrict__ outWB){
  int gid = blockIdx.x*256 + threadIdx.x;
  if (gid >= 5*256) return;
  int b = gid >> 8, r = gid & 255;
  int l = r & 63;
  int col = l & 15;
  int k0 = r >> 6;
  int kbase = k0*32 + (l >> 4)*8;
  ushort4 o0 = {0,0,0,0}, o1 = {0,0,0,0};
  if (col < 2){
    const float* S = outW + (size_t)b*256;
    o0.x=f2b(S[(kbase+0)*2+col]); o0.y=f2b(S[(kbase+1)*2+col]);
    o0.z=f2b(S[(kbase+2)*2+col]); o0.w=f2b(S[(kbase+3)*2+col]);
    o1.x=f2b(S[(kbase+4)*2+col]); o1.y=f2b(S[(kbase+5)*2+col]);
    o1.z=f2b(S[(kbase+6)*2+col]); o1.w=f2b(S[(kbase+7)*2+col]);
  }
  unsigned short* D = outWB + ((size_t)b*256 + r)*8;
  ((ushort4*)D)[0]=o0; ((ushort4*)D)[1]=o1;
}

// ---------- MFMA 16-row tile machinery ----------
// tile: bf16 [16][136]; WB: one prepacked matrix (16384 ushorts). Wave w computes
// col-tiles T=w*4+tt. C[tt] = tile(16x128) @ W[:, T*16..T*16+16).
__device__ __forceinline__ void mmtile(const unsigned short* tile,
    const unsigned short* __restrict__ WB, int w, int l, ffrag C[4]){
  int m = l & 15, q = l >> 4;
  bfrag A[4];
  #pragma unroll
  for (int k0 = 0; k0 < 4; ++k0)
    A[k0] = *(const bfrag*)(tile + m*136 + k0*32 + q*8);
  #pragma unroll
  for (int tt = 0; tt < 4; ++tt){
    ffrag c = {0.f,0.f,0.f,0.f};
    const bfrag* bp = (const bfrag*)(WB + (((w*4+tt)*4)*64 + l)*8);
    #pragma unroll
    for (int k0 = 0; k0 < 4; ++k0)
      c = __builtin_amdgcn_mfma_f32_16x16x32_bf16(A[k0], bp[k0*64], c, 0, 0, 0);
    C[tt] = c;
  }
}

// phase1: x = emb[Z]; m_g = act(act(x)@Wi0+bi0); xjb = act(act(x)@Wj0+bj0)
__global__ __launch_bounds__(128) void k_phase1m(
    const int* __restrict__ Z, const float* __restrict__ emb,
    const unsigned short* __restrict__ WB45,  // slots 13/14 of b=4 hold Wi[0]/Wj[0]
    const float* __restrict__ bi0, const float* __restrict__ bj0,
    float* __restrict__ x_g, float* __restrict__ m_g, float* __restrict__ xjb_g, int N){
  __shared__ unsigned short tile[16*136];
  int tid = threadIdx.x, w = tid >> 6, l = tid & 63;
  int m = l & 15, q = l >> 4, rbase = blockIdx.x*16;
  #pragma unroll
  for (int r = 0; r < 4; ++r){
    int row = rbase + q*4 + r;
    int z = Z[row];
    #pragma unroll
    for (int tt = 0; tt < 4; ++tt){
      int c = (w*4+tt)*16 + m;
      float v = emb[(size_t)z*128 + c];
      x_g[(size_t)row*128 + c] = v;
      tile[(q*4+r)*136 + c] = f2b(actf(v));
    }
  }
  __syncthreads();
  ffrag C[4];
  mmtile(tile, WB45 + 13*16384, w, l, C);
  #pragma unroll
  for (int tt = 0; tt < 4; ++tt){
    int c = (w*4+tt)*16 + m;
    float bb = bi0[c];
    #pragma unroll
    for (int r = 0; r < 4; ++r)
      m_g[(size_t)(rbase + q*4 + r)*128 + c] = actf(C[tt][r] + bb);
  }
  mmtile(tile, WB45 + 14*16384, w, l, C);
  #pragma unroll
  for (int tt = 0; tt < 4; ++tt){
    int c = (w*4+tt)*16 + m;
    float bb = bj0[c];
    #pragma unroll
    for (int r = 0; r < 4; ++r)
      xjb_g[(size_t)(rbase + q*4 + r)*128 + c] = actf(C[tt][r] + bb);
  }
}

// MFMA pair-message (unchanged from round 4, HW-verified)
__global__ __launch_bounds__(256) void k_pairmsg2(
    const unsigned short* __restrict__ rbf_s, const unsigned short* __restrict__ k2fP,
    const int* __restrict__ i_s, const int* __restrict__ j_s,
    const float* __restrict__ xj, float* __restrict__ m_g, int P){
  __shared__ float G[4][16*130];
  int tid = threadIdx.x, w = tid >> 6, l = tid & 63;
  float* Gw = &G[w][0];
  bfrag B[8][2];
  #pragma unroll
  for (int t = 0; t < 8; ++t){
    #pragma unroll
    for (int kh = 0; kh < 2; ++kh)
      B[t][kh] = *(const bfrag*)(k2fP + (size_t)((t*2+kh)*64 + l)*8);
  }
  int wstart = (blockIdx.x*4 + w)*128;
  int row16 = l & 15, quad = l >> 4;
  float a0 = 0.f, a1 = 0.f;
  int iCur = -1;
  for (int bt = wstart; bt < wstart + 128; bt += 16){
    if (bt >= P) break;
    int arow = bt + row16;
    bfrag A0 = {0,0,0,0,0,0,0,0}, A1 = {0,0,0,0,0,0,0,0};
    if (arow < P){
      A0 = *(const bfrag*)(rbf_s + (size_t)arow*64 + quad*8);
      A1 = *(const bfrag*)(rbf_s + (size_t)arow*64 + 32 + quad*8);
    }
    #pragma unroll
    for (int t = 0; t < 8; ++t){
      ffrag C = {0.f,0.f,0.f,0.f};
      C = __builtin_amdgcn_mfma_f32_16x16x32_bf16(A0, B[t][0], C, 0, 0, 0);
      C = __builtin_amdgcn_mfma_f32_16x16x32_bf16(A1, B[t][1], C, 0, 0, 0);
      #pragma unroll
      for (int r = 0; r < 4; ++r)
        Gw[(quad*4+r)*130 + t*16 + row16] = C[r];
    }
    int tmax = P - bt; if (tmax > 16) tmax = 16;
    for (int k = 0; k < 16; ++k){
      if (k >= tmax) break;
      int t = bt + k;
      int i = i_s[t], j = j_s[t];
      if (i != iCur){
        if (iCur >= 0){
          unsafeAtomicAdd(&m_g[(size_t)iCur*128 + 2*l],     a0);
          unsafeAtomicAdd(&m_g[(size_t)iCur*128 + 2*l + 1], a1);
        }
        iCur = i; a0 = 0.f; a1 = 0.f;
      }
      float2 xv = *(const float2*)(xj + (size_t)j*128 + 2*l);
      float g0 = Gw[k*130 + 2*l], g1 = Gw[k*130 + 2*l + 1];
      a0 = fmaf(g0, xv.x, a0);
      a1 = fmaf(g1, xv.y, a1);
    }
  }
  if (iCur >= 0){
    unsafeAtomicAdd(&m_g[(size_t)iCur*128 + 2*l],     a0);
    unsafeAtomicAdd(&m_g[(size_t)iCur*128 + 2*l + 1], a1);
  }
}

// ---------- phase 2: full per-block chain on MFMA ----------
// Slots in WBb: riW1[l]=2l, riW2[l]=2l+1, dW=6, raW1[l]=7+2l, raW2[l]=8+2l,
// roW1=11, roW2=12, WiN=13, WjN=14.
template<int HASNEXT, int NH>
__global__ __launch_bounds__(128) void k_phase2m(
    float* __restrict__ m_g, float* __restrict__ x_g, float* __restrict__ xjb_g,
    const unsigned short* __restrict__ WBb,
    const float* __restrict__ rib1, const float* __restrict__ rib2,
    const float* __restrict__ db, const float* __restrict__ u,
    const float* __restrict__ rab1, const float* __restrict__ rab2,
    const float* __restrict__ rob1, const float* __restrict__ rob2,
    const float* __restrict__ biN, const float* __restrict__ bjN,
    const unsigned short* __restrict__ outWBb,
    float* __restrict__ Ea, float* __restrict__ Qa,
    float* __restrict__ last2, float* __restrict__ nh, int N){
  __shared__ unsigned short tiles[2][16*136];
  int tid = threadIdx.x, w = tid >> 6, l = tid & 63;
  int m = l & 15, q = l >> 4, rbase = blockIdx.x*16;
  ffrag mC[4], xC[4], C[4];
  int cur = 0;

  // S0: load m -> mC; tiles[0] = act(m)
  #pragma unroll
  for (int tt = 0; tt < 4; ++tt){
    int c = (w*4+tt)*16 + m;
    #pragma unroll
    for (int r = 0; r < 4; ++r){
      float v = m_g[(size_t)(rbase + q*4 + r)*128 + c];
      mC[tt][r] = v;
      tiles[0][(q*4+r)*136 + c] = f2b(actf(v));
    }
  }
  // NRI residuals on m
  #pragma unroll 1
  for (int li = 0; li < 3; ++li){
    __syncthreads();
    mmtile(tiles[cur], WBb + (size_t)(2*li)*16384, w, l, C);
    #pragma unroll
    for (int tt = 0; tt < 4; ++tt){
      int c = (w*4+tt)*16 + m;
      float bb = rib1[li*128 + c];
      #pragma unroll
      for (int r = 0; r < 4; ++r)
        tiles[1-cur][(q*4+r)*136 + c] = f2b(actf(C[tt][r] + bb));
    }
    cur ^= 1;
    __syncthreads();
    mmtile(tiles[cur], WBb + (size_t)(2*li+1)*16384, w, l, C);
    #pragma unroll
    for (int tt = 0; tt < 4; ++tt){
      int c = (w*4+tt)*16 + m;
      float bb = rib2[li*128 + c];
      #pragma unroll
      for (int r = 0; r < 4; ++r){
        float nv = mC[tt][r] + C[tt][r] + bb;
        mC[tt][r] = nv;
        tiles[1-cur][(q*4+r)*136 + c] = f2b(actf(nv));
      }
    }
    cur ^= 1;
  }
  // x-update: x = u*x + act(m)@dW + db
  __syncthreads();
  mmtile(tiles[cur], WBb + (size_t)6*16384, w, l, C);
  #pragma unroll
  for (int tt = 0; tt < 4; ++tt){
    int c = (w*4+tt)*16 + m;
    float uu = u[c], bb = db[c];
    #pragma unroll
    for (int r = 0; r < 4; ++r){
      float xv = x_g[(size_t)(rbase + q*4 + r)*128 + c];
      float nv = uu*xv + C[tt][r] + bb;
      xC[tt][r] = nv;
      tiles[1-cur][(q*4+r)*136 + c] = f2b(actf(nv));
    }
  }
  cur ^= 1;
  // NRA residuals on x
  #pragma unroll 1
  for (int li = 0; li < 2; ++li){
    __syncthreads();
    mmtile(tiles[cur], WBb + (size_t)(7+2*li)*16384, w, l, C);
    #pragma unroll
    for (int tt = 0; tt < 4; ++tt){
      int c = (w*4+tt)*16 + m;
      float bb = rab1[li*128 + c];
      #pragma unroll
      for (int r = 0; r < 4; ++r)
        tiles[1-cur][(q*4+r)*136 + c] = f2b(actf(C[tt][r] + bb));
    }
    cur ^= 1;
    __syncthreads();
    mmtile(tiles[cur], WBb + (size_t)(8+2*li)*16384, w, l, C);
    #pragma unroll
    for (int tt = 0; tt < 4; ++tt){
      int c = (w*4+tt)*16 + m;
      float bb = rab2[li*128 + c];
      #pragma unroll
      for (int r = 0; r < 4; ++r){
        float nv = xC[tt][r] + C[tt][r] + bb;
        xC[tt][r] = nv;
        tiles[1-cur][(q*4+r)*136 + c] = f2b(actf(nv));
        if (HASNEXT && li == 1)
          x_g[(size_t)(rbase + q*4 + r)*128 + c] = nv;
      }
    }
    cur ^= 1;
  }
  // cur tile now holds ax = act(x_final)
  if (HASNEXT){
    __syncthreads();
    mmtile(tiles[cur], WBb + (size_t)13*16384, w, l, C);
    #pragma unroll
    for (int tt = 0; tt < 4; ++tt){
      int c = (w*4+tt)*16 + m;
      float bb = biN[c];
      #pragma unroll
      for (int r = 0; r < 4; ++r)
        m_g[(size_t)(rbase + q*4 + r)*128 + c] = actf(C[tt][r] + bb);
    }
    mmtile(tiles[cur], WBb + (size_t)14*16384, w, l, C);
    #pragma unroll
    for (int tt = 0; tt < 4; ++tt){
      int c = (w*4+tt)*16 + m;
      float bb = bjN[c];
      #pragma unroll
      for (int r = 0; r < 4; ++r)
        xjb_g[(size_t)(rbase + q*4 + r)*128 + c] = actf(C[tt][r] + bb);
    }
  }
  // output block: h = act(ax@roW1+rob1); o = x + h@roW2+rob2; tile = act(o)
  __syncthreads();
  mmtile(tiles[cur], WBb + (size_t)11*16384, w, l, C);
  #pragma unroll
  for (int tt = 0; tt < 4; ++tt){
    int c = (w*4+tt)*16 + m;
    float bb = rob1[c];
    #pragma unroll
    for (int r = 0; r < 4; ++r)
      tiles[1-cur][(q*4+r)*136 + c] = f2b(actf(C[tt][r] + bb));
  }
  cur ^= 1;
  __syncthreads();
  mmtile(tiles[cur], WBb + (size_t)12*16384, w, l, C);
  #pragma unroll
  for (int tt = 0; tt < 4; ++tt){
    int c = (w*4+tt)*16 + m;
    float bb = rob2[c];
    #pragma unroll
    for (int r = 0; r < 4; ++r){
      float ov = xC[tt][r] + C[tt][r] + bb;
      tiles[1-cur][(q*4+r)*136 + c] = f2b(actf(ov));
    }
  }
  cur ^= 1;
  // head: out = act(o) @ outW (padded to 16 cols)
  __syncthreads();
  if (w == 0){
    bfrag A[4];
    #pragma unroll
    for (int k0 = 0; k0 < 4; ++k0)
      A[k0] = *(const bfrag*)(&tiles[cur][0] + m*136 + k0*32 + q*8);
    ffrag Ch = {0.f,0.f,0.f,0.f};
    #pragma unroll
    for (int k0 = 0; k0 < 4; ++k0){
      bfrag B = *(const bfrag*)(outWBb + (size_t)(k0*64 + l)*8);
      Ch = __builtin_amdgcn_mfma_f32_16x16x32_bf16(A[k0], B, Ch, 0, 0, 0);
    }
    int col = m;
    if (col < 2){
      float tp = 0.f;
      #pragma unroll
      for (int r = 0; r < 4; ++r){
        int row = rbase + q*4 + r;
        float val = Ch[r];
        if (col == 0) Ea[row] += val; else Qa[row] += val;
        float sq = val*val;
        if (NH){
          float lastv = last2[row*2 + col];
          tp += sq/(sq + lastv + 1e-7f);
        }
        last2[row*2 + col] = sq;
      }
      if (NH) unsafeAtomicAdd(nh, tp);
    }
  }
}

__global__ __launch_bounds__(256) void k_final(
    const int* __restrict__ Z, const float* __restrict__ Ea, const float* __restrict__ Qa,
    const float* __restrict__ Es, const float* __restrict__ Eh,
    const float* __restrict__ Qs, const float* __restrict__ Qh,
    const float* __restrict__ nh, float* __restrict__ out, int N, int P){
  int n = blockIdx.x*256 + threadIdx.x;
  if (n < N){
    int z = Z[n];
    out[n]   = Es[z]*Ea[n] + Eh[z];
    out[N+n] = Qs[z]*Qa[n] + Qh[z];
  }
  if (blockIdx.x == 0 && threadIdx.x == 0)
    out[(size_t)2*N + P] = nh[0] / (2.f * (float)N);
}

extern "C" void kernel_launch(void* const* d_in, const int* in_sizes, int n_in,
                              void* d_out, int out_size, void* d_ws, size_t ws_size,
                              hipStream_t stream){
  const int N = in_sizes[0];
  const int P = in_sizes[2];
  const int F = 128;

  const int* Z      = (const int*)d_in[0];
  const float* R    = (const float*)d_in[1];
  const int* idx_i  = (const int*)d_in[2];
  const int* idx_j  = (const int*)d_in[3];
  const float* emb  = (const float*)d_in[4];
  const float* cent = (const float*)d_in[5];
  const float* wid  = (const float*)d_in[6];
  const float* k2f  = (const float*)d_in[7];
  const float* Wi   = (const float*)d_in[8];  const float* bi   = (const float*)d_in[9];
  const float* Wj   = (const float*)d_in[10]; const float* bj   = (const float*)d_in[11];
  const float* riW1 = (const float*)d_in[12]; const float* rib1 = (const float*)d_in[13];
  const float* riW2 = (const float*)d_in[14]; const float* rib2 = (const float*)d_in[15];
  const float* dWp  = (const float*)d_in[16]; const float* dbp  = (const float*)d_in[17];
  const float* u    = (const float*)d_in[18];
  const float* raW1 = (const float*)d_in[19]; const float* rab1 = (const float*)d_in[20];
  const float* raW2 = (const float*)d_in[21]; const float* rab2 = (const float*)d_in[22];
  const float* roW1 = (const float*)d_in[23]; const float* rob1 = (const float*)d_in[24];
  const float* roW2 = (const float*)d_in[25]; const float* rob2 = (const float*)d_in[26];
  const float* outW = (const float*)d_in[27];
  const float* Es   = (const float*)d_in[28]; const float* Eh   = (const float*)d_in[29];
  const float* Qs   = (const float*)d_in[30]; const float* Qh   = (const float*)d_in[31];

  char* ws = (char*)d_ws;
  size_t off = 0;
  float* DijF  = (float*)(ws + off); off += (size_t)P*4;
  float* D_s   = (float*)(ws + off); off += (size_t)P*4;
  int*   i_s   = (int*)  (ws + off); off += (size_t)P*4;
  int*   j_s   = (int*)  (ws + off); off += (size_t)P*4;
  unsigned short* rbf_s = (unsigned short*)(ws + off); off += (size_t)P*64*2;
  unsigned short* k2fP  = (unsigned short*)(ws + off); off += (size_t)5*16*64*8*2;
  unsigned short* WBall = (unsigned short*)(ws + off); off += (size_t)75*16384*2;
  unsigned short* outWB = (unsigned short*)(ws + off); off += (size_t)5*2048*2;
  float* x     = (float*)(ws + off); off += (size_t)N*F*4;
  float* xjb   = (float*)(ws + off); off += (size_t)N*F*4;
  float* m     = (float*)(ws + off); off += (size_t)N*F*4;
  float* last2 = (float*)(ws + off); off += (size_t)N*2*4;
  float* Ea    = (float*)(ws + off); off += (size_t)N*4;   // zero region start
  float* Qa    = (float*)(ws + off); off += (size_t)N*4;
  float* nh    = (float*)(ws + off); off += 256;
  int*   counts= (int*)  (ws + off); off += (size_t)N*4;   // zero region end
  int*   starts= (int*)  (ws + off); off += (size_t)(N+1)*4;
  int*   cursor= (int*)  (ws + off); off += (size_t)N*4;

  float* outF = (float*)d_out;
  float* Dout = outF + (size_t)2*N;

  const int nzero = 3*N + 64;
  k_zero<<<dim3((nzero+255)/256), dim3(256), 0, stream>>>(Ea, nzero);
  k_dij_count<<<dim3((P+255)/256), dim3(256), 0, stream>>>(R, idx_i, idx_j, DijF, Dout, counts, P);
  k_scan<<<dim3(1), dim3(256), 0, stream>>>(counts, starts, cursor, N);
  k_scatter<<<dim3((P+255)/256), dim3(256), 0, stream>>>(idx_i, idx_j, DijF, cursor, i_s, j_s, D_s, P);
  k_rbf<<<dim3((P*64+255)/256), dim3(256), 0, stream>>>(D_s, cent, wid, rbf_s, P);
  k_prep<<<dim3(20), dim3(256), 0, stream>>>(k2f, k2fP);

  // weight prepack: slots riW1[l]=2l riW2[l]=2l+1 dW=6 raW1=7+2l raW2=8+2l roW1=11 roW2=12 WiN=13 WjN=14
  auto prep = [&](const float* src, int nmat, int nl, int offv, int step, int bBase){
    k_prepW<<<dim3((nmat*2048+255)/256), dim3(256), 0, stream>>>(src, WBall, nmat, nl, offv, step, bBase);
  };
  prep(riW1, 15, 3, 0, 2, 0);
  prep(riW2, 15, 3, 1, 2, 0);
  prep(dWp,   5, 1, 6, 0, 0);
  prep(raW1, 10, 2, 7, 2, 0);
  prep(raW2, 10, 2, 8, 2, 0);
  prep(roW1,  5, 1, 11, 0, 0);
  prep(roW2,  5, 1, 12, 0, 0);
  prep(Wi + 16384, 4, 1, 13, 0, 0);   // WiN for b=0..3
  prep(Wi,         1, 1, 13, 0, 4);   // slot [4][13] = Wi[0] (used by phase1)
  prep(Wj + 16384, 4, 1, 14, 0, 0);
  prep(Wj,         1, 1, 14, 0, 4);
  k_prepO<<<dim3(5), dim3(256), 0, stream>>>(outW, outWB);

  const int G16 = (N + 15)/16;   // N=10000 -> 625 exactly
  k_phase1m<<<dim3(G16), dim3(128), 0, stream>>>(Z, emb, WBall + (size_t)4*15*16384,
                                                 bi, bj, x, m, xjb, N);

  const int pmg = (P + 511)/512;
  for (int b = 0; b < 5; ++b){
    k_pairmsg2<<<dim3(pmg), dim3(256), 0, stream>>>(rbf_s, k2fP + (size_t)b*16*64*8,
                                                    i_s, j_s, xjb, m, P);
    const unsigned short* WBb = WBall + (size_t)b*15*16384;
    const float* a_rib1 = rib1 + (size_t)b*3*F;
    const float* a_rib2 = rib2 + (size_t)b*3*F;
    const float* a_db   = dbp  + (size_t)b*F;
    const float* a_u    = u    + (size_t)b*F;
    const float* a_rab1 = rab1 + (size_t)b*2*F;
    const float* a_rab2 = rab2 + (size_t)b*2*F;
    const float* a_rob1 = rob1 + (size_t)b*F;
    const float* a_rob2 = rob2 + (size_t)b*F;
    int bn = (b < 4) ? (b+1) : 0;
    const float* a_biN = bi + (size_t)bn*F;
    const float* a_bjN = bj + (size_t)bn*F;
    const unsigned short* oWB = outWB + (size_t)b*2048;
    if (b == 0){
      k_phase2m<1,0><<<dim3(G16), dim3(128), 0, stream>>>(m, x, xjb, WBb,
        a_rib1, a_rib2, a_db, a_u, a_rab1, a_rab2, a_rob1, a_rob2,
        a_biN, a_bjN, oWB, Ea, Qa, last2, nh, N);
    } else if (b < 4){
      k_phase2m<1,1><<<dim3(G16), dim3(128), 0, stream>>>(m, x, xjb, WBb,
        a_rib1, a_rib2, a_db, a_u, a_rab1, a_rab2, a_rob1, a_rob2,
        a_biN, a_bjN, oWB, Ea, Qa, last2, nh, N);
    } else {
      k_phase2m<0,1><<<dim3(G16), dim3(128), 0, stream>>>(m, x, xjb, WBb,
        a_rib1, a_rib2, a_db, a_u, a_rab1, a_rab2, a_rob1, a_rob2,
        a_biN, a_bjN, oWB, Ea, Qa, last2, nh, N);
    }
  }
  k_final<<<dim3((N+255)/256), dim3(256), 0, stream>>>(Z, Ea, Qa, Es, Eh, Qs, Qh, nh, outF, N, P);
}

// Round 8
// 576.952 us; speedup vs baseline: 8.5591x; 1.6218x over previous
//
#include <hip/hip_runtime.h>

typedef __attribute__((ext_vector_type(8))) short bfrag;   // 8 bf16 (4 VGPRs)
typedef __attribute__((ext_vector_type(4))) float ffrag;   // 4 fp32

__device__ __forceinline__ unsigned short f2b(float f){
  unsigned int u = __float_as_uint(f);
  return (unsigned short)((u + 0x7FFFu + ((u >> 16) & 1u)) >> 16);
}
// shifted softplus via v_exp/v_log (both base-2 on gfx950):
// max(x,0) + log2(1 + 2^(-|x|*log2e))*ln2 - ln2
__device__ __forceinline__ float actf(float v){
  float e = __builtin_amdgcn_exp2f(-fabsf(v)*1.44269504088896341f);
  return fmaxf(v, 0.f) + __builtin_amdgcn_logf(1.f + e)*0.69314718055994531f - 0.69314718055994531f;
}

// ---------- small utility kernels ----------
__global__ __launch_bounds__(256) void k_zero(float* p, int n){
  int i = blockIdx.x*256 + threadIdx.x;
  if (i < n) p[i] = 0.f;
}

__global__ __launch_bounds__(256) void k_dij_count(
    const float* __restrict__ R, const int* __restrict__ idx_i, const int* __restrict__ idx_j,
    float* __restrict__ DijF, float* __restrict__ Dout, int* __restrict__ counts, int P){
  int p = blockIdx.x*256 + threadIdx.x;
  if (p >= P) return;
  int i = idx_i[p], j = idx_j[p];
  float dx = R[i*3+0] - R[j*3+0];
  float dy = R[i*3+1] - R[j*3+1];
  float dz = R[i*3+2] - R[j*3+2];
  float D = sqrtf(fmaxf(dx*dx + dy*dy + dz*dz, 0.f));
  DijF[p] = D;
  Dout[p] = D;
  atomicAdd(&counts[i], 1);
}

__global__ __launch_bounds__(256) void k_scan(const int* __restrict__ counts,
    int* __restrict__ starts, int* __restrict__ cursor, int N){
  __shared__ int buf[256];
  __shared__ int carryS;
  int tid = threadIdx.x;
  if (tid == 0) carryS = 0;
  __syncthreads();
  for (int base = 0; base < N; base += 256){
    int idx = base + tid;
    int v = (idx < N) ? counts[idx] : 0;
    buf[tid] = v;
    __syncthreads();
    for (int off = 1; off < 256; off <<= 1){
      int t = (tid >= off) ? buf[tid-off] : 0;
      __syncthreads();
      buf[tid] += t;
      __syncthreads();
    }
    int excl = carryS + buf[tid] - v;
    if (idx < N){ starts[idx] = excl; cursor[idx] = excl; }
    __syncthreads();
    if (tid == 255) carryS += buf[255];
    __syncthreads();
  }
  if (tid == 0) starts[N] = carryS;
}

__global__ __launch_bounds__(256) void k_scatter(const int* __restrict__ idx_i,
    const int* __restrict__ idx_j, const float* __restrict__ DijF,
    int* __restrict__ cursor, int* __restrict__ i_s, int* __restrict__ j_s,
    float* __restrict__ D_s, int P){
  int p = blockIdx.x*256 + threadIdx.x;
  if (p >= P) return;
  int i = idx_i[p];
  int pos = atomicAdd(&cursor[i], 1);
  i_s[pos] = i;
  j_s[pos] = idx_j[p];
  D_s[pos] = DijF[p];
}

__global__ __launch_bounds__(256) void k_rbf(
    const float* __restrict__ D_s, const float* __restrict__ cent, const float* __restrict__ wid,
    unsigned short* __restrict__ rbf_s, int P){
  int gid = blockIdx.x*256 + threadIdx.x;
  if (gid >= P*64) return;
  int t = gid >> 6, k = gid & 63;
  float D = D_s[t];
  float xc = D * 0.1f;
  float cut = 0.f;
  if (xc < 1.f){
    float x3 = xc*xc*xc, x4 = x3*xc, x5 = x4*xc;
    cut = 1.f - 6.f*x5 + 15.f*x4 - 10.f*x3;
  }
  float tt = expf(-D) - cent[k];
  rbf_s[gid] = f2b(cut * expf(-wid[k]*tt*tt));
}

// k2f B-frag prep -- unchanged, HW-verified
__global__ __launch_bounds__(256) void k_prep(const float* __restrict__ k2f,
    unsigned short* __restrict__ k2fP){
  int gid = blockIdx.x*256 + threadIdx.x;
  if (gid >= 5120) return;
  int l = gid & 63, fr = (gid >> 6) & 15, b = gid >> 10;
  int tile = fr >> 1, kh = fr & 1;
  const float* src = k2f + (size_t)b*64*128;
  int n = tile*16 + (l & 15);
  int kbase = kh*32 + (l >> 4)*8;
  ushort4 o0, o1;
  o0.x = f2b(src[(kbase+0)*128+n]); o0.y = f2b(src[(kbase+1)*128+n]);
  o0.z = f2b(src[(kbase+2)*128+n]); o0.w = f2b(src[(kbase+3)*128+n]);
  o1.x = f2b(src[(kbase+4)*128+n]); o1.y = f2b(src[(kbase+5)*128+n]);
  o1.z = f2b(src[(kbase+6)*128+n]); o1.w = f2b(src[(kbase+7)*128+n]);
  ushort4* dst = (ushort4*)(k2fP + (size_t)gid*8);
  dst[0] = o0; dst[1] = o1;
}

// Repack [128x128] fp32 matrices into B-frag bf16 order -- unchanged
__global__ __launch_bounds__(256) void k_prepW(const float* __restrict__ src,
    unsigned short* __restrict__ WBall, int nmat, int nl, int off, int step, int bBase){
  int gid = blockIdx.x*256 + threadIdx.x;
  if (gid >= nmat*2048) return;
  int i = gid >> 11, r = gid & 2047;
  int fr = r >> 6, l = r & 63;
  int T = fr >> 2, k0 = fr & 3;
  int n = T*16 + (l & 15);
  int kbase = k0*32 + (l >> 4)*8;
  int slot = (bBase + i/nl)*15 + off + (i % nl)*step;
  const float* S = src + (size_t)i*16384;
  unsigned short* D = WBall + ((size_t)slot*2048 + r)*8;
  ushort4 o0, o1;
  o0.x=f2b(S[(kbase+0)*128+n]); o0.y=f2b(S[(kbase+1)*128+n]);
  o0.z=f2b(S[(kbase+2)*128+n]); o0.w=f2b(S[(kbase+3)*128+n]);
  o1.x=f2b(S[(kbase+4)*128+n]); o1.y=f2b(S[(kbase+5)*128+n]);
  o1.z=f2b(S[(kbase+6)*128+n]); o1.w=f2b(S[(kbase+7)*128+n]);
  ((ushort4*)D)[0]=o0; ((ushort4*)D)[1]=o1;
}

// outW[b] [128x2] -> padded B-frags -- unchanged
__global__ __launch_bounds__(256) void k_prepO(const float* __restrict__ outW,
    unsigned short* __restrict__ outWB){
  int gid = blockIdx.x*256 + threadIdx.x;
  if (gid >= 5*256) return;
  int b = gid >> 8, r = gid & 255;
  int l = r & 63;
  int col = l & 15;
  int k0 = r >> 6;
  int kbase = k0*32 + (l >> 4)*8;
  ushort4 o0 = {0,0,0,0}, o1 = {0,0,0,0};
  if (col < 2){
    const float* S = outW + (size_t)b*256;
    o0.x=f2b(S[(kbase+0)*2+col]); o0.y=f2b(S[(kbase+1)*2+col]);
    o0.z=f2b(S[(kbase+2)*2+col]); o0.w=f2b(S[(kbase+3)*2+col]);
    o1.x=f2b(S[(kbase+4)*2+col]); o1.y=f2b(S[(kbase+5)*2+col]);
    o1.z=f2b(S[(kbase+6)*2+col]); o1.w=f2b(S[(kbase+7)*2+col]);
  }
  unsigned short* D = outWB + ((size_t)b*256 + r)*8;
  ((ushort4*)D)[0]=o0; ((ushort4*)D)[1]=o1;
}

// ---------- MFMA tile machinery ----------
// 2-wave form (phase1): wave w covers col-tiles w*4..w*4+3
__device__ __forceinline__ void mmtile(const unsigned short* tile,
    const unsigned short* __restrict__ WB, int w, int l, ffrag C[4]){
  int m = l & 15, q = l >> 4;
  bfrag A[4];
  #pragma unroll
  for (int k0 = 0; k0 < 4; ++k0)
    A[k0] = *(const bfrag*)(tile + m*136 + k0*32 + q*8);
  #pragma unroll
  for (int tt = 0; tt < 4; ++tt){
    ffrag c = {0.f,0.f,0.f,0.f};
    const bfrag* bp = (const bfrag*)(WB + (((w*4+tt)*4)*64 + l)*8);
    #pragma unroll
    for (int k0 = 0; k0 < 4; ++k0)
      c = __builtin_amdgcn_mfma_f32_16x16x32_bf16(A[k0], bp[k0*64], c, 0, 0, 0);
    C[tt] = c;
  }
}

// 4-wave form (phase2): wave w covers col-tiles w*2, w*2+1
__device__ __forceinline__ void mmtile2(const unsigned short* tile,
    const unsigned short* __restrict__ WB, int w, int l, ffrag C[2]){
  int m = l & 15, q = l >> 4;
  bfrag A[4];
  #pragma unroll
  for (int k0 = 0; k0 < 4; ++k0)
    A[k0] = *(const bfrag*)(tile + m*136 + k0*32 + q*8);
  #pragma unroll
  for (int tt = 0; tt < 2; ++tt){
    ffrag c = {0.f,0.f,0.f,0.f};
    const bfrag* bp = (const bfrag*)(WB + (((w*2+tt)*4)*64 + l)*8);
    #pragma unroll
    for (int k0 = 0; k0 < 4; ++k0)
      c = __builtin_amdgcn_mfma_f32_16x16x32_bf16(A[k0], bp[k0*64], c, 0, 0, 0);
    C[tt] = c;
  }
}

// phase1: x = emb[Z]; m_g = act(act(x)@Wi0+bi0); xjb = act(act(x)@Wj0+bj0)
__global__ __launch_bounds__(128) void k_phase1m(
    const int* __restrict__ Z, const float* __restrict__ emb,
    const unsigned short* __restrict__ WB45,  // slots 13/14 of b=4 hold Wi[0]/Wj[0]
    const float* __restrict__ bi0, const float* __restrict__ bj0,
    float* __restrict__ x_g, float* __restrict__ m_g, float* __restrict__ xjb_g, int N){
  __shared__ unsigned short tile[16*136];
  int tid = threadIdx.x, w = tid >> 6, l = tid & 63;
  int m = l & 15, q = l >> 4, rbase = blockIdx.x*16;
  #pragma unroll
  for (int r = 0; r < 4; ++r){
    int row = rbase + q*4 + r;
    int z = Z[row];
    #pragma unroll
    for (int tt = 0; tt < 4; ++tt){
      int c = (w*4+tt)*16 + m;
      float v = emb[(size_t)z*128 + c];
      x_g[(size_t)row*128 + c] = v;
      tile[(q*4+r)*136 + c] = f2b(actf(v));
    }
  }
  __syncthreads();
  ffrag C[4];
  mmtile(tile, WB45 + 13*16384, w, l, C);
  #pragma unroll
  for (int tt = 0; tt < 4; ++tt){
    int c = (w*4+tt)*16 + m;
    float bb = bi0[c];
    #pragma unroll
    for (int r = 0; r < 4; ++r)
      m_g[(size_t)(rbase + q*4 + r)*128 + c] = actf(C[tt][r] + bb);
  }
  mmtile(tile, WB45 + 14*16384, w, l, C);
  #pragma unroll
  for (int tt = 0; tt < 4; ++tt){
    int c = (w*4+tt)*16 + m;
    float bb = bj0[c];
    #pragma unroll
    for (int r = 0; r < 4; ++r)
      xjb_g[(size_t)(rbase + q*4 + r)*128 + c] = actf(C[tt][r] + bb);
  }
}

// MFMA pair-message with batched index/xj prefetch. Assumes each wave's 128
// pairs are fully in range (true when P % 512 == 0; P=320000 -> grid 625 exact).
__global__ __launch_bounds__(256) void k_pairmsg2(
    const unsigned short* __restrict__ rbf_s, const unsigned short* __restrict__ k2fP,
    const int* __restrict__ i_s, const int* __restrict__ j_s,
    const float* __restrict__ xj, float* __restrict__ m_g, int P){
  __shared__ float G[4][16*130];
  int tid = threadIdx.x, w = tid >> 6, l = tid & 63;
  float* Gw = &G[w][0];
  bfrag B[8][2];
  #pragma unroll
  for (int t = 0; t < 8; ++t){
    #pragma unroll
    for (int kh = 0; kh < 2; ++kh)
      B[t][kh] = *(const bfrag*)(k2fP + (size_t)((t*2+kh)*64 + l)*8);
  }
  int wstart = (blockIdx.x*4 + w)*128;
  if (wstart >= P) return;
  int row16 = l & 15, quad = l >> 4;
  float a0 = 0.f, a1 = 0.f;
  int iCur = -1;
  #pragma unroll 1
  for (int bt = wstart; bt < wstart + 128; bt += 16){
    int arow = bt + row16;
    bfrag A0 = *(const bfrag*)(rbf_s + (size_t)arow*64 + quad*8);
    bfrag A1 = *(const bfrag*)(rbf_s + (size_t)arow*64 + 32 + quad*8);
    // prefetch pair indices and xj gathers (issued before MFMA so they overlap)
    int4 iv[4], jv[4];
    #pragma unroll
    for (int g = 0; g < 4; ++g){
      iv[g] = *(const int4*)(i_s + bt + g*4);
      jv[g] = *(const int4*)(j_s + bt + g*4);
    }
    const int* ip = (const int*)iv;
    const int* jp = (const int*)jv;
    float2 xv[16];
    #pragma unroll
    for (int k = 0; k < 16; ++k)
      xv[k] = *(const float2*)(xj + (size_t)jp[k]*128 + 2*l);
    #pragma unroll
    for (int t = 0; t < 8; ++t){
      ffrag C = {0.f,0.f,0.f,0.f};
      C = __builtin_amdgcn_mfma_f32_16x16x32_bf16(A0, B[t][0], C, 0, 0, 0);
      C = __builtin_amdgcn_mfma_f32_16x16x32_bf16(A1, B[t][1], C, 0, 0, 0);
      #pragma unroll
      for (int r = 0; r < 4; ++r)
        Gw[(quad*4+r)*130 + t*16 + row16] = C[r];
    }
    #pragma unroll
    for (int k = 0; k < 16; ++k){
      int i = ip[k];
      if (i != iCur){
        if (iCur >= 0){
          unsafeAtomicAdd(&m_g[(size_t)iCur*128 + 2*l],     a0);
          unsafeAtomicAdd(&m_g[(size_t)iCur*128 + 2*l + 1], a1);
        }
        iCur = i; a0 = 0.f; a1 = 0.f;
      }
      float g0 = Gw[k*130 + 2*l], g1 = Gw[k*130 + 2*l + 1];
      a0 = fmaf(g0, xv[k].x, a0);
      a1 = fmaf(g1, xv[k].y, a1);
    }
  }
  if (iCur >= 0){
    unsafeAtomicAdd(&m_g[(size_t)iCur*128 + 2*l],     a0);
    unsafeAtomicAdd(&m_g[(size_t)iCur*128 + 2*l + 1], a1);
  }
}

// ---------- phase 2: full per-block chain on MFMA, 4 waves / 16-row tile ----------
// W slots: riW1[l]=2l, riW2[l]=2l+1, dW=6, raW1[l]=7+2l, raW2[l]=8+2l,
// roW1=11, roW2=12, WiN=13, WjN=14.
// Bias LDS slots: 0-2 rib1, 3-5 rib2, 6 db, 7 u, 8-9 rab1, 10-11 rab2,
// 12 rob1, 13 rob2, 14 biN, 15 bjN.
template<int HASNEXT, int NH>
__global__ __launch_bounds__(256) void k_phase2m(
    float* __restrict__ m_g, float* __restrict__ x_g, float* __restrict__ xjb_g,
    const unsigned short* __restrict__ WBb,
    const float* __restrict__ rib1, const float* __restrict__ rib2,
    const float* __restrict__ db, const float* __restrict__ u,
    const float* __restrict__ rab1, const float* __restrict__ rab2,
    const float* __restrict__ rob1, const float* __restrict__ rob2,
    const float* __restrict__ biN, const float* __restrict__ bjN,
    const unsigned short* __restrict__ outWBb,
    float* __restrict__ Ea, float* __restrict__ Qa,
    float* __restrict__ last2, float* __restrict__ nh, int N){
  __shared__ unsigned short tiles[2][16*136];
  __shared__ float biasS[16*128];
  int tid = threadIdx.x, w = tid >> 6, l = tid & 63;
  int m = l & 15, q = l >> 4, rbase = blockIdx.x*16;
  ffrag mC[2], xC[2], C[2];
  int cur = 0;

  // stage all biases into LDS once
  if (tid < 128){
    biasS[0*128+tid]  = rib1[tid];
    biasS[1*128+tid]  = rib1[128+tid];
    biasS[2*128+tid]  = rib1[256+tid];
    biasS[3*128+tid]  = rib2[tid];
    biasS[4*128+tid]  = rib2[128+tid];
    biasS[5*128+tid]  = rib2[256+tid];
    biasS[6*128+tid]  = db[tid];
    biasS[7*128+tid]  = u[tid];
    biasS[8*128+tid]  = rab1[tid];
    biasS[9*128+tid]  = rab1[128+tid];
    biasS[10*128+tid] = rab2[tid];
    biasS[11*128+tid] = rab2[128+tid];
    biasS[12*128+tid] = rob1[tid];
    biasS[13*128+tid] = rob2[tid];
    biasS[14*128+tid] = biN[tid];
    biasS[15*128+tid] = bjN[tid];
  }
  // S0: load m -> mC; tiles[0] = act(m)
  #pragma unroll
  for (int tt = 0; tt < 2; ++tt){
    int c = (w*2+tt)*16 + m;
    #pragma unroll
    for (int r = 0; r < 4; ++r){
      float v = m_g[(size_t)(rbase + q*4 + r)*128 + c];
      mC[tt][r] = v;
      tiles[0][(q*4+r)*136 + c] = f2b(actf(v));
    }
  }
  // NRI residuals on m
  #pragma unroll 1
  for (int li = 0; li < 3; ++li){
    __syncthreads();
    mmtile2(tiles[cur], WBb + (size_t)(2*li)*16384, w, l, C);
    #pragma unroll
    for (int tt = 0; tt < 2; ++tt){
      int c = (w*2+tt)*16 + m;
      float bb = biasS[li*128 + c];
      #pragma unroll
      for (int r = 0; r < 4; ++r)
        tiles[1-cur][(q*4+r)*136 + c] = f2b(actf(C[tt][r] + bb));
    }
    cur ^= 1;
    __syncthreads();
    mmtile2(tiles[cur], WBb + (size_t)(2*li+1)*16384, w, l, C);
    #pragma unroll
    for (int tt = 0; tt < 2; ++tt){
      int c = (w*2+tt)*16 + m;
      float bb = biasS[(3+li)*128 + c];
      #pragma unroll
      for (int r = 0; r < 4; ++r){
        float nv = mC[tt][r] + C[tt][r] + bb;
        mC[tt][r] = nv;
        tiles[1-cur][(q*4+r)*136 + c] = f2b(actf(nv));
      }
    }
    cur ^= 1;
  }
  // x-update: x = u*x + act(m)@dW + db
  __syncthreads();
  mmtile2(tiles[cur], WBb + (size_t)6*16384, w, l, C);
  #pragma unroll
  for (int tt = 0; tt < 2; ++tt){
    int c = (w*2+tt)*16 + m;
    float uu = biasS[7*128 + c], bb = biasS[6*128 + c];
    #pragma unroll
    for (int r = 0; r < 4; ++r){
      float xv = x_g[(size_t)(rbase + q*4 + r)*128 + c];
      float nv = uu*xv + C[tt][r] + bb;
      xC[tt][r] = nv;
      tiles[1-cur][(q*4+r)*136 + c] = f2b(actf(nv));
    }
  }
  cur ^= 1;
  // NRA residuals on x
  #pragma unroll 1
  for (int li = 0; li < 2; ++li){
    __syncthreads();
    mmtile2(tiles[cur], WBb + (size_t)(7+2*li)*16384, w, l, C);
    #pragma unroll
    for (int tt = 0; tt < 2; ++tt){
      int c = (w*2+tt)*16 + m;
      float bb = biasS[(8+li)*128 + c];
      #pragma unroll
      for (int r = 0; r < 4; ++r)
        tiles[1-cur][(q*4+r)*136 + c] = f2b(actf(C[tt][r] + bb));
    }
    cur ^= 1;
    __syncthreads();
    mmtile2(tiles[cur], WBb + (size_t)(8+2*li)*16384, w, l, C);
    #pragma unroll
    for (int tt = 0; tt < 2; ++tt){
      int c = (w*2+tt)*16 + m;
      float bb = biasS[(10+li)*128 + c];
      #pragma unroll
      for (int r = 0; r < 4; ++r){
        float nv = xC[tt][r] + C[tt][r] + bb;
        xC[tt][r] = nv;
        tiles[1-cur][(q*4+r)*136 + c] = f2b(actf(nv));
        if (HASNEXT && li == 1)
          x_g[(size_t)(rbase + q*4 + r)*128 + c] = nv;
      }
    }
    cur ^= 1;
  }
  // cur tile now holds ax = act(x_final)
  if (HASNEXT){
    __syncthreads();
    mmtile2(tiles[cur], WBb + (size_t)13*16384, w, l, C);
    #pragma unroll
    for (int tt = 0; tt < 2; ++tt){
      int c = (w*2+tt)*16 + m;
      float bb = biasS[14*128 + c];
      #pragma unroll
      for (int r = 0; r < 4; ++r)
        m_g[(size_t)(rbase + q*4 + r)*128 + c] = actf(C[tt][r] + bb);
    }
    mmtile2(tiles[cur], WBb + (size_t)14*16384, w, l, C);
    #pragma unroll
    for (int tt = 0; tt < 2; ++tt){
      int c = (w*2+tt)*16 + m;
      float bb = biasS[15*128 + c];
      #pragma unroll
      for (int r = 0; r < 4; ++r)
        xjb_g[(size_t)(rbase + q*4 + r)*128 + c] = actf(C[tt][r] + bb);
    }
  }
  // output block: h = act(ax@roW1+rob1); o = x + h@roW2+rob2; tile = act(o)
  __syncthreads();
  mmtile2(tiles[cur], WBb + (size_t)11*16384, w, l, C);
  #pragma unroll
  for (int tt = 0; tt < 2; ++tt){
    int c = (w*2+tt)*16 + m;
    float bb = biasS[12*128 + c];
    #pragma unroll
    for (int r = 0; r < 4; ++r)
      tiles[1-cur][(q*4+r)*136 + c] = f2b(actf(C[tt][r] + bb));
  }
  cur ^= 1;
  __syncthreads();
  mmtile2(tiles[cur], WBb + (size_t)12*16384, w, l, C);
  #pragma unroll
  for (int tt = 0; tt < 2; ++tt){
    int c = (w*2+tt)*16 + m;
    float bb = biasS[13*128 + c];
    #pragma unroll
    for (int r = 0; r < 4; ++r){
      float ov = xC[tt][r] + C[tt][r] + bb;
      tiles[1-cur][(q*4+r)*136 + c] = f2b(actf(ov));
    }
  }
  cur ^= 1;
  // head: out = act(o) @ outW (padded to 16 cols), wave 0 only
  __syncthreads();
  if (w == 0){
    bfrag A[4];
    #pragma unroll
    for (int k0 = 0; k0 < 4; ++k0)
      A[k0] = *(const bfrag*)(&tiles[cur][0] + m*136 + k0*32 + q*8);
    ffrag Ch = {0.f,0.f,0.f,0.f};
    #pragma unroll
    for (int k0 = 0; k0 < 4; ++k0){
      bfrag B = *(const bfrag*)(outWBb + (size_t)(k0*64 + l)*8);
      Ch = __builtin_amdgcn_mfma_f32_16x16x32_bf16(A[k0], B, Ch, 0, 0, 0);
    }
    int col = m;
    if (col < 2){
      float tp = 0.f;
      #pragma unroll
      for (int r = 0; r < 4; ++r){
        int row = rbase + q*4 + r;
        float val = Ch[r];
        if (col == 0) Ea[row] += val; else Qa[row] += val;
        float sq = val*val;
        if (NH){
          float lastv = last2[row*2 + col];
          tp += sq/(sq + lastv + 1e-7f);
        }
        last2[row*2 + col] = sq;
      }
      if (NH) unsafeAtomicAdd(nh, tp);
    }
  }
}

__global__ __launch_bounds__(256) void k_final(
    const int* __restrict__ Z, const float* __restrict__ Ea, const float* __restrict__ Qa,
    const float* __restrict__ Es, const float* __restrict__ Eh,
    const float* __restrict__ Qs, const float* __restrict__ Qh,
    const float* __restrict__ nh, float* __restrict__ out, int N, int P){
  int n = blockIdx.x*256 + threadIdx.x;
  if (n < N){
    int z = Z[n];
    out[n]   = Es[z]*Ea[n] + Eh[z];
    out[N+n] = Qs[z]*Qa[n] + Qh[z];
  }
  if (blockIdx.x == 0 && threadIdx.x == 0)
    out[(size_t)2*N + P] = nh[0] / (2.f * (float)N);
}

extern "C" void kernel_launch(void* const* d_in, const int* in_sizes, int n_in,
                              void* d_out, int out_size, void* d_ws, size_t ws_size,
                              hipStream_t stream){
  const int N = in_sizes[0];
  const int P = in_sizes[2];
  const int F = 128;

  const int* Z      = (const int*)d_in[0];
  const float* R    = (const float*)d_in[1];
  const int* idx_i  = (const int*)d_in[2];
  const int* idx_j  = (const int*)d_in[3];
  const float* emb  = (const float*)d_in[4];
  const float* cent = (const float*)d_in[5];
  const float* wid  = (const float*)d_in[6];
  const float* k2f  = (const float*)d_in[7];
  const float* Wi   = (const float*)d_in[8];  const float* bi   = (const float*)d_in[9];
  const float* Wj   = (const float*)d_in[10]; const float* bj   = (const float*)d_in[11];
  const float* riW1 = (const float*)d_in[12]; const float* rib1 = (const float*)d_in[13];
  const float* riW2 = (const float*)d_in[14]; const float* rib2 = (const float*)d_in[15];
  const float* dWp  = (const float*)d_in[16]; const float* dbp  = (const float*)d_in[17];
  const float* u    = (const float*)d_in[18];
  const float* raW1 = (const float*)d_in[19]; const float* rab1 = (const float*)d_in[20];
  const float* raW2 = (const float*)d_in[21]; const float* rab2 = (const float*)d_in[22];
  const float* roW1 = (const float*)d_in[23]; const float* rob1 = (const float*)d_in[24];
  const float* roW2 = (const float*)d_in[25]; const float* rob2 = (const float*)d_in[26];
  const float* outW = (const float*)d_in[27];
  const float* Es   = (const float*)d_in[28]; const float* Eh   = (const float*)d_in[29];
  const float* Qs   = (const float*)d_in[30]; const float* Qh   = (const float*)d_in[31];

  char* ws = (char*)d_ws;
  size_t off = 0;
  float* DijF  = (float*)(ws + off); off += (size_t)P*4;
  float* D_s   = (float*)(ws + off); off += (size_t)P*4;
  int*   i_s   = (int*)  (ws + off); off += (size_t)P*4;
  int*   j_s   = (int*)  (ws + off); off += (size_t)P*4;
  unsigned short* rbf_s = (unsigned short*)(ws + off); off += (size_t)P*64*2;
  unsigned short* k2fP  = (unsigned short*)(ws + off); off += (size_t)5*16*64*8*2;
  unsigned short* WBall = (unsigned short*)(ws + off); off += (size_t)75*16384*2;
  unsigned short* outWB = (unsigned short*)(ws + off); off += (size_t)5*2048*2;
  float* x     = (float*)(ws + off); off += (size_t)N*F*4;
  float* xjb   = (float*)(ws + off); off += (size_t)N*F*4;
  float* m     = (float*)(ws + off); off += (size_t)N*F*4;
  float* last2 = (float*)(ws + off); off += (size_t)N*2*4;
  float* Ea    = (float*)(ws + off); off += (size_t)N*4;   // zero region start
  float* Qa    = (float*)(ws + off); off += (size_t)N*4;
  float* nh    = (float*)(ws + off); off += 256;
  int*   counts= (int*)  (ws + off); off += (size_t)N*4;   // zero region end
  int*   starts= (int*)  (ws + off); off += (size_t)(N+1)*4;
  int*   cursor= (int*)  (ws + off); off += (size_t)N*4;

  float* outF = (float*)d_out;
  float* Dout = outF + (size_t)2*N;

  const int nzero = 3*N + 64;
  k_zero<<<dim3((nzero+255)/256), dim3(256), 0, stream>>>(Ea, nzero);
  k_dij_count<<<dim3((P+255)/256), dim3(256), 0, stream>>>(R, idx_i, idx_j, DijF, Dout, counts, P);
  k_scan<<<dim3(1), dim3(256), 0, stream>>>(counts, starts, cursor, N);
  k_scatter<<<dim3((P+255)/256), dim3(256), 0, stream>>>(idx_i, idx_j, DijF, cursor, i_s, j_s, D_s, P);
  k_rbf<<<dim3((P*64+255)/256), dim3(256), 0, stream>>>(D_s, cent, wid, rbf_s, P);
  k_prep<<<dim3(20), dim3(256), 0, stream>>>(k2f, k2fP);

  auto prep = [&](const float* src, int nmat, int nl, int offv, int step, int bBase){
    k_prepW<<<dim3((nmat*2048+255)/256), dim3(256), 0, stream>>>(src, WBall, nmat, nl, offv, step, bBase);
  };
  prep(riW1, 15, 3, 0, 2, 0);
  prep(riW2, 15, 3, 1, 2, 0);
  prep(dWp,   5, 1, 6, 0, 0);
  prep(raW1, 10, 2, 7, 2, 0);
  prep(raW2, 10, 2, 8, 2, 0);
  prep(roW1,  5, 1, 11, 0, 0);
  prep(roW2,  5, 1, 12, 0, 0);
  prep(Wi + 16384, 4, 1, 13, 0, 0);   // WiN for b=0..3
  prep(Wi,         1, 1, 13, 0, 4);   // slot [4][13] = Wi[0] (used by phase1)
  prep(Wj + 16384, 4, 1, 14, 0, 0);
  prep(Wj,         1, 1, 14, 0, 4);
  k_prepO<<<dim3(5), dim3(256), 0, stream>>>(outW, outWB);

  const int G16 = (N + 15)/16;   // N=10000 -> 625 exactly
  k_phase1m<<<dim3(G16), dim3(128), 0, stream>>>(Z, emb, WBall + (size_t)4*15*16384,
                                                 bi, bj, x, m, xjb, N);

  const int pmg = (P + 511)/512;
  for (int b = 0; b < 5; ++b){
    k_pairmsg2<<<dim3(pmg), dim3(256), 0, stream>>>(rbf_s, k2fP + (size_t)b*16*64*8,
                                                    i_s, j_s, xjb, m, P);
    const unsigned short* WBb = WBall + (size_t)b*15*16384;
    const float* a_rib1 = rib1 + (size_t)b*3*F;
    const float* a_rib2 = rib2 + (size_t)b*3*F;
    const float* a_db   = dbp  + (size_t)b*F;
    const float* a_u    = u    + (size_t)b*F;
    const float* a_rab1 = rab1 + (size_t)b*2*F;
    const float* a_rab2 = rab2 + (size_t)b*2*F;
    const float* a_rob1 = rob1 + (size_t)b*F;
    const float* a_rob2 = rob2 + (size_t)b*F;
    int bn = (b < 4) ? (b+1) : 0;
    const float* a_biN = bi + (size_t)bn*F;
    const float* a_bjN = bj + (size_t)bn*F;
    const unsigned short* oWB = outWB + (size_t)b*2048;
    if (b == 0){
      k_phase2m<1,0><<<dim3(G16), dim3(256), 0, stream>>>(m, x, xjb, WBb,
        a_rib1, a_rib2, a_db, a_u, a_rab1, a_rab2, a_rob1, a_rob2,
        a_biN, a_bjN, oWB, Ea, Qa, last2, nh, N);
    } else if (b < 4){
      k_phase2m<1,1><<<dim3(G16), dim3(256), 0, stream>>>(m, x, xjb, WBb,
        a_rib1, a_rib2, a_db, a_u, a_rab1, a_rab2, a_rob1, a_rob2,
        a_biN, a_bjN, oWB, Ea, Qa, last2, nh, N);
    } else {
      k_phase2m<0,1><<<dim3(G16), dim3(256), 0, stream>>>(m, x, xjb, WBb,
        a_rib1, a_rib2, a_db, a_u, a_rab1, a_rab2, a_rob1, a_rob2,
        a_biN, a_bjN, oWB, Ea, Qa, last2, nh, N);
    }
  }
  k_final<<<dim3((N+255)/256), dim3(256), 0, stream>>>(Z, Ea, Qa, Es, Eh, Qs, Qh, nh, outF, N, P);
}

// Round 9
// 520.787 us; speedup vs baseline: 9.4821x; 1.1078x over previous
//
#include <hip/hip_runtime.h>

typedef __attribute__((ext_vector_type(8))) short bfrag;   // 8 bf16 (4 VGPRs)
typedef __attribute__((ext_vector_type(4))) float ffrag;   // 4 fp32

__device__ __forceinline__ unsigned short f2b(float f){
  unsigned int u = __float_as_uint(f);
  return (unsigned short)((u + 0x7FFFu + ((u >> 16) & 1u)) >> 16);
}
// shifted softplus via v_exp/v_log (both base-2 on gfx950)
__device__ __forceinline__ float actf(float v){
  float e = __builtin_amdgcn_exp2f(-fabsf(v)*1.44269504088896341f);
  return fmaxf(v, 0.f) + __builtin_amdgcn_logf(1.f + e)*0.69314718055994531f - 0.69314718055994531f;
}

// ---------- small utility kernels ----------
__global__ __launch_bounds__(256) void k_zero(float* p, int n){
  int i = blockIdx.x*256 + threadIdx.x;
  if (i < n) p[i] = 0.f;
}

__global__ __launch_bounds__(256) void k_dij_count(
    const float* __restrict__ R, const int* __restrict__ idx_i, const int* __restrict__ idx_j,
    float* __restrict__ DijF, float* __restrict__ Dout, int* __restrict__ counts, int P){
  int p = blockIdx.x*256 + threadIdx.x;
  if (p >= P) return;
  int i = idx_i[p], j = idx_j[p];
  float dx = R[i*3+0] - R[j*3+0];
  float dy = R[i*3+1] - R[j*3+1];
  float dz = R[i*3+2] - R[j*3+2];
  float D = sqrtf(fmaxf(dx*dx + dy*dy + dz*dz, 0.f));
  DijF[p] = D;
  Dout[p] = D;
  atomicAdd(&counts[i], 1);
}

// hierarchical scan: A) per-block scan + block sum, B) scan block sums, C) add offsets
__global__ __launch_bounds__(256) void k_scanA(const int* __restrict__ counts,
    int* __restrict__ locEx, int* __restrict__ bsum, int N){
  __shared__ int buf[256];
  int tid = threadIdx.x, idx = blockIdx.x*256 + tid;
  int v = (idx < N) ? counts[idx] : 0;
  buf[tid] = v;
  __syncthreads();
  for (int off = 1; off < 256; off <<= 1){
    int t = (tid >= off) ? buf[tid-off] : 0;
    __syncthreads();
    buf[tid] += t;
    __syncthreads();
  }
  if (idx < N) locEx[idx] = buf[tid] - v;
  if (tid == 255) bsum[blockIdx.x] = buf[255];
}
__global__ __launch_bounds__(64) void k_scanB(int* __restrict__ bsum,
    int* __restrict__ boff, int nb){
  if (threadIdx.x == 0){
    int acc = 0;
    for (int i = 0; i < nb; ++i){ boff[i] = acc; acc += bsum[i]; }
    boff[nb] = acc;
  }
}
__global__ __launch_bounds__(256) void k_scanC(const int* __restrict__ locEx,
    const int* __restrict__ boff, int* __restrict__ starts, int* __restrict__ cursor,
    int N, int nb){
  int idx = blockIdx.x*256 + threadIdx.x;
  if (idx < N){
    int s = locEx[idx] + boff[blockIdx.x];
    starts[idx] = s; cursor[idx] = s;
  }
  if (idx == 0) starts[N] = boff[nb];
}

__global__ __launch_bounds__(256) void k_scatter(const int* __restrict__ idx_i,
    const int* __restrict__ idx_j, const float* __restrict__ DijF,
    int* __restrict__ cursor, int* __restrict__ i_s, int* __restrict__ j_s,
    float* __restrict__ D_s, int P){
  int p = blockIdx.x*256 + threadIdx.x;
  if (p >= P) return;
  int i = idx_i[p];
  int pos = atomicAdd(&cursor[i], 1);
  i_s[pos] = i;
  j_s[pos] = idx_j[p];
  D_s[pos] = DijF[p];
}

__global__ __launch_bounds__(256) void k_rbf(
    const float* __restrict__ D_s, const float* __restrict__ cent, const float* __restrict__ wid,
    unsigned short* __restrict__ rbf_s, int P){
  int gid = blockIdx.x*256 + threadIdx.x;
  if (gid >= P*64) return;
  int t = gid >> 6, k = gid & 63;
  float D = D_s[t];
  float xc = D * 0.1f;
  float cut = 0.f;
  if (xc < 1.f){
    float x3 = xc*xc*xc, x4 = x3*xc, x5 = x4*xc;
    cut = 1.f - 6.f*x5 + 15.f*x4 - 10.f*x3;
  }
  float tt = expf(-D) - cent[k];
  rbf_s[gid] = f2b(cut * expf(-wid[k]*tt*tt));
}

// k2f B-frag prep -- unchanged, HW-verified
__global__ __launch_bounds__(256) void k_prep(const float* __restrict__ k2f,
    unsigned short* __restrict__ k2fP){
  int gid = blockIdx.x*256 + threadIdx.x;
  if (gid >= 5120) return;
  int l = gid & 63, fr = (gid >> 6) & 15, b = gid >> 10;
  int tile = fr >> 1, kh = fr & 1;
  const float* src = k2f + (size_t)b*64*128;
  int n = tile*16 + (l & 15);
  int kbase = kh*32 + (l >> 4)*8;
  ushort4 o0, o1;
  o0.x = f2b(src[(kbase+0)*128+n]); o0.y = f2b(src[(kbase+1)*128+n]);
  o0.z = f2b(src[(kbase+2)*128+n]); o0.w = f2b(src[(kbase+3)*128+n]);
  o1.x = f2b(src[(kbase+4)*128+n]); o1.y = f2b(src[(kbase+5)*128+n]);
  o1.z = f2b(src[(kbase+6)*128+n]); o1.w = f2b(src[(kbase+7)*128+n]);
  ushort4* dst = (ushort4*)(k2fP + (size_t)gid*8);
  dst[0] = o0; dst[1] = o1;
}

// ALL 75 weight matrices repacked in ONE launch.
// mat index mapping (75 total): 0-14 riW1, 15-29 riW2, 30-34 dW, 35-44 raW1,
// 45-54 raW2, 55-59 roW1, 60-64 roW2, 65-69 Wi, 70-74 Wj.
__global__ __launch_bounds__(256) void k_prepAll(
    const float* __restrict__ riW1, const float* __restrict__ riW2,
    const float* __restrict__ dW,   const float* __restrict__ raW1,
    const float* __restrict__ raW2, const float* __restrict__ roW1,
    const float* __restrict__ roW2, const float* __restrict__ Wi,
    const float* __restrict__ Wj,   unsigned short* __restrict__ WBall){
  int gid = blockIdx.x*256 + threadIdx.x;
  if (gid >= 75*2048) return;
  int i = gid >> 11, r = gid & 2047;
  const float* S;
  int slot;
  if (i < 15)      { S = riW1 + (size_t)i*16384;      slot = (i/3)*15 + 2*(i%3); }
  else if (i < 30) { int j=i-15; S = riW2 + (size_t)j*16384; slot = (j/3)*15 + 2*(j%3) + 1; }
  else if (i < 35) { int j=i-30; S = dW   + (size_t)j*16384; slot = j*15 + 6; }
  else if (i < 45) { int j=i-35; S = raW1 + (size_t)j*16384; slot = (j/2)*15 + 7 + 2*(j%2); }
  else if (i < 55) { int j=i-45; S = raW2 + (size_t)j*16384; slot = (j/2)*15 + 8 + 2*(j%2); }
  else if (i < 60) { int j=i-55; S = roW1 + (size_t)j*16384; slot = j*15 + 11; }
  else if (i < 65) { int j=i-60; S = roW2 + (size_t)j*16384; slot = j*15 + 12; }
  else if (i < 70) { int j=i-65; S = Wi   + (size_t)j*16384; slot = ((j==0)?4:(j-1))*15 + 13; }
  else             { int j=i-70; S = Wj   + (size_t)j*16384; slot = ((j==0)?4:(j-1))*15 + 14; }
  int fr = r >> 6, l = r & 63;
  int T = fr >> 2, k0 = fr & 3;
  int n = T*16 + (l & 15);
  int kbase = k0*32 + (l >> 4)*8;
  unsigned short* D = WBall + ((size_t)slot*2048 + r)*8;
  ushort4 o0, o1;
  o0.x=f2b(S[(kbase+0)*128+n]); o0.y=f2b(S[(kbase+1)*128+n]);
  o0.z=f2b(S[(kbase+2)*128+n]); o0.w=f2b(S[(kbase+3)*128+n]);
  o1.x=f2b(S[(kbase+4)*128+n]); o1.y=f2b(S[(kbase+5)*128+n]);
  o1.z=f2b(S[(kbase+6)*128+n]); o1.w=f2b(S[(kbase+7)*128+n]);
  ((ushort4*)D)[0]=o0; ((ushort4*)D)[1]=o1;
}

// outW[b] [128x2] -> padded B-frags -- unchanged
__global__ __launch_bounds__(256) void k_prepO(const float* __restrict__ outW,
    unsigned short* __restrict__ outWB){
  int gid = blockIdx.x*256 + threadIdx.x;
  if (gid >= 5*256) return;
  int b = gid >> 8, r = gid & 255;
  int l = r & 63;
  int col = l & 15;
  int k0 = r >> 6;
  int kbase = k0*32 + (l >> 4)*8;
  ushort4 o0 = {0,0,0,0}, o1 = {0,0,0,0};
  if (col < 2){
    const float* S = outW + (size_t)b*256;
    o0.x=f2b(S[(kbase+0)*2+col]); o0.y=f2b(S[(kbase+1)*2+col]);
    o0.z=f2b(S[(kbase+2)*2+col]); o0.w=f2b(S[(kbase+3)*2+col]);
    o1.x=f2b(S[(kbase+4)*2+col]); o1.y=f2b(S[(kbase+5)*2+col]);
    o1.z=f2b(S[(kbase+6)*2+col]); o1.w=f2b(S[(kbase+7)*2+col]);
  }
  unsigned short* D = outWB + ((size_t)b*256 + r)*8;
  ((ushort4*)D)[0]=o0; ((ushort4*)D)[1]=o1;
}

// ---------- MFMA tile machinery ----------
__device__ __forceinline__ void mmtile(const unsigned short* tile,
    const unsigned short* __restrict__ WB, int w, int l, ffrag C[4]){
  int m = l & 15, q = l >> 4;
  bfrag A[4];
  #pragma unroll
  for (int k0 = 0; k0 < 4; ++k0)
    A[k0] = *(const bfrag*)(tile + m*136 + k0*32 + q*8);
  #pragma unroll
  for (int tt = 0; tt < 4; ++tt){
    ffrag c = {0.f,0.f,0.f,0.f};
    const bfrag* bp = (const bfrag*)(WB + (((w*4+tt)*4)*64 + l)*8);
    #pragma unroll
    for (int k0 = 0; k0 < 4; ++k0)
      c = __builtin_amdgcn_mfma_f32_16x16x32_bf16(A[k0], bp[k0*64], c, 0, 0, 0);
    C[tt] = c;
  }
}

__device__ __forceinline__ void mmtile2(const unsigned short* tile,
    const unsigned short* __restrict__ WB, int w, int l, ffrag C[2]){
  int m = l & 15, q = l >> 4;
  bfrag A[4];
  #pragma unroll
  for (int k0 = 0; k0 < 4; ++k0)
    A[k0] = *(const bfrag*)(tile + m*136 + k0*32 + q*8);
  #pragma unroll
  for (int tt = 0; tt < 2; ++tt){
    ffrag c = {0.f,0.f,0.f,0.f};
    const bfrag* bp = (const bfrag*)(WB + (((w*2+tt)*4)*64 + l)*8);
    #pragma unroll
    for (int k0 = 0; k0 < 4; ++k0)
      c = __builtin_amdgcn_mfma_f32_16x16x32_bf16(A[k0], bp[k0*64], c, 0, 0, 0);
    C[tt] = c;
  }
}

// phase1: x = emb[Z]; m_g = act(act(x)@Wi0+bi0); xjb = act(act(x)@Wj0+bj0)
__global__ __launch_bounds__(128) void k_phase1m(
    const int* __restrict__ Z, const float* __restrict__ emb,
    const unsigned short* __restrict__ WB45,
    const float* __restrict__ bi0, const float* __restrict__ bj0,
    float* __restrict__ x_g, float* __restrict__ m_g, float* __restrict__ xjb_g, int N){
  __shared__ unsigned short tile[16*136];
  int tid = threadIdx.x, w = tid >> 6, l = tid & 63;
  int m = l & 15, q = l >> 4, rbase = blockIdx.x*16;
  #pragma unroll
  for (int r = 0; r < 4; ++r){
    int row = rbase + q*4 + r;
    int z = Z[row];
    #pragma unroll
    for (int tt = 0; tt < 4; ++tt){
      int c = (w*4+tt)*16 + m;
      float v = emb[(size_t)z*128 + c];
      x_g[(size_t)row*128 + c] = v;
      tile[(q*4+r)*136 + c] = f2b(actf(v));
    }
  }
  __syncthreads();
  ffrag C[4];
  mmtile(tile, WB45 + 13*16384, w, l, C);
  #pragma unroll
  for (int tt = 0; tt < 4; ++tt){
    int c = (w*4+tt)*16 + m;
    float bb = bi0[c];
    #pragma unroll
    for (int r = 0; r < 4; ++r)
      m_g[(size_t)(rbase + q*4 + r)*128 + c] = actf(C[tt][r] + bb);
  }
  mmtile(tile, WB45 + 14*16384, w, l, C);
  #pragma unroll
  for (int tt = 0; tt < 4; ++tt){
    int c = (w*4+tt)*16 + m;
    float bb = bj0[c];
    #pragma unroll
    for (int r = 0; r < 4; ++r)
      xjb_g[(size_t)(rbase + q*4 + r)*128 + c] = actf(C[tt][r] + bb);
  }
}

// MFMA pair-message with batched index/xj prefetch (P % 512 == 0)
__global__ __launch_bounds__(256) void k_pairmsg2(
    const unsigned short* __restrict__ rbf_s, const unsigned short* __restrict__ k2fP,
    const int* __restrict__ i_s, const int* __restrict__ j_s,
    const float* __restrict__ xj, float* __restrict__ m_g, int P){
  __shared__ float G[4][16*130];
  int tid = threadIdx.x, w = tid >> 6, l = tid & 63;
  float* Gw = &G[w][0];
  bfrag B[8][2];
  #pragma unroll
  for (int t = 0; t < 8; ++t){
    #pragma unroll
    for (int kh = 0; kh < 2; ++kh)
      B[t][kh] = *(const bfrag*)(k2fP + (size_t)((t*2+kh)*64 + l)*8);
  }
  int wstart = (blockIdx.x*4 + w)*128;
  if (wstart >= P) return;
  int row16 = l & 15, quad = l >> 4;
  float a0 = 0.f, a1 = 0.f;
  int iCur = -1;
  #pragma unroll 1
  for (int bt = wstart; bt < wstart + 128; bt += 16){
    int arow = bt + row16;
    bfrag A0 = *(const bfrag*)(rbf_s + (size_t)arow*64 + quad*8);
    bfrag A1 = *(const bfrag*)(rbf_s + (size_t)arow*64 + 32 + quad*8);
    int4 iv[4], jv[4];
    #pragma unroll
    for (int g = 0; g < 4; ++g){
      iv[g] = *(const int4*)(i_s + bt + g*4);
      jv[g] = *(const int4*)(j_s + bt + g*4);
    }
    const int* ip = (const int*)iv;
    const int* jp = (const int*)jv;
    float2 xv[16];
    #pragma unroll
    for (int k = 0; k < 16; ++k)
      xv[k] = *(const float2*)(xj + (size_t)jp[k]*128 + 2*l);
    #pragma unroll
    for (int t = 0; t < 8; ++t){
      ffrag C = {0.f,0.f,0.f,0.f};
      C = __builtin_amdgcn_mfma_f32_16x16x32_bf16(A0, B[t][0], C, 0, 0, 0);
      C = __builtin_amdgcn_mfma_f32_16x16x32_bf16(A1, B[t][1], C, 0, 0, 0);
      #pragma unroll
      for (int r = 0; r < 4; ++r)
        Gw[(quad*4+r)*130 + t*16 + row16] = C[r];
    }
    #pragma unroll
    for (int k = 0; k < 16; ++k){
      int i = ip[k];
      if (i != iCur){
        if (iCur >= 0){
          unsafeAtomicAdd(&m_g[(size_t)iCur*128 + 2*l],     a0);
          unsafeAtomicAdd(&m_g[(size_t)iCur*128 + 2*l + 1], a1);
        }
        iCur = i; a0 = 0.f; a1 = 0.f;
      }
      float g0 = Gw[k*130 + 2*l], g1 = Gw[k*130 + 2*l + 1];
      a0 = fmaf(g0, xv[k].x, a0);
      a1 = fmaf(g1, xv[k].y, a1);
    }
  }
  if (iCur >= 0){
    unsafeAtomicAdd(&m_g[(size_t)iCur*128 + 2*l],     a0);
    unsafeAtomicAdd(&m_g[(size_t)iCur*128 + 2*l + 1], a1);
  }
}

// ---------- phase 2: full per-block chain on MFMA, 4 waves / 16-row tile ----------
template<int HASNEXT, int NH>
__global__ __launch_bounds__(256) void k_phase2m(
    float* __restrict__ m_g, float* __restrict__ x_g, float* __restrict__ xjb_g,
    const unsigned short* __restrict__ WBb,
    const float* __restrict__ rib1, const float* __restrict__ rib2,
    const float* __restrict__ db, const float* __restrict__ u,
    const float* __restrict__ rab1, const float* __restrict__ rab2,
    const float* __restrict__ rob1, const float* __restrict__ rob2,
    const float* __restrict__ biN, const float* __restrict__ bjN,
    const unsigned short* __restrict__ outWBb,
    float* __restrict__ Ea, float* __restrict__ Qa,
    float* __restrict__ last2, float* __restrict__ nh, int N){
  __shared__ unsigned short tiles[2][16*136];
  __shared__ float biasS[16*128];
  int tid = threadIdx.x, w = tid >> 6, l = tid & 63;
  int m = l & 15, q = l >> 4, rbase = blockIdx.x*16;
  ffrag mC[2], xC[2], C[2];
  int cur = 0;

  if (tid < 128){
    biasS[0*128+tid]  = rib1[tid];
    biasS[1*128+tid]  = rib1[128+tid];
    biasS[2*128+tid]  = rib1[256+tid];
    biasS[3*128+tid]  = rib2[tid];
    biasS[4*128+tid]  = rib2[128+tid];
    biasS[5*128+tid]  = rib2[256+tid];
    biasS[6*128+tid]  = db[tid];
    biasS[7*128+tid]  = u[tid];
    biasS[8*128+tid]  = rab1[tid];
    biasS[9*128+tid]  = rab1[128+tid];
    biasS[10*128+tid] = rab2[tid];
    biasS[11*128+tid] = rab2[128+tid];
    biasS[12*128+tid] = rob1[tid];
    biasS[13*128+tid] = rob2[tid];
    biasS[14*128+tid] = biN[tid];
    biasS[15*128+tid] = bjN[tid];
  }
  #pragma unroll
  for (int tt = 0; tt < 2; ++tt){
    int c = (w*2+tt)*16 + m;
    #pragma unroll
    for (int r = 0; r < 4; ++r){
      float v = m_g[(size_t)(rbase + q*4 + r)*128 + c];
      mC[tt][r] = v;
      tiles[0][(q*4+r)*136 + c] = f2b(actf(v));
    }
  }
  #pragma unroll 1
  for (int li = 0; li < 3; ++li){
    __syncthreads();
    mmtile2(tiles[cur], WBb + (size_t)(2*li)*16384, w, l, C);
    #pragma unroll
    for (int tt = 0; tt < 2; ++tt){
      int c = (w*2+tt)*16 + m;
      float bb = biasS[li*128 + c];
      #pragma unroll
      for (int r = 0; r < 4; ++r)
        tiles[1-cur][(q*4+r)*136 + c] = f2b(actf(C[tt][r] + bb));
    }
    cur ^= 1;
    __syncthreads();
    mmtile2(tiles[cur], WBb + (size_t)(2*li+1)*16384, w, l, C);
    #pragma unroll
    for (int tt = 0; tt < 2; ++tt){
      int c = (w*2+tt)*16 + m;
      float bb = biasS[(3+li)*128 + c];
      #pragma unroll
      for (int r = 0; r < 4; ++r){
        float nv = mC[tt][r] + C[tt][r] + bb;
        mC[tt][r] = nv;
        tiles[1-cur][(q*4+r)*136 + c] = f2b(actf(nv));
      }
    }
    cur ^= 1;
  }
  __syncthreads();
  mmtile2(tiles[cur], WBb + (size_t)6*16384, w, l, C);
  #pragma unroll
  for (int tt = 0; tt < 2; ++tt){
    int c = (w*2+tt)*16 + m;
    float uu = biasS[7*128 + c], bb = biasS[6*128 + c];
    #pragma unroll
    for (int r = 0; r < 4; ++r){
      float xv = x_g[(size_t)(rbase + q*4 + r)*128 + c];
      float nv = uu*xv + C[tt][r] + bb;
      xC[tt][r] = nv;
      tiles[1-cur][(q*4+r)*136 + c] = f2b(actf(nv));
    }
  }
  cur ^= 1;
  #pragma unroll 1
  for (int li = 0; li < 2; ++li){
    __syncthreads();
    mmtile2(tiles[cur], WBb + (size_t)(7+2*li)*16384, w, l, C);
    #pragma unroll
    for (int tt = 0; tt < 2; ++tt){
      int c = (w*2+tt)*16 + m;
      float bb = biasS[(8+li)*128 + c];
      #pragma unroll
      for (int r = 0; r < 4; ++r)
        tiles[1-cur][(q*4+r)*136 + c] = f2b(actf(C[tt][r] + bb));
    }
    cur ^= 1;
    __syncthreads();
    mmtile2(tiles[cur], WBb + (size_t)(8+2*li)*16384, w, l, C);
    #pragma unroll
    for (int tt = 0; tt < 2; ++tt){
      int c = (w*2+tt)*16 + m;
      float bb = biasS[(10+li)*128 + c];
      #pragma unroll
      for (int r = 0; r < 4; ++r){
        float nv = xC[tt][r] + C[tt][r] + bb;
        xC[tt][r] = nv;
        tiles[1-cur][(q*4+r)*136 + c] = f2b(actf(nv));
        if (HASNEXT && li == 1)
          x_g[(size_t)(rbase + q*4 + r)*128 + c] = nv;
      }
    }
    cur ^= 1;
  }
  if (HASNEXT){
    __syncthreads();
    mmtile2(tiles[cur], WBb + (size_t)13*16384, w, l, C);
    #pragma unroll
    for (int tt = 0; tt < 2; ++tt){
      int c = (w*2+tt)*16 + m;
      float bb = biasS[14*128 + c];
      #pragma unroll
      for (int r = 0; r < 4; ++r)
        m_g[(size_t)(rbase + q*4 + r)*128 + c] = actf(C[tt][r] + bb);
    }
    mmtile2(tiles[cur], WBb + (size_t)14*16384, w, l, C);
    #pragma unroll
    for (int tt = 0; tt < 2; ++tt){
      int c = (w*2+tt)*16 + m;
      float bb = biasS[15*128 + c];
      #pragma unroll
      for (int r = 0; r < 4; ++r)
        xjb_g[(size_t)(rbase + q*4 + r)*128 + c] = actf(C[tt][r] + bb);
    }
  }
  __syncthreads();
  mmtile2(tiles[cur], WBb + (size_t)11*16384, w, l, C);
  #pragma unroll
  for (int tt = 0; tt < 2; ++tt){
    int c = (w*2+tt)*16 + m;
    float bb = biasS[12*128 + c];
    #pragma unroll
    for (int r = 0; r < 4; ++r)
      tiles[1-cur][(q*4+r)*136 + c] = f2b(actf(C[tt][r] + bb));
  }
  cur ^= 1;
  __syncthreads();
  mmtile2(tiles[cur], WBb + (size_t)12*16384, w, l, C);
  #pragma unroll
  for (int tt = 0; tt < 2; ++tt){
    int c = (w*2+tt)*16 + m;
    float bb = biasS[13*128 + c];
    #pragma unroll
    for (int r = 0; r < 4; ++r){
      float ov = xC[tt][r] + C[tt][r] + bb;
      tiles[1-cur][(q*4+r)*136 + c] = f2b(actf(ov));
    }
  }
  cur ^= 1;
  __syncthreads();
  if (w == 0){
    bfrag A[4];
    #pragma unroll
    for (int k0 = 0; k0 < 4; ++k0)
      A[k0] = *(const bfrag*)(&tiles[cur][0] + m*136 + k0*32 + q*8);
    ffrag Ch = {0.f,0.f,0.f,0.f};
    #pragma unroll
    for (int k0 = 0; k0 < 4; ++k0){
      bfrag B = *(const bfrag*)(outWBb + (size_t)(k0*64 + l)*8);
      Ch = __builtin_amdgcn_mfma_f32_16x16x32_bf16(A[k0], B, Ch, 0, 0, 0);
    }
    int col = m;
    if (col < 2){
      float tp = 0.f;
      #pragma unroll
      for (int r = 0; r < 4; ++r){
        int row = rbase + q*4 + r;
        float val = Ch[r];
        if (col == 0) Ea[row] += val; else Qa[row] += val;
        float sq = val*val;
        if (NH){
          float lastv = last2[row*2 + col];
          tp += sq/(sq + lastv + 1e-7f);
        }
        last2[row*2 + col] = sq;
      }
      if (NH) unsafeAtomicAdd(nh, tp);
    }
  }
}

__global__ __launch_bounds__(256) void k_final(
    const int* __restrict__ Z, const float* __restrict__ Ea, const float* __restrict__ Qa,
    const float* __restrict__ Es, const float* __restrict__ Eh,
    const float* __restrict__ Qs, const float* __restrict__ Qh,
    const float* __restrict__ nh, float* __restrict__ out, int N, int P){
  int n = blockIdx.x*256 + threadIdx.x;
  if (n < N){
    int z = Z[n];
    out[n]   = Es[z]*Ea[n] + Eh[z];
    out[N+n] = Qs[z]*Qa[n] + Qh[z];
  }
  if (blockIdx.x == 0 && threadIdx.x == 0)
    out[(size_t)2*N + P] = nh[0] / (2.f * (float)N);
}

extern "C" void kernel_launch(void* const* d_in, const int* in_sizes, int n_in,
                              void* d_out, int out_size, void* d_ws, size_t ws_size,
                              hipStream_t stream){
  const int N = in_sizes[0];
  const int P = in_sizes[2];
  const int F = 128;

  const int* Z      = (const int*)d_in[0];
  const float* R    = (const float*)d_in[1];
  const int* idx_i  = (const int*)d_in[2];
  const int* idx_j  = (const int*)d_in[3];
  const float* emb  = (const float*)d_in[4];
  const float* cent = (const float*)d_in[5];
  const float* wid  = (const float*)d_in[6];
  const float* k2f  = (const float*)d_in[7];
  const float* Wi   = (const float*)d_in[8];  const float* bi   = (const float*)d_in[9];
  const float* Wj   = (const float*)d_in[10]; const float* bj   = (const float*)d_in[11];
  const float* riW1 = (const float*)d_in[12]; const float* rib1 = (const float*)d_in[13];
  const float* riW2 = (const float*)d_in[14]; const float* rib2 = (const float*)d_in[15];
  const float* dWp  = (const float*)d_in[16]; const float* dbp  = (const float*)d_in[17];
  const float* u    = (const float*)d_in[18];
  const float* raW1 = (const float*)d_in[19]; const float* rab1 = (const float*)d_in[20];
  const float* raW2 = (const float*)d_in[21]; const float* rab2 = (const float*)d_in[22];
  const float* roW1 = (const float*)d_in[23]; const float* rob1 = (const float*)d_in[24];
  const float* roW2 = (const float*)d_in[25]; const float* rob2 = (const float*)d_in[26];
  const float* outW = (const float*)d_in[27];
  const float* Es   = (const float*)d_in[28]; const float* Eh   = (const float*)d_in[29];
  const float* Qs   = (const float*)d_in[30]; const float* Qh   = (const float*)d_in[31];

  char* ws = (char*)d_ws;
  size_t off = 0;
  float* DijF  = (float*)(ws + off); off += (size_t)P*4;
  float* D_s   = (float*)(ws + off); off += (size_t)P*4;
  int*   i_s   = (int*)  (ws + off); off += (size_t)P*4;
  int*   j_s   = (int*)  (ws + off); off += (size_t)P*4;
  unsigned short* rbf_s = (unsigned short*)(ws + off); off += (size_t)P*64*2;
  unsigned short* k2fP  = (unsigned short*)(ws + off); off += (size_t)5*16*64*8*2;
  unsigned short* WBall = (unsigned short*)(ws + off); off += (size_t)75*16384*2;
  unsigned short* outWB = (unsigned short*)(ws + off); off += (size_t)5*2048*2;
  float* x     = (float*)(ws + off); off += (size_t)N*F*4;
  float* xjb   = (float*)(ws + off); off += (size_t)N*F*4;
  float* m     = (float*)(ws + off); off += (size_t)N*F*4;
  float* last2 = (float*)(ws + off); off += (size_t)N*2*4;
  float* Ea    = (float*)(ws + off); off += (size_t)N*4;   // zero region start
  float* Qa    = (float*)(ws + off); off += (size_t)N*4;
  float* nh    = (float*)(ws + off); off += 256;
  int*   counts= (int*)  (ws + off); off += (size_t)N*4;   // zero region end
  int*   starts= (int*)  (ws + off); off += (size_t)(N+1)*4;
  int*   cursor= (int*)  (ws + off); off += (size_t)N*4;
  int*   locEx = (int*)  (ws + off); off += (size_t)N*4;
  int*   bsum  = (int*)  (ws + off); off += 64*4;
  int*   boff  = (int*)  (ws + off); off += 68*4;

  float* outF = (float*)d_out;
  float* Dout = outF + (size_t)2*N;

  const int nb = (N + 255)/256;   // 40
  const int nzero = 3*N + 64;
  k_zero<<<dim3((nzero+255)/256), dim3(256), 0, stream>>>(Ea, nzero);
  k_dij_count<<<dim3((P+255)/256), dim3(256), 0, stream>>>(R, idx_i, idx_j, DijF, Dout, counts, P);
  k_scanA<<<dim3(nb), dim3(256), 0, stream>>>(counts, locEx, bsum, N);
  k_scanB<<<dim3(1), dim3(64), 0, stream>>>(bsum, boff, nb);
  k_scanC<<<dim3(nb), dim3(256), 0, stream>>>(locEx, boff, starts, cursor, N, nb);
  k_scatter<<<dim3((P+255)/256), dim3(256), 0, stream>>>(idx_i, idx_j, DijF, cursor, i_s, j_s, D_s, P);
  k_rbf<<<dim3((P*64+255)/256), dim3(256), 0, stream>>>(D_s, cent, wid, rbf_s, P);
  k_prep<<<dim3(20), dim3(256), 0, stream>>>(k2f, k2fP);
  k_prepAll<<<dim3((75*2048+255)/256), dim3(256), 0, stream>>>(riW1, riW2, dWp, raW1, raW2,
                                                               roW1, roW2, Wi, Wj, WBall);
  k_prepO<<<dim3(5), dim3(256), 0, stream>>>(outW, outWB);

  const int G16 = (N + 15)/16;   // 625
  k_phase1m<<<dim3(G16), dim3(128), 0, stream>>>(Z, emb, WBall + (size_t)4*15*16384,
                                                 bi, bj, x, m, xjb, N);

  const int pmg = (P + 511)/512;
  for (int b = 0; b < 5; ++b){
    k_pairmsg2<<<dim3(pmg), dim3(256), 0, stream>>>(rbf_s, k2fP + (size_t)b*16*64*8,
                                                    i_s, j_s, xjb, m, P);
    const unsigned short* WBb = WBall + (size_t)b*15*16384;
    const float* a_rib1 = rib1 + (size_t)b*3*F;
    const float* a_rib2 = rib2 + (size_t)b*3*F;
    const float* a_db   = dbp  + (size_t)b*F;
    const float* a_u    = u    + (size_t)b*F;
    const float* a_rab1 = rab1 + (size_t)b*2*F;
    const float* a_rab2 = rab2 + (size_t)b*2*F;
    const float* a_rob1 = rob1 + (size_t)b*F;
    const float* a_rob2 = rob2 + (size_t)b*F;
    int bn = (b < 4) ? (b+1) : 0;
    const float* a_biN = bi + (size_t)bn*F;
    const float* a_bjN = bj + (size_t)bn*F;
    const unsigned short* oWB = outWB + (size_t)b*2048;
    if (b == 0){
      k_phase2m<1,0><<<dim3(G16), dim3(256), 0, stream>>>(m, x, xjb, WBb,
        a_rib1, a_rib2, a_db, a_u, a_rab1, a_rab2, a_rob1, a_rob2,
        a_biN, a_bjN, oWB, Ea, Qa, last2, nh, N);
    } else if (b < 4){
      k_phase2m<1,1><<<dim3(G16), dim3(256), 0, stream>>>(m, x, xjb, WBb,
        a_rib1, a_rib2, a_db, a_u, a_rab1, a_rab2, a_rob1, a_rob2,
        a_biN, a_bjN, oWB, Ea, Qa, last2, nh, N);
    } else {
      k_phase2m<0,1><<<dim3(G16), dim3(256), 0, stream>>>(m, x, xjb, WBb,
        a_rib1, a_rib2, a_db, a_u, a_rab1, a_rab2, a_rob1, a_rob2,
        a_biN, a_bjN, oWB, Ea, Qa, last2, nh, N);
    }
  }
  k_final<<<dim3((N+255)/256), dim3(256), 0, stream>>>(Z, Ea, Qa, Es, Eh, Qs, Qh, nh, outF, N, P);
}

// Round 10
// 518.666 us; speedup vs baseline: 9.5209x; 1.0041x over previous
//
#include <hip/hip_runtime.h>

typedef __attribute__((ext_vector_type(8))) short bfrag;   // 8 bf16 (4 VGPRs)
typedef __attribute__((ext_vector_type(4))) float ffrag;   // 4 fp32

__device__ __forceinline__ unsigned short f2b(float f){
  unsigned int u = __float_as_uint(f);
  return (unsigned short)((u + 0x7FFFu + ((u >> 16) & 1u)) >> 16);
}
// shifted softplus via v_exp/v_log (both base-2 on gfx950)
__device__ __forceinline__ float actf(float v){
  float e = __builtin_amdgcn_exp2f(-fabsf(v)*1.44269504088896341f);
  return fmaxf(v, 0.f) + __builtin_amdgcn_logf(1.f + e)*0.69314718055994531f - 0.69314718055994531f;
}

// ---------- small utility kernels ----------
__global__ __launch_bounds__(256) void k_zero(float* p, int n){
  int i = blockIdx.x*256 + threadIdx.x;
  if (i < n) p[i] = 0.f;
}

__global__ __launch_bounds__(256) void k_dij_count(
    const float* __restrict__ R, const int* __restrict__ idx_i, const int* __restrict__ idx_j,
    float* __restrict__ DijF, float* __restrict__ Dout, int* __restrict__ counts, int P){
  int p = blockIdx.x*256 + threadIdx.x;
  if (p >= P) return;
  int i = idx_i[p], j = idx_j[p];
  float dx = R[i*3+0] - R[j*3+0];
  float dy = R[i*3+1] - R[j*3+1];
  float dz = R[i*3+2] - R[j*3+2];
  float D = sqrtf(fmaxf(dx*dx + dy*dy + dz*dz, 0.f));
  DijF[p] = D;
  Dout[p] = D;
  atomicAdd(&counts[i], 1);
}

// hierarchical scan
__global__ __launch_bounds__(256) void k_scanA(const int* __restrict__ counts,
    int* __restrict__ locEx, int* __restrict__ bsum, int N){
  __shared__ int buf[256];
  int tid = threadIdx.x, idx = blockIdx.x*256 + tid;
  int v = (idx < N) ? counts[idx] : 0;
  buf[tid] = v;
  __syncthreads();
  for (int off = 1; off < 256; off <<= 1){
    int t = (tid >= off) ? buf[tid-off] : 0;
    __syncthreads();
    buf[tid] += t;
    __syncthreads();
  }
  if (idx < N) locEx[idx] = buf[tid] - v;
  if (tid == 255) bsum[blockIdx.x] = buf[255];
}
__global__ __launch_bounds__(64) void k_scanB(int* __restrict__ bsum,
    int* __restrict__ boff, int nb){
  if (threadIdx.x == 0){
    int acc = 0;
    for (int i = 0; i < nb; ++i){ boff[i] = acc; acc += bsum[i]; }
    boff[nb] = acc;
  }
}
__global__ __launch_bounds__(256) void k_scanC(const int* __restrict__ locEx,
    const int* __restrict__ boff, int* __restrict__ starts, int* __restrict__ cursor,
    int N, int nb){
  int idx = blockIdx.x*256 + threadIdx.x;
  if (idx < N){
    int s = locEx[idx] + boff[blockIdx.x];
    starts[idx] = s; cursor[idx] = s;
  }
  if (idx == 0) starts[N] = boff[nb];
}

__global__ __launch_bounds__(256) void k_scatter(const int* __restrict__ idx_i,
    const int* __restrict__ idx_j, const float* __restrict__ DijF,
    int* __restrict__ cursor, int* __restrict__ i_s, int* __restrict__ j_s,
    float* __restrict__ D_s, int P){
  int p = blockIdx.x*256 + threadIdx.x;
  if (p >= P) return;
  int i = idx_i[p];
  int pos = atomicAdd(&cursor[i], 1);
  i_s[pos] = i;
  j_s[pos] = idx_j[p];
  D_s[pos] = DijF[p];
}

__global__ __launch_bounds__(256) void k_rbf(
    const float* __restrict__ D_s, const float* __restrict__ cent, const float* __restrict__ wid,
    unsigned short* __restrict__ rbf_s, int P){
  int gid = blockIdx.x*256 + threadIdx.x;
  if (gid >= P*64) return;
  int t = gid >> 6, k = gid & 63;
  float D = D_s[t];
  float xc = D * 0.1f;
  float cut = 0.f;
  if (xc < 1.f){
    float x3 = xc*xc*xc, x4 = x3*xc, x5 = x4*xc;
    cut = 1.f - 6.f*x5 + 15.f*x4 - 10.f*x3;
  }
  float tt = expf(-D) - cent[k];
  rbf_s[gid] = f2b(cut * expf(-wid[k]*tt*tt));
}

// k2f B-frag prep -- unchanged, HW-verified
__global__ __launch_bounds__(256) void k_prep(const float* __restrict__ k2f,
    unsigned short* __restrict__ k2fP){
  int gid = blockIdx.x*256 + threadIdx.x;
  if (gid >= 5120) return;
  int l = gid & 63, fr = (gid >> 6) & 15, b = gid >> 10;
  int tile = fr >> 1, kh = fr & 1;
  const float* src = k2f + (size_t)b*64*128;
  int n = tile*16 + (l & 15);
  int kbase = kh*32 + (l >> 4)*8;
  ushort4 o0, o1;
  o0.x = f2b(src[(kbase+0)*128+n]); o0.y = f2b(src[(kbase+1)*128+n]);
  o0.z = f2b(src[(kbase+2)*128+n]); o0.w = f2b(src[(kbase+3)*128+n]);
  o1.x = f2b(src[(kbase+4)*128+n]); o1.y = f2b(src[(kbase+5)*128+n]);
  o1.z = f2b(src[(kbase+6)*128+n]); o1.w = f2b(src[(kbase+7)*128+n]);
  ushort4* dst = (ushort4*)(k2fP + (size_t)gid*8);
  dst[0] = o0; dst[1] = o1;
}

// ALL 75 weight matrices repacked in ONE launch (mapping as round 9)
__global__ __launch_bounds__(256) void k_prepAll(
    const float* __restrict__ riW1, const float* __restrict__ riW2,
    const float* __restrict__ dW,   const float* __restrict__ raW1,
    const float* __restrict__ raW2, const float* __restrict__ roW1,
    const float* __restrict__ roW2, const float* __restrict__ Wi,
    const float* __restrict__ Wj,   unsigned short* __restrict__ WBall){
  int gid = blockIdx.x*256 + threadIdx.x;
  if (gid >= 75*2048) return;
  int i = gid >> 11, r = gid & 2047;
  const float* S;
  int slot;
  if (i < 15)      { S = riW1 + (size_t)i*16384;      slot = (i/3)*15 + 2*(i%3); }
  else if (i < 30) { int j=i-15; S = riW2 + (size_t)j*16384; slot = (j/3)*15 + 2*(j%3) + 1; }
  else if (i < 35) { int j=i-30; S = dW   + (size_t)j*16384; slot = j*15 + 6; }
  else if (i < 45) { int j=i-35; S = raW1 + (size_t)j*16384; slot = (j/2)*15 + 7 + 2*(j%2); }
  else if (i < 55) { int j=i-45; S = raW2 + (size_t)j*16384; slot = (j/2)*15 + 8 + 2*(j%2); }
  else if (i < 60) { int j=i-55; S = roW1 + (size_t)j*16384; slot = j*15 + 11; }
  else if (i < 65) { int j=i-60; S = roW2 + (size_t)j*16384; slot = j*15 + 12; }
  else if (i < 70) { int j=i-65; S = Wi   + (size_t)j*16384; slot = ((j==0)?4:(j-1))*15 + 13; }
  else             { int j=i-70; S = Wj   + (size_t)j*16384; slot = ((j==0)?4:(j-1))*15 + 14; }
  int fr = r >> 6, l = r & 63;
  int T = fr >> 2, k0 = fr & 3;
  int n = T*16 + (l & 15);
  int kbase = k0*32 + (l >> 4)*8;
  unsigned short* D = WBall + ((size_t)slot*2048 + r)*8;
  ushort4 o0, o1;
  o0.x=f2b(S[(kbase+0)*128+n]); o0.y=f2b(S[(kbase+1)*128+n]);
  o0.z=f2b(S[(kbase+2)*128+n]); o0.w=f2b(S[(kbase+3)*128+n]);
  o1.x=f2b(S[(kbase+4)*128+n]); o1.y=f2b(S[(kbase+5)*128+n]);
  o1.z=f2b(S[(kbase+6)*128+n]); o1.w=f2b(S[(kbase+7)*128+n]);
  ((ushort4*)D)[0]=o0; ((ushort4*)D)[1]=o1;
}

// outW[b] [128x2] -> padded B-frags -- unchanged
__global__ __launch_bounds__(256) void k_prepO(const float* __restrict__ outW,
    unsigned short* __restrict__ outWB){
  int gid = blockIdx.x*256 + threadIdx.x;
  if (gid >= 5*256) return;
  int b = gid >> 8, r = gid & 255;
  int l = r & 63;
  int col = l & 15;
  int k0 = r >> 6;
  int kbase = k0*32 + (l >> 4)*8;
  ushort4 o0 = {0,0,0,0}, o1 = {0,0,0,0};
  if (col < 2){
    const float* S = outW + (size_t)b*256;
    o0.x=f2b(S[(kbase+0)*2+col]); o0.y=f2b(S[(kbase+1)*2+col]);
    o0.z=f2b(S[(kbase+2)*2+col]); o0.w=f2b(S[(kbase+3)*2+col]);
    o1.x=f2b(S[(kbase+4)*2+col]); o1.y=f2b(S[(kbase+5)*2+col]);
    o1.z=f2b(S[(kbase+6)*2+col]); o1.w=f2b(S[(kbase+7)*2+col]);
  }
  unsigned short* D = outWB + ((size_t)b*256 + r)*8;
  ((ushort4*)D)[0]=o0; ((ushort4*)D)[1]=o1;
}

// ---------- MFMA tile machinery ----------
// phase1 (2 waves, 4 col-tiles each)
__device__ __forceinline__ void mmtile(const unsigned short* tile,
    const unsigned short* __restrict__ WB, int w, int l, ffrag C[4]){
  int m = l & 15, q = l >> 4;
  bfrag A[4];
  #pragma unroll
  for (int k0 = 0; k0 < 4; ++k0)
    A[k0] = *(const bfrag*)(tile + m*136 + k0*32 + q*8);
  #pragma unroll
  for (int tt = 0; tt < 4; ++tt){
    ffrag c = {0.f,0.f,0.f,0.f};
    const bfrag* bp = (const bfrag*)(WB + (((w*4+tt)*4)*64 + l)*8);
    #pragma unroll
    for (int k0 = 0; k0 < 4; ++k0)
      c = __builtin_amdgcn_mfma_f32_16x16x32_bf16(A[k0], bp[k0*64], c, 0, 0, 0);
    C[tt] = c;
  }
}

// phase2 pipelined helpers: B held in registers (8 bfrags per stage)
__device__ __forceinline__ void loadB8(const unsigned short* __restrict__ WB,
    int w, int l, bfrag* B){
  #pragma unroll
  for (int tt = 0; tt < 2; ++tt)
    #pragma unroll
    for (int k0 = 0; k0 < 4; ++k0)
      B[tt*4+k0] = *(const bfrag*)(WB + ((size_t)((((w*2+tt)*4)+k0)*64 + l))*8);
}
__device__ __forceinline__ void mmB(const unsigned short* tile, const bfrag* B,
    int l, ffrag C[2]){
  int m = l & 15, q = l >> 4;
  bfrag A[4];
  #pragma unroll
  for (int k0 = 0; k0 < 4; ++k0)
    A[k0] = *(const bfrag*)(tile + m*136 + k0*32 + q*8);
  #pragma unroll
  for (int tt = 0; tt < 2; ++tt){
    ffrag c = {0.f,0.f,0.f,0.f};
    #pragma unroll
    for (int k0 = 0; k0 < 4; ++k0)
      c = __builtin_amdgcn_mfma_f32_16x16x32_bf16(A[k0], B[tt*4+k0], c, 0, 0, 0);
    C[tt] = c;
  }
}

// phase1: x = emb[Z]; m_g = act(act(x)@Wi0+bi0); xjb = act(act(x)@Wj0+bj0)
__global__ __launch_bounds__(128) void k_phase1m(
    const int* __restrict__ Z, const float* __restrict__ emb,
    const unsigned short* __restrict__ WB45,
    const float* __restrict__ bi0, const float* __restrict__ bj0,
    float* __restrict__ x_g, float* __restrict__ m_g, float* __restrict__ xjb_g, int N){
  __shared__ unsigned short tile[16*136];
  int tid = threadIdx.x, w = tid >> 6, l = tid & 63;
  int m = l & 15, q = l >> 4, rbase = blockIdx.x*16;
  #pragma unroll
  for (int r = 0; r < 4; ++r){
    int row = rbase + q*4 + r;
    int z = Z[row];
    #pragma unroll
    for (int tt = 0; tt < 4; ++tt){
      int c = (w*4+tt)*16 + m;
      float v = emb[(size_t)z*128 + c];
      x_g[(size_t)row*128 + c] = v;
      tile[(q*4+r)*136 + c] = f2b(actf(v));
    }
  }
  __syncthreads();
  ffrag C[4];
  mmtile(tile, WB45 + 13*16384, w, l, C);
  #pragma unroll
  for (int tt = 0; tt < 4; ++tt){
    int c = (w*4+tt)*16 + m;
    float bb = bi0[c];
    #pragma unroll
    for (int r = 0; r < 4; ++r)
      m_g[(size_t)(rbase + q*4 + r)*128 + c] = actf(C[tt][r] + bb);
  }
  mmtile(tile, WB45 + 14*16384, w, l, C);
  #pragma unroll
  for (int tt = 0; tt < 4; ++tt){
    int c = (w*4+tt)*16 + m;
    float bb = bj0[c];
    #pragma unroll
    for (int r = 0; r < 4; ++r)
      xjb_g[(size_t)(rbase + q*4 + r)*128 + c] = actf(C[tt][r] + bb);
  }
}

// MFMA pair-message, pipelined: prefetch next batch's A-frags + indices during
// the current batch's consume loop. (P % 512 == 0)
__global__ __launch_bounds__(256) void k_pairmsg2(
    const unsigned short* __restrict__ rbf_s, const unsigned short* __restrict__ k2fP,
    const int* __restrict__ i_s, const int* __restrict__ j_s,
    const float* __restrict__ xj, float* __restrict__ m_g, int P){
  __shared__ float G[4][16*130];
  int tid = threadIdx.x, w = tid >> 6, l = tid & 63;
  float* Gw = &G[w][0];
  bfrag B[16];
  #pragma unroll
  for (int t = 0; t < 8; ++t){
    #pragma unroll
    for (int kh = 0; kh < 2; ++kh)
      B[t*2+kh] = *(const bfrag*)(k2fP + (size_t)((t*2+kh)*64 + l)*8);
  }
  int wstart = (blockIdx.x*4 + w)*128;
  if (wstart >= P) return;
  int row16 = l & 15, quad = l >> 4;
  float a0 = 0.f, a1 = 0.f;
  int iCur = -1;
  // preload batch 0
  bfrag A0 = *(const bfrag*)(rbf_s + (size_t)(wstart + row16)*64 + quad*8);
  bfrag A1 = *(const bfrag*)(rbf_s + (size_t)(wstart + row16)*64 + 32 + quad*8);
  int4 iv[4], jv[4];
  #pragma unroll
  for (int g = 0; g < 4; ++g){
    iv[g] = *(const int4*)(i_s + wstart + g*4);
    jv[g] = *(const int4*)(j_s + wstart + g*4);
  }
  #pragma unroll 1
  for (int bi2 = 0; bi2 < 8; ++bi2){
    int bt = wstart + bi2*16;
    const int* ip = (const int*)iv;
    const int* jp = (const int*)jv;
    float2 xv[16];
    #pragma unroll
    for (int k = 0; k < 16; ++k)
      xv[k] = *(const float2*)(xj + (size_t)jp[k]*128 + 2*l);
    #pragma unroll
    for (int t = 0; t < 8; ++t){
      ffrag C = {0.f,0.f,0.f,0.f};
      C = __builtin_amdgcn_mfma_f32_16x16x32_bf16(A0, B[t*2],   C, 0, 0, 0);
      C = __builtin_amdgcn_mfma_f32_16x16x32_bf16(A1, B[t*2+1], C, 0, 0, 0);
      #pragma unroll
      for (int r = 0; r < 4; ++r)
        Gw[(quad*4+r)*130 + t*16 + row16] = C[r];
    }
    // prefetch next batch (overlaps consume loop below)
    bfrag nA0, nA1;
    int4 niv[4], njv[4];
    if (bi2 < 7){
      int btn = bt + 16;
      nA0 = *(const bfrag*)(rbf_s + (size_t)(btn + row16)*64 + quad*8);
      nA1 = *(const bfrag*)(rbf_s + (size_t)(btn + row16)*64 + 32 + quad*8);
      #pragma unroll
      for (int g = 0; g < 4; ++g){
        niv[g] = *(const int4*)(i_s + btn + g*4);
        njv[g] = *(const int4*)(j_s + btn + g*4);
      }
    }
    #pragma unroll
    for (int k = 0; k < 16; ++k){
      int i = ip[k];
      if (i != iCur){
        if (iCur >= 0){
          unsafeAtomicAdd(&m_g[(size_t)iCur*128 + 2*l],     a0);
          unsafeAtomicAdd(&m_g[(size_t)iCur*128 + 2*l + 1], a1);
        }
        iCur = i; a0 = 0.f; a1 = 0.f;
      }
      float g0 = Gw[k*130 + 2*l], g1 = Gw[k*130 + 2*l + 1];
      a0 = fmaf(g0, xv[k].x, a0);
      a1 = fmaf(g1, xv[k].y, a1);
    }
    if (bi2 < 7){
      A0 = nA0; A1 = nA1;
      #pragma unroll
      for (int g = 0; g < 4; ++g){ iv[g] = niv[g]; jv[g] = njv[g]; }
    }
  }
  if (iCur >= 0){
    unsafeAtomicAdd(&m_g[(size_t)iCur*128 + 2*l],     a0);
    unsafeAtomicAdd(&m_g[(size_t)iCur*128 + 2*l + 1], a1);
  }
}

// ---------- phase 2: pipelined stage loop, 4 waves / 16-row tile ----------
// W slots: riW1[l]=2l riW2[l]=2l+1 dW=6 raW1=7+2l raW2=8+2l roW1=11 roW2=12 WiN=13 WjN=14
// Stage seq (HASNEXT): 0,1,2,3,4,5,6,7,8,9,10,13,14,11,12 ; (!HASNEXT): 0..10,11,12
// Bias LDS: 0-2 rib1, 3-5 rib2, 6 db, 7 u, 8-9 rab1, 10-11 rab2, 12 rob1, 13 rob2, 14 biN, 15 bjN
template<int HASNEXT, int NH>
__global__ __launch_bounds__(256) void k_phase2m(
    float* __restrict__ m_g, float* __restrict__ x_g, float* __restrict__ xjb_g,
    const unsigned short* __restrict__ WBb,
    const float* __restrict__ rib1, const float* __restrict__ rib2,
    const float* __restrict__ db, const float* __restrict__ u,
    const float* __restrict__ rab1, const float* __restrict__ rab2,
    const float* __restrict__ rob1, const float* __restrict__ rob2,
    const float* __restrict__ biN, const float* __restrict__ bjN,
    const unsigned short* __restrict__ outWBb,
    float* __restrict__ Ea, float* __restrict__ Qa,
    float* __restrict__ last2, float* __restrict__ nh, int N){
  __shared__ unsigned short tiles[2][16*136];
  __shared__ float biasS[16*128];
  int tid = threadIdx.x, w = tid >> 6, l = tid & 63;
  int m = l & 15, q = l >> 4, rbase = blockIdx.x*16;
  ffrag mC[2], xC[2], C[2];
  int cur = 0;
  const int nst = HASNEXT ? 15 : 13;
  const int slotSeq[15] = {0,1,2,3,4,5,6,7,8,9,10,
                           HASNEXT?13:11, HASNEXT?14:12, 11, 12};
  bfrag Bb[2][8];
  loadB8(WBb + (size_t)slotSeq[0]*16384, w, l, Bb[0]);

  if (tid < 128){
    biasS[0*128+tid]  = rib1[tid];
    biasS[1*128+tid]  = rib1[128+tid];
    biasS[2*128+tid]  = rib1[256+tid];
    biasS[3*128+tid]  = rib2[tid];
    biasS[4*128+tid]  = rib2[128+tid];
    biasS[5*128+tid]  = rib2[256+tid];
    biasS[6*128+tid]  = db[tid];
    biasS[7*128+tid]  = u[tid];
    biasS[8*128+tid]  = rab1[tid];
    biasS[9*128+tid]  = rab1[128+tid];
    biasS[10*128+tid] = rab2[tid];
    biasS[11*128+tid] = rab2[128+tid];
    biasS[12*128+tid] = rob1[tid];
    biasS[13*128+tid] = rob2[tid];
    biasS[14*128+tid] = biN[tid];
    biasS[15*128+tid] = bjN[tid];
  }
  // preload x rows (used at stage 6)
  float xrow[2][4];
  #pragma unroll
  for (int tt = 0; tt < 2; ++tt){
    int c = (w*2+tt)*16 + m;
    #pragma unroll
    for (int r = 0; r < 4; ++r)
      xrow[tt][r] = x_g[(size_t)(rbase + q*4 + r)*128 + c];
  }
  // S0: load m -> mC; tiles[0] = act(m)
  #pragma unroll
  for (int tt = 0; tt < 2; ++tt){
    int c = (w*2+tt)*16 + m;
    #pragma unroll
    for (int r = 0; r < 4; ++r){
      float v = m_g[(size_t)(rbase + q*4 + r)*128 + c];
      mC[tt][r] = v;
      tiles[0][(q*4+r)*136 + c] = f2b(actf(v));
    }
  }
  #pragma unroll
  for (int s = 0; s < nst; ++s){
    __syncthreads();
    if (s+1 < nst) loadB8(WBb + (size_t)slotSeq[s+1]*16384, w, l, Bb[(s+1)&1]);
    mmB(tiles[cur], Bb[s&1], l, C);
    if (HASNEXT && s == 11){            // WiN -> m_g for next block
      #pragma unroll
      for (int tt = 0; tt < 2; ++tt){
        int c = (w*2+tt)*16 + m;
        float bb = biasS[14*128 + c];
        #pragma unroll
        for (int r = 0; r < 4; ++r)
          m_g[(size_t)(rbase + q*4 + r)*128 + c] = actf(C[tt][r] + bb);
      }
    } else if (HASNEXT && s == 12){     // WjN -> xjb for next block
      #pragma unroll
      for (int tt = 0; tt < 2; ++tt){
        int c = (w*2+tt)*16 + m;
        float bb = biasS[15*128 + c];
        #pragma unroll
        for (int r = 0; r < 4; ++r)
          xjb_g[(size_t)(rbase + q*4 + r)*128 + c] = actf(C[tt][r] + bb);
      }
    } else if (s == 6){                 // x-update
      #pragma unroll
      for (int tt = 0; tt < 2; ++tt){
        int c = (w*2+tt)*16 + m;
        float uu = biasS[7*128 + c], bb = biasS[6*128 + c];
        #pragma unroll
        for (int r = 0; r < 4; ++r){
          float nv = uu*xrow[tt][r] + C[tt][r] + bb;
          xC[tt][r] = nv;
          tiles[1-cur][(q*4+r)*136 + c] = f2b(actf(nv));
        }
      }
      cur ^= 1;
    } else if (s == 1 || s == 3 || s == 5){   // m-residual close
      #pragma unroll
      for (int tt = 0; tt < 2; ++tt){
        int c = (w*2+tt)*16 + m;
        float bb = biasS[(3 + (s>>1))*128 + c];
        #pragma unroll
        for (int r = 0; r < 4; ++r){
          float nv = mC[tt][r] + C[tt][r] + bb;
          mC[tt][r] = nv;
          tiles[1-cur][(q*4+r)*136 + c] = f2b(actf(nv));
        }
      }
      cur ^= 1;
    } else if (s == 8 || s == 10){            // x-residual close
      #pragma unroll
      for (int tt = 0; tt < 2; ++tt){
        int c = (w*2+tt)*16 + m;
        float bb = biasS[(10 + ((s-8)>>1))*128 + c];
        #pragma unroll
        for (int r = 0; r < 4; ++r){
          float nv = xC[tt][r] + C[tt][r] + bb;
          xC[tt][r] = nv;
          tiles[1-cur][(q*4+r)*136 + c] = f2b(actf(nv));
          if (HASNEXT && s == 10)
            x_g[(size_t)(rbase + q*4 + r)*128 + c] = nv;
        }
      }
      cur ^= 1;
    } else if ((HASNEXT && s == 14) || (!HASNEXT && s == 12)){  // o = x + h@roW2 + b
      #pragma unroll
      for (int tt = 0; tt < 2; ++tt){
        int c = (w*2+tt)*16 + m;
        float bb = biasS[13*128 + c];
        #pragma unroll
        for (int r = 0; r < 4; ++r){
          float ov = xC[tt][r] + C[tt][r] + bb;
          tiles[1-cur][(q*4+r)*136 + c] = f2b(actf(ov));
        }
      }
      cur ^= 1;
    } else {                                  // act-only stages
      int bidx = (s==0)?0:(s==2)?1:(s==4)?2:(s==7)?8:(s==9)?9:12;
      #pragma unroll
      for (int tt = 0; tt < 2; ++tt){
        int c = (w*2+tt)*16 + m;
        float bb = biasS[bidx*128 + c];
        #pragma unroll
        for (int r = 0; r < 4; ++r)
          tiles[1-cur][(q*4+r)*136 + c] = f2b(actf(C[tt][r] + bb));
      }
      cur ^= 1;
    }
  }
  // head: out = act(o) @ outW (padded to 16 cols), wave 0 only
  __syncthreads();
  if (w == 0){
    bfrag A[4];
    #pragma unroll
    for (int k0 = 0; k0 < 4; ++k0)
      A[k0] = *(const bfrag*)(&tiles[cur][0] + m*136 + k0*32 + q*8);
    ffrag Ch = {0.f,0.f,0.f,0.f};
    #pragma unroll
    for (int k0 = 0; k0 < 4; ++k0){
      bfrag B = *(const bfrag*)(outWBb + (size_t)(k0*64 + l)*8);
      Ch = __builtin_amdgcn_mfma_f32_16x16x32_bf16(A[k0], B, Ch, 0, 0, 0);
    }
    int col = m;
    if (col < 2){
      float tp = 0.f;
      #pragma unroll
      for (int r = 0; r < 4; ++r){
        int row = rbase + q*4 + r;
        float val = Ch[r];
        if (col == 0) Ea[row] += val; else Qa[row] += val;
        float sq = val*val;
        if (NH){
          float lastv = last2[row*2 + col];
          tp += sq/(sq + lastv + 1e-7f);
        }
        last2[row*2 + col] = sq;
      }
      if (NH) unsafeAtomicAdd(nh, tp);
    }
  }
}

__global__ __launch_bounds__(256) void k_final(
    const int* __restrict__ Z, const float* __restrict__ Ea, const float* __restrict__ Qa,
    const float* __restrict__ Es, const float* __restrict__ Eh,
    const float* __restrict__ Qs, const float* __restrict__ Qh,
    const float* __restrict__ nh, float* __restrict__ out, int N, int P){
  int n = blockIdx.x*256 + threadIdx.x;
  if (n < N){
    int z = Z[n];
    out[n]   = Es[z]*Ea[n] + Eh[z];
    out[N+n] = Qs[z]*Qa[n] + Qh[z];
  }
  if (blockIdx.x == 0 && threadIdx.x == 0)
    out[(size_t)2*N + P] = nh[0] / (2.f * (float)N);
}

extern "C" void kernel_launch(void* const* d_in, const int* in_sizes, int n_in,
                              void* d_out, int out_size, void* d_ws, size_t ws_size,
                              hipStream_t stream){
  const int N = in_sizes[0];
  const int P = in_sizes[2];
  const int F = 128;

  const int* Z      = (const int*)d_in[0];
  const float* R    = (const float*)d_in[1];
  const int* idx_i  = (const int*)d_in[2];
  const int* idx_j  = (const int*)d_in[3];
  const float* emb  = (const float*)d_in[4];
  const float* cent = (const float*)d_in[5];
  const float* wid  = (const float*)d_in[6];
  const float* k2f  = (const float*)d_in[7];
  const float* Wi   = (const float*)d_in[8];  const float* bi   = (const float*)d_in[9];
  const float* Wj   = (const float*)d_in[10]; const float* bj   = (const float*)d_in[11];
  const float* riW1 = (const float*)d_in[12]; const float* rib1 = (const float*)d_in[13];
  const float* riW2 = (const float*)d_in[14]; const float* rib2 = (const float*)d_in[15];
  const float* dWp  = (const float*)d_in[16]; const float* dbp  = (const float*)d_in[17];
  const float* u    = (const float*)d_in[18];
  const float* raW1 = (const float*)d_in[19]; const float* rab1 = (const float*)d_in[20];
  const float* raW2 = (const float*)d_in[21]; const float* rab2 = (const float*)d_in[22];
  const float* roW1 = (const float*)d_in[23]; const float* rob1 = (const float*)d_in[24];
  const float* roW2 = (const float*)d_in[25]; const float* rob2 = (const float*)d_in[26];
  const float* outW = (const float*)d_in[27];
  const float* Es   = (const float*)d_in[28]; const float* Eh   = (const float*)d_in[29];
  const float* Qs   = (const float*)d_in[30]; const float* Qh   = (const float*)d_in[31];

  char* ws = (char*)d_ws;
  size_t off = 0;
  float* DijF  = (float*)(ws + off); off += (size_t)P*4;
  float* D_s   = (float*)(ws + off); off += (size_t)P*4;
  int*   i_s   = (int*)  (ws + off); off += (size_t)P*4;
  int*   j_s   = (int*)  (ws + off); off += (size_t)P*4;
  unsigned short* rbf_s = (unsigned short*)(ws + off); off += (size_t)P*64*2;
  unsigned short* k2fP  = (unsigned short*)(ws + off); off += (size_t)5*16*64*8*2;
  unsigned short* WBall = (unsigned short*)(ws + off); off += (size_t)75*16384*2;
  unsigned short* outWB = (unsigned short*)(ws + off); off += (size_t)5*2048*2;
  float* x     = (float*)(ws + off); off += (size_t)N*F*4;
  float* xjb   = (float*)(ws + off); off += (size_t)N*F*4;
  float* m     = (float*)(ws + off); off += (size_t)N*F*4;
  float* last2 = (float*)(ws + off); off += (size_t)N*2*4;
  float* Ea    = (float*)(ws + off); off += (size_t)N*4;   // zero region start
  float* Qa    = (float*)(ws + off); off += (size_t)N*4;
  float* nh    = (float*)(ws + off); off += 256;
  int*   counts= (int*)  (ws + off); off += (size_t)N*4;   // zero region end
  int*   starts= (int*)  (ws + off); off += (size_t)(N+1)*4;
  int*   cursor= (int*)  (ws + off); off += (size_t)N*4;
  int*   locEx = (int*)  (ws + off); off += (size_t)N*4;
  int*   bsum  = (int*)  (ws + off); off += 64*4;
  int*   boff  = (int*)  (ws + off); off += 68*4;

  float* outF = (float*)d_out;
  float* Dout = outF + (size_t)2*N;

  const int nb = (N + 255)/256;   // 40
  const int nzero = 3*N + 64;
  k_zero<<<dim3((nzero+255)/256), dim3(256), 0, stream>>>(Ea, nzero);
  k_dij_count<<<dim3((P+255)/256), dim3(256), 0, stream>>>(R, idx_i, idx_j, DijF, Dout, counts, P);
  k_scanA<<<dim3(nb), dim3(256), 0, stream>>>(counts, locEx, bsum, N);
  k_scanB<<<dim3(1), dim3(64), 0, stream>>>(bsum, boff, nb);
  k_scanC<<<dim3(nb), dim3(256), 0, stream>>>(locEx, boff, starts, cursor, N, nb);
  k_scatter<<<dim3((P+255)/256), dim3(256), 0, stream>>>(idx_i, idx_j, DijF, cursor, i_s, j_s, D_s, P);
  k_rbf<<<dim3((P*64+255)/256), dim3(256), 0, stream>>>(D_s, cent, wid, rbf_s, P);
  k_prep<<<dim3(20), dim3(256), 0, stream>>>(k2f, k2fP);
  k_prepAll<<<dim3((75*2048+255)/256), dim3(256), 0, stream>>>(riW1, riW2, dWp, raW1, raW2,
                                                               roW1, roW2, Wi, Wj, WBall);
  k_prepO<<<dim3(5), dim3(256), 0, stream>>>(outW, outWB);

  const int G16 = (N + 15)/16;   // 625
  k_phase1m<<<dim3(G16), dim3(128), 0, stream>>>(Z, emb, WBall + (size_t)4*15*16384,
                                                 bi, bj, x, m, xjb, N);

  const int pmg = (P + 511)/512;
  for (int b = 0; b < 5; ++b){
    k_pairmsg2<<<dim3(pmg), dim3(256), 0, stream>>>(rbf_s, k2fP + (size_t)b*16*64*8,
                                                    i_s, j_s, xjb, m, P);
    const unsigned short* WBb = WBall + (size_t)b*15*16384;
    const float* a_rib1 = rib1 + (size_t)b*3*F;
    const float* a_rib2 = rib2 + (size_t)b*3*F;
    const float* a_db   = dbp  + (size_t)b*F;
    const float* a_u    = u    + (size_t)b*F;
    const float* a_rab1 = rab1 + (size_t)b*2*F;
    const float* a_rab2 = rab2 + (size_t)b*2*F;
    const float* a_rob1 = rob1 + (size_t)b*F;
    const float* a_rob2 = rob2 + (size_t)b*F;
    int bn = (b < 4) ? (b+1) : 0;
    const float* a_biN = bi + (size_t)bn*F;
    const float* a_bjN = bj + (size_t)bn*F;
    const unsigned short* oWB = outWB + (size_t)b*2048;
    if (b == 0){
      k_phase2m<1,0><<<dim3(G16), dim3(256), 0, stream>>>(m, x, xjb, WBb,
        a_rib1, a_rib2, a_db, a_u, a_rab1, a_rab2, a_rob1, a_rob2,
        a_biN, a_bjN, oWB, Ea, Qa, last2, nh, N);
    } else if (b < 4){
      k_phase2m<1,1><<<dim3(G16), dim3(256), 0, stream>>>(m, x, xjb, WBb,
        a_rib1, a_rib2, a_db, a_u, a_rab1, a_rab2, a_rob1, a_rob2,
        a_biN, a_bjN, oWB, Ea, Qa, last2, nh, N);
    } else {
      k_phase2m<0,1><<<dim3(G16), dim3(256), 0, stream>>>(m, x, xjb, WBb,
        a_rib1, a_rib2, a_db, a_u, a_rab1, a_rab2, a_rob1, a_rob2,
        a_biN, a_bjN, oWB, Ea, Qa, last2, nh, N);
    }
  }
  k_final<<<dim3((N+255)/256), dim3(256), 0, stream>>>(Z, Ea, Qa, Es, Eh, Qs, Qh, nh, outF, N, P);
}